// Round 16
// baseline (886.622 us; speedup 1.0000x reference)
//
#include <hip/hip_runtime.h>
#include <hip/hip_bf16.h>
#include <math.h>

typedef __attribute__((ext_vector_type(8))) short bf16x8;
typedef __attribute__((ext_vector_type(8))) unsigned short u16x8;
typedef __attribute__((ext_vector_type(4))) float f32x4;
typedef __attribute__((ext_vector_type(2))) long longx2;

// ---------------- workspace layout (bytes) ----------------
#define OFF_X1   0ull           // x1 [8,258,258,32] bf16; DEAD after conv2 -> reused as xq8
#define OFF_XQ8  0ull           // xq8 [8,128,128,256] fp8 (33.5 MB), k-permuted per 128-half
#define OFF_X2   34080768ull
#define OFF_X3   51386368ull
#define OFF_Y4   60039168ull
#define OFF_WB8  127148032ull   // wb8 [512,9,256] fp8 (1.18 MB), k-permuted per 128-half
#define OFF_WB2  129507328ull
#define OFF_WB3  129548288ull
#define OFF_WBT  129695744ull
#define OFF_ST1  130744320ull
#define OFF_ST2  130746368ull
#define OFF_ST3  130750464ull
#define OFF_ST4  130758656ull
#define OFF_SUMS 130775040ull
#define OFF_CNT  131086336ull
#define OFF_MS1  131086944ull
#define OFF_MS2  131088992ull
#define OFF_MS3  131093088ull
#define OFF_MS4  131101280ull
#define OFF_LAB  131117664ull
#define OFF_DWS  131641952ull   // dws  [512][256] f32 (512 KB)
#define OFF_WSM  132166240ull   // wsum [512][256] f32 (512 KB)
#define OFF_ST5  132690528ull   // st5  [8][2][256] f32 (16 KB, zeroed)
#define OFF_CB   132706912ull   // cb   [8][512] f32 (16 KB)

__device__ __forceinline__ float bfu2f(unsigned short u) {
  return __builtin_bit_cast(float, ((unsigned)u) << 16);
}
__device__ __forceinline__ unsigned short f2bfu(float f) {
  __hip_bfloat16 h = __float2bfloat16(f);
  return __builtin_bit_cast(unsigned short, h);
}
__device__ __forceinline__ void gload_lds16(const void* g, void* l) {
  __builtin_amdgcn_global_load_lds(
      (const __attribute__((address_space(1))) unsigned int*)g,
      (__attribute__((address_space(3))) unsigned int*)l, 16, 0, 0);
}
template <bool HI>
__device__ __forceinline__ int cvtpk8(float a, float b, int old) {
  return __builtin_amdgcn_cvt_pk_fp8_f32(a, b, old, HI);
}
template <int SEL>
__device__ __forceinline__ float cvtf8(int v) {
  return __builtin_amdgcn_cvt_f32_fp8(v, SEL);
}

#define WAITV(N) asm volatile("s_waitcnt vmcnt(" #N ")" ::: "memory")

// counted-vmcnt pipelined step (2-phase, used by convT)
#define PIPE_STEP(WAITN, BUF, DOSTAGE, SNEXT)                 \
  asm volatile("s_waitcnt vmcnt(" #WAITN ")" ::: "memory");   \
  __builtin_amdgcn_s_barrier();                               \
  __builtin_amdgcn_sched_barrier(0);                          \
  mmaStep(BUF, (BUF) + 16384);                                \
  __builtin_amdgcn_sched_barrier(0);                          \
  __builtin_amdgcn_s_barrier();                               \
  if (DOSTAGE) stage(SNEXT, BUF);

// ---------------- pad-zero: x1/x2/x3 borders only (replaces 60MB memset) ----------------
__global__ __launch_bounds__(256) void padz_k(unsigned short* __restrict__ x1,
                                              unsigned short* __restrict__ x2,
                                              unsigned short* __restrict__ x3) {
  int u = blockIdx.x * 256 + threadIdx.x;  // < 82944
  int b = u / 10368, r = u % 10368;
  u16x8 z = {0, 0, 0, 0, 0, 0, 0, 0};
  if (r < 4128) {
    unsigned short* base = x1 + (size_t)b * 2130048;
    if (r < 2064) {
      int row = r < 1032 ? 0 : 257, pos = r < 1032 ? r : r - 1032;
      base += (row * 258 + (pos >> 2)) * 32 + (pos & 3) * 8;
    } else {
      int rc = r - 2064;
      int col = rc < 1032 ? 0 : 257, pos = rc < 1032 ? rc : rc - 1032;
      base += ((pos >> 2) * 258 + col) * 32 + (pos & 3) * 8;
    }
    *(u16x8*)base = z;
  } else if (r < 8288) {
    int s = r - 4128;
    unsigned short* base = x2 + (size_t)b * 1081600;
    if (s < 2080) {
      int row = s < 1040 ? 0 : 129, pos = s < 1040 ? s : s - 1040;
      base += (row * 130 + (pos >> 3)) * 64 + (pos & 7) * 8;
    } else {
      int sc = s - 2080;
      int col = sc < 1040 ? 0 : 129, pos = sc < 1040 ? sc : sc - 1040;
      base += ((pos >> 3) * 130 + col) * 64 + (pos & 7) * 8;
    }
    *(u16x8*)base = z;
  } else {
    int t = r - 8288;
    unsigned short* base = x3 + (size_t)b * 540800;
    if (t < 1040) {
      base += (64 * 65 + (t >> 4)) * 128 + (t & 15) * 8;
    } else {
      int pos = t - 1040;
      base += ((pos >> 4) * 65 + 64) * 128 + (pos & 15) * 8;
    }
    *(u16x8*)base = z;
  }
}

// ---------------- conv1: reflect-pad 3->32 -> x1 NHWC padded bf16 ----------------
__global__ __launch_bounds__(256) void conv1_k(const float* __restrict__ img,
                                               const float* __restrict__ w1,
                                               unsigned short* __restrict__ x1) {
  __shared__ float wl[864];  // [k 27][oc 32]
  int t = threadIdx.x, y = blockIdx.x, b = blockIdx.y;
  for (int i = t; i < 864; i += 256) wl[i] = w1[(i & 31) * 27 + (i >> 5)];
  __syncthreads();
  int x = t;
  float val[27];
  for (int ic = 0; ic < 3; ++ic) {
    const float* ip = img + ((size_t)(b * 3 + ic)) * 65536;
#pragma unroll
    for (int ky = 0; ky < 3; ++ky) {
      int gy = y - 1 + ky; gy = gy < 0 ? -gy : (gy > 255 ? 510 - gy : gy);
#pragma unroll
      for (int kx = 0; kx < 3; ++kx) {
        int gx = x - 1 + kx; gx = gx < 0 ? -gx : (gx > 255 ? 510 - gx : gx);
        val[ic * 9 + ky * 3 + kx] = ip[gy * 256 + gx];
      }
    }
  }
  float a[32];
#pragma unroll
  for (int oc = 0; oc < 32; ++oc) a[oc] = 0.f;
#pragma unroll
  for (int k = 0; k < 27; ++k) {
    float vv = val[k];
#pragma unroll
    for (int oc = 0; oc < 32; ++oc) a[oc] += wl[k * 32 + oc] * vv;
  }
  unsigned short ov[32];
#pragma unroll
  for (int oc = 0; oc < 32; ++oc) ov[oc] = f2bfu(a[oc]);
  unsigned short* op = x1 + ((size_t)(b * 258 + y + 1) * 258 + (x + 1)) * 32;
#pragma unroll
  for (int i = 0; i < 4; ++i) *(u16x8*)(op + i * 8) = *(const u16x8*)(ov + i * 8);
}

// ---------------- generic NHWC channel stats (sum, sumsq) ----------------
template <int C>
__global__ void statsn_k(const unsigned short* __restrict__ base, int rowStride, int unitsLog,
                         int rowsPer, long bStride, float* __restrict__ stats) {
  const int CH8 = C / 8;
  __shared__ float bins[C * 2];
  int tid = threadIdx.x, slice = blockIdx.x, b = blockIdx.y;
  for (int i = tid; i < C * 2; i += 256) bins[i] = 0.f;
  __syncthreads();
  const unsigned short* bp = base + (size_t)b * bStride + (size_t)(slice * rowsPer) * rowStride;
  int total = rowsPer << unitsLog;
  float s8[8] = {0, 0, 0, 0, 0, 0, 0, 0}, q8[8] = {0, 0, 0, 0, 0, 0, 0, 0};
  for (int idx = tid; idx < total; idx += 256) {
    int rl = idx >> unitsLog, ux = idx & ((1 << unitsLog) - 1);
    u16x8 v = *(const u16x8*)(bp + (size_t)rl * rowStride + ux * 8);
#pragma unroll
    for (int e = 0; e < 8; ++e) { float f = bfu2f(v[e]); s8[e] += f; q8[e] += f * f; }
  }
#pragma unroll
  for (int e = 0; e < 8; ++e)
    for (int off = 32; off >= CH8; off >>= 1) {
      s8[e] += __shfl_xor(s8[e], off);
      q8[e] += __shfl_xor(q8[e], off);
    }
  int lane = tid & 63;
  if (lane < CH8) {
#pragma unroll
    for (int e = 0; e < 8; ++e) {
      atomicAdd(&bins[(lane * 8 + e) * 2], s8[e]);
      atomicAdd(&bins[(lane * 8 + e) * 2 + 1], q8[e]);
    }
  }
  __syncthreads();
  for (int i = tid; i < C * 2; i += 256) atomicAdd(&stats[b * C * 2 + i], bins[i]);
}

// ---------------- stats -> (mean, rstd) ----------------
__global__ void msn_k(const float* __restrict__ st, float2* __restrict__ ms, float invN, int total) {
  int i = blockIdx.x * 256 + threadIdx.x;
  if (i < total) {
    float m = st[2 * i] * invN;
    float v = st[2 * i + 1] * invN - m * m;
    ms[i] = make_float2(m, rsqrtf(fmaxf(v, 0.f) + 1e-5f));
  }
}

// ---------------- normalize + leaky-relu in place (NHWC bf16, interior) ----------------
template <int C>
__global__ void nln_k(unsigned short* __restrict__ base, int rowStride, int unitsPerRow,
                      long bStride, const float2* __restrict__ ms) {
  const int CH8 = C / 8;
  int row = blockIdx.x, b = blockIdx.y;
  unsigned short* rp = base + (size_t)b * bStride + (size_t)row * rowStride;
  const float2* msb = ms + b * C;
  for (int idx = threadIdx.x; idx < unitsPerRow; idx += 256) {
    u16x8 v = *(u16x8*)(rp + idx * 8);
    int ch = (idx & (CH8 - 1)) * 8;
    u16x8 o;
#pragma unroll
    for (int e = 0; e < 8; ++e) {
      float2 m = msb[ch + e];
      float f = (bfu2f(v[e]) - m.x) * m.y;
      o[e] = f2bfu(f >= 0.f ? f : 0.2f * f);
    }
    *(u16x8*)(rp + idx * 8) = o;
  }
}

// ---------------- nln8: y4 bf16 -> norm+lrelu -> fp8 xq8 (k-permuted) + channel sums ------
__global__ __launch_bounds__(256) void nln8_k(const unsigned short* __restrict__ y4,
                                              const float2* __restrict__ ms,
                                              unsigned char* __restrict__ xq8,
                                              float* __restrict__ st5) {
  __shared__ float bs[512];
  int t = threadIdx.x, row = blockIdx.x, b = blockIdx.y;
  int cg = t & 31, pg = t >> 5;
  int wof0 = (cg >> 4) * 128 + ((((cg & 15) & 3) << 2) | ((cg & 15) >> 2)) * 8;
  const float2* msb = ms + b * 256;
  float2 m0[8];
#pragma unroll
  for (int e = 0; e < 8; ++e) m0[e] = msb[cg * 8 + e];
  const unsigned short* rp = y4 + ((size_t)b * 16384 + row * 128) * 256;
  unsigned char* op = xq8 + ((size_t)b * 16384 + (size_t)row * 128) * 256;
  float s[8] = {0, 0, 0, 0, 0, 0, 0, 0}, d[8] = {0, 0, 0, 0, 0, 0, 0, 0};
  for (int i = 0; i < 16; ++i) {
    int px = pg * 16 + i;
    u16x8 v = *(const u16x8*)(rp + (size_t)px * 256 + cg * 8);
    float f[8];
#pragma unroll
    for (int e = 0; e < 8; ++e) {
      float x = (bfu2f(v[e]) - m0[e].x) * m0[e].y;
      f[e] = x >= 0.f ? x : 0.2f * x;
    }
    int lo = cvtpk8<false>(f[0], f[1], 0); lo = cvtpk8<true>(f[2], f[3], lo);
    int hi = cvtpk8<false>(f[4], f[5], 0); hi = cvtpk8<true>(f[6], f[7], hi);
    *(long*)(op + (size_t)px * 256 + wof0) =
        ((long)(unsigned)hi << 32) | (unsigned)lo;
    float fq;
    fq = cvtf8<0>(lo); s[0] += fq; d[0] += fq - f[0];
    fq = cvtf8<1>(lo); s[1] += fq; d[1] += fq - f[1];
    fq = cvtf8<2>(lo); s[2] += fq; d[2] += fq - f[2];
    fq = cvtf8<3>(lo); s[3] += fq; d[3] += fq - f[3];
    fq = cvtf8<0>(hi); s[4] += fq; d[4] += fq - f[4];
    fq = cvtf8<1>(hi); s[5] += fq; d[5] += fq - f[5];
    fq = cvtf8<2>(hi); s[6] += fq; d[6] += fq - f[6];
    fq = cvtf8<3>(hi); s[7] += fq; d[7] += fq - f[7];
  }
  for (int i = t; i < 512; i += 256) bs[i] = 0.f;
  __syncthreads();
#pragma unroll
  for (int e = 0; e < 8; ++e) {
    atomicAdd(&bs[cg * 8 + e], s[e]);
    atomicAdd(&bs[256 + cg * 8 + e], d[e]);
  }
  __syncthreads();
  for (int i = t; i < 512; i += 256) atomicAdd(&st5[b * 512 + i], bs[i]);
}

// ---------------- weight repacks ----------------
__global__ void wrep2_k(const float* __restrict__ w2, unsigned short* __restrict__ wb2) {
  int idx = blockIdx.x * 256 + threadIdx.x;
  if (idx >= 20480) return;
  int oc = idx / 320, r = idx % 320, tap = r >> 5, ic = r & 31;
  wb2[idx] = tap < 9 ? f2bfu(w2[(oc * 32 + ic) * 9 + tap]) : (unsigned short)0;
}
__global__ void wrep3_k(const float* __restrict__ w3, unsigned short* __restrict__ wb3) {
  int idx = blockIdx.x * 256 + threadIdx.x;
  int oc = idx / 576, r = idx % 576, tap = r >> 6, ic = r & 63;
  wb3[idx] = f2bfu(w3[(oc * 64 + ic) * 9 + tap]);
}
__device__ const int c_taptab[16] = {4, -1, -1, -1, 5, 3, -1, -1, 7, -1, 1, -1, 8, 6, 2, 0};
__global__ void wrepT_k(const float* __restrict__ wt, unsigned short* __restrict__ wbt) {
  int idx = blockIdx.x * 256 + threadIdx.x;
  int n = idx >> 9, k = idx & 511;
  int cl = n >> 8, oc = n & 255, nb = k >> 7, ic = k & 127;
  int tap = c_taptab[cl * 4 + nb];
  wbt[idx] = tap < 0 ? (unsigned short)0 : f2bfu(wt[(ic * 256 + oc) * 9 + tap]);
}
// w4 OIHW f32 -> wb8 [oc][9][256] fp8 (k-permuted), dws = sum_tap(wq - w), wsum = sum_tap(w)
__global__ __launch_bounds__(256) void dwrep_k(const float* __restrict__ w4,
                                               unsigned char* __restrict__ wb8,
                                               float* __restrict__ dws,
                                               float* __restrict__ wsum) {
  int oc = blockIdx.x, ic = threadIdx.x;
  int local = ic & 127;
  int p = (ic & 128) + ((local >> 3) & 3) * 32 + ((local >> 5) & 3) * 8 + (local & 7);
  float ds = 0.f, ws = 0.f;
  for (int kk = 0; kk < 9; ++kk) {
    float w = w4[(size_t)oc * 2304 + ic * 9 + kk];
    int pk = cvtpk8<false>(w, 0.f, 0);
    wb8[((size_t)oc * 9 + kk) * 256 + p] = (unsigned char)(pk & 0xff);
    float wq = cvtf8<0>(pk);
    ds += wq - w; ws += w;
  }
  dws[oc * 256 + ic] = ds;
  wsum[oc * 256 + ic] = ws;
}

// ---------------- cbias: c[b][oc] = sum_ic( muq*dws + dmu*wsum ) ----------------
__global__ __launch_bounds__(256) void cbias_k(const float* __restrict__ st5,
                                               const float* __restrict__ dws,
                                               const float* __restrict__ wsum,
                                               float* __restrict__ cb) {
  int oc = blockIdx.x, b = blockIdx.y, t = threadIdx.x;
  const float inv = 1.f / 16384.f;
  float muq = st5[b * 512 + t] * inv;
  float dmu = st5[b * 512 + 256 + t] * inv;
  float a = muq * dws[oc * 256 + t] + dmu * wsum[oc * 256 + t];
#pragma unroll
  for (int o = 1; o < 64; o <<= 1) a += __shfl_xor(a, o);
  __shared__ float r[4];
  if ((t & 63) == 0) r[t >> 6] = a;
  __syncthreads();
  if (t == 0) cb[b * 512 + oc] = r[0] + r[1] + r[2] + r[3];
}

// ---------------- conv2 MFMA (double-buffered): x1 -> x2 + stats ----------------
__global__ __launch_bounds__(256) void conv2_k(const unsigned short* __restrict__ x1,
                                               const unsigned short* __restrict__ wb2,
                                               unsigned short* __restrict__ x2,
                                               float* __restrict__ st2) {
  __shared__ char smem[49664];
  float* bins = (float*)(smem + 49152);
  int tid = threadIdx.x, y = blockIdx.x, b = blockIdx.y;
  int lane = tid & 63, w = tid >> 6, wm = w >> 1, wn = w & 1;
  int lr = lane & 15, lg = lane >> 4;
  f32x4 acc[4][2];
#pragma unroll
  for (int i = 0; i < 4; ++i)
#pragma unroll
    for (int j = 0; j < 2; ++j) acc[i][j] = (f32x4){0.f, 0.f, 0.f, 0.f};

  int rowA[4], lcA[4], PbA[4];
#pragma unroll
  for (int i = 0; i < 4; ++i) {
    int pb = i * 256 + tid;
    PbA[i] = pb * 16; rowA[i] = pb >> 3; lcA[i] = (pb & 7) ^ (rowA[i] & 7);
  }
  int rowB[2], lcB[2], PbB[2];
#pragma unroll
  for (int i = 0; i < 2; ++i) {
    int pb = i * 256 + tid;
    PbB[i] = pb * 16; rowB[i] = pb >> 3; lcB[i] = (pb & 7) ^ (rowB[i] & 7);
  }
  const unsigned short* xb = x1 + (size_t)b * 2130048;

  auto stage = [&](int kb, char* base) {
    char* As = base;
    char* Bs = base + 16384;
#pragma unroll
    for (int i = 0; i < 4; ++i) {
      int tp = kb * 2 + (lcA[i] >> 2);
      int ky = (tp * 11) >> 5;
      int kx = tp - ky * 3;
      gload_lds16(xb + ((size_t)((2 * y + ky) * 258 + 2 * rowA[i] + kx)) * 32 + (lcA[i] & 3) * 8,
                  As + PbA[i]);
    }
#pragma unroll
    for (int i = 0; i < 2; ++i)
      gload_lds16(wb2 + rowB[i] * 320 + kb * 64 + lcB[i] * 8, Bs + PbB[i]);
  };

  stage(0, smem);
  __syncthreads();
  for (int kb = 0; kb < 5; ++kb) {
    char* base = smem + (kb & 1) * 24576;
    if (kb + 1 < 5) stage(kb + 1, smem + ((kb + 1) & 1) * 24576);
    char* As = base;
    char* Bs = base + 16384;
    bf16x8 af[4][2], bfr[2][2];
#pragma unroll
    for (int mi = 0; mi < 4; ++mi)
#pragma unroll
      for (int kh = 0; kh < 2; ++kh) {
        int row = wm * 64 + mi * 16 + lr;
        int byte = row * 128 + ((kh * 64 + lg * 16) ^ ((row & 7) << 4));
        af[mi][kh] = *(const bf16x8*)(As + byte);
      }
#pragma unroll
    for (int ni = 0; ni < 2; ++ni)
#pragma unroll
      for (int kh = 0; kh < 2; ++kh) {
        int row = wn * 32 + ni * 16 + lr;
        int byte = row * 128 + ((kh * 64 + lg * 16) ^ ((row & 7) << 4));
        bfr[ni][kh] = *(const bf16x8*)(Bs + byte);
      }
#pragma unroll
    for (int mi = 0; mi < 4; ++mi)
#pragma unroll
      for (int ni = 0; ni < 2; ++ni)
#pragma unroll
        for (int kh = 0; kh < 2; ++kh)
          acc[mi][ni] = __builtin_amdgcn_mfma_f32_16x16x32_bf16(af[mi][kh], bfr[ni][kh],
                                                                acc[mi][ni], 0, 0, 0);
    __syncthreads();
  }

  if (tid < 128) bins[tid] = 0.f;
  __syncthreads();
  unsigned short* ob = x2 + (size_t)b * 1081600;
#pragma unroll
  for (int ni = 0; ni < 2; ++ni) {
    int oc = wn * 32 + ni * 16 + lr;
    float s = 0.f, q = 0.f;
#pragma unroll
    for (int mi = 0; mi < 4; ++mi)
#pragma unroll
      for (int r = 0; r < 4; ++r) {
        int m = wm * 64 + mi * 16 + lg * 4 + r;
        float v = acc[mi][ni][r];
        ob[((y + 1) * 130 + m + 1) * 64 + oc] = f2bfu(v);
        s += v; q += v * v;
      }
    atomicAdd(&bins[oc * 2], s);
    atomicAdd(&bins[oc * 2 + 1], q);
  }
  __syncthreads();
  if (tid < 128) atomicAdd(&st2[b * 128 + tid], bins[tid]);
}

// ---------------- conv3 MFMA (double-buffered): x2 -> x3 + stats ----------------
__global__ __launch_bounds__(256) void conv3_k(const unsigned short* __restrict__ x2,
                                               const unsigned short* __restrict__ wb3,
                                               unsigned short* __restrict__ x3,
                                               float* __restrict__ st3) {
  __shared__ char smem[66560];
  float* bins = (float*)(smem + 65536);
  int tid = threadIdx.x, y0 = blockIdx.x * 2, b = blockIdx.y;
  int lane = tid & 63, w = tid >> 6, wm = w >> 1, wn = w & 1;
  int lr = lane & 15, lg = lane >> 4;
  f32x4 acc[4][4];
#pragma unroll
  for (int i = 0; i < 4; ++i)
#pragma unroll
    for (int j = 0; j < 4; ++j) acc[i][j] = (f32x4){0.f, 0.f, 0.f, 0.f};

  int rowS[4], lc[4], Pb[4];
#pragma unroll
  for (int i = 0; i < 4; ++i) {
    int pb = i * 256 + tid;
    Pb[i] = pb * 16; rowS[i] = pb >> 3; lc[i] = (pb & 7) ^ (rowS[i] & 7);
  }
  const unsigned short* xb = x2 + (size_t)b * 1081600;

  auto stage = [&](int kk, char* base) {
    int ky = kk / 3, kx = kk - ky * 3;
#pragma unroll
    for (int i = 0; i < 4; ++i) {
      int m = rowS[i], di = m >> 6, xx = m & 63;
      gload_lds16(xb + ((size_t)((2 * (y0 + di) + ky) * 130 + 2 * xx + kx)) * 64 + lc[i] * 8,
                  base + Pb[i]);
    }
#pragma unroll
    for (int i = 0; i < 4; ++i)
      gload_lds16(wb3 + (rowS[i] * 9 + kk) * 64 + lc[i] * 8, base + 16384 + Pb[i]);
  };

  stage(0, smem);
  __syncthreads();
  for (int kk = 0; kk < 9; ++kk) {
    char* base = smem + (kk & 1) * 32768;
    if (kk + 1 < 9) stage(kk + 1, smem + ((kk + 1) & 1) * 32768);
    char* As = base;
    char* Bs = base + 16384;
    bf16x8 af[4][2], bfr[4][2];
#pragma unroll
    for (int mi = 0; mi < 4; ++mi)
#pragma unroll
      for (int kh = 0; kh < 2; ++kh) {
        int row = wm * 64 + mi * 16 + lr;
        int byte = row * 128 + ((kh * 64 + lg * 16) ^ ((row & 7) << 4));
        af[mi][kh] = *(const bf16x8*)(As + byte);
      }
#pragma unroll
    for (int ni = 0; ni < 4; ++ni)
#pragma unroll
      for (int kh = 0; kh < 2; ++kh) {
        int row = wn * 64 + ni * 16 + lr;
        int byte = row * 128 + ((kh * 64 + lg * 16) ^ ((row & 7) << 4));
        bfr[ni][kh] = *(const bf16x8*)(Bs + byte);
      }
#pragma unroll
    for (int mi = 0; mi < 4; ++mi)
#pragma unroll
      for (int ni = 0; ni < 4; ++ni)
#pragma unroll
        for (int kh = 0; kh < 2; ++kh)
          acc[mi][ni] = __builtin_amdgcn_mfma_f32_16x16x32_bf16(af[mi][kh], bfr[ni][kh],
                                                                acc[mi][ni], 0, 0, 0);
    __syncthreads();
  }

  if (tid < 256) bins[tid] = 0.f;
  __syncthreads();
  unsigned short* ob = x3 + (size_t)b * 540800;
#pragma unroll
  for (int ni = 0; ni < 4; ++ni) {
    int oc = wn * 64 + ni * 16 + lr;
    float s = 0.f, q = 0.f;
#pragma unroll
    for (int mi = 0; mi < 4; ++mi)
#pragma unroll
      for (int r = 0; r < 4; ++r) {
        int m = wm * 64 + mi * 16 + lg * 4 + r;
        int di = m >> 6, xx = m & 63;
        float v = acc[mi][ni][r];
        ob[((y0 + di) * 65 + xx) * 128 + oc] = f2bfu(v);
        s += v; q += v * v;
      }
    atomicAdd(&bins[oc * 2], s);
    atomicAdd(&bins[oc * 2 + 1], q);
  }
  __syncthreads();
  if (tid < 256) atomicAdd(&st3[b * 256 + tid], bins[tid]);
}

// ---------------- convT MFMA (counted-vmcnt pipeline): x3 -> y4 + stats ----------------
__global__ __launch_bounds__(256) void convT_k(const unsigned short* __restrict__ x3,
                                               const unsigned short* __restrict__ wbt,
                                               unsigned short* __restrict__ y4,
                                               float* __restrict__ st4) {
  __shared__ char smem[67584];
  float* bins = (float*)(smem + 65536);
  int tid = threadIdx.x, i0 = blockIdx.x * 2, nblk = blockIdx.y, b = blockIdx.z;
  int n0 = nblk * 128, cl = nblk >> 1, och0 = (nblk & 1) * 128;
  int lane = tid & 63, w = tid >> 6, wm = w >> 1, wn = w & 1;
  int lr = lane & 15, lg = lane >> 4;
  f32x4 acc[4][4];
#pragma unroll
  for (int i = 0; i < 4; ++i)
#pragma unroll
    for (int j = 0; j < 4; ++j) acc[i][j] = (f32x4){0.f, 0.f, 0.f, 0.f};

  int rowS[4], lc[4], Pb[4];
#pragma unroll
  for (int i = 0; i < 4; ++i) {
    int pb = i * 256 + tid;
    Pb[i] = pb * 16; rowS[i] = pb >> 3; lc[i] = (pb & 7) ^ (rowS[i] & 7);
  }
  int aoff[4][2], boff[4][2];
#pragma unroll
  for (int mi = 0; mi < 4; ++mi)
#pragma unroll
    for (int kh = 0; kh < 2; ++kh) {
      int row = wm * 64 + mi * 16 + lr;
      aoff[mi][kh] = row * 128 + ((kh * 64 + lg * 16) ^ ((row & 7) << 4));
      int rowb = wn * 64 + mi * 16 + lr;
      boff[mi][kh] = rowb * 128 + ((kh * 64 + lg * 16) ^ ((rowb & 7) << 4));
    }
  const unsigned short* xb = x3 + (size_t)b * 540800;

  auto stage = [&](int kb, char* base) {
    int nb = kb >> 1, chalf = (kb & 1) * 64;
#pragma unroll
    for (int i = 0; i < 4; ++i) {
      int m = rowS[i], di = m >> 6, j = m & 63;
      int pi = i0 + di + (nb >> 1), pj = j + (nb & 1);
      gload_lds16(xb + ((size_t)(pi * 65 + pj)) * 128 + chalf + lc[i] * 8, base + Pb[i]);
    }
#pragma unroll
    for (int i = 0; i < 4; ++i)
      gload_lds16(wbt + (size_t)(n0 + rowS[i]) * 512 + kb * 64 + lc[i] * 8,
                  base + 16384 + Pb[i]);
  };

  auto mmaStep = [&](char* As, char* Bs) {
    bf16x8 af[4][2], bfr[4][2];
#pragma unroll
    for (int mi = 0; mi < 4; ++mi)
#pragma unroll
      for (int kh = 0; kh < 2; ++kh) af[mi][kh] = *(const bf16x8*)(As + aoff[mi][kh]);
#pragma unroll
    for (int ni = 0; ni < 4; ++ni)
#pragma unroll
      for (int kh = 0; kh < 2; ++kh) bfr[ni][kh] = *(const bf16x8*)(Bs + boff[ni][kh]);
#pragma unroll
    for (int mi = 0; mi < 4; ++mi)
#pragma unroll
      for (int ni = 0; ni < 4; ++ni)
#pragma unroll
        for (int kh = 0; kh < 2; ++kh)
          acc[mi][ni] = __builtin_amdgcn_mfma_f32_16x16x32_bf16(af[mi][kh], bfr[ni][kh],
                                                                acc[mi][ni], 0, 0, 0);
  };

  char* B0 = smem;
  char* B1 = smem + 32768;
  stage(0, B0);
  stage(1, B1);
  for (int sp = 0; sp < 3; ++sp) {
    PIPE_STEP(8, B0, true, 2 * sp + 2);
    PIPE_STEP(8, B1, true, 2 * sp + 3);
  }
  PIPE_STEP(8, B0, false, 0);
  PIPE_STEP(0, B1, false, 0);

  if (tid < 256) bins[tid] = 0.f;
  __syncthreads();
  unsigned short* ob = y4 + (size_t)b * 4194304;
  int dy = cl >> 1, dx = cl & 1;
#pragma unroll
  for (int ni = 0; ni < 4; ++ni) {
    int loc = wn * 64 + ni * 16 + lr;
    int oc = och0 + loc;
    float s = 0.f, q = 0.f;
#pragma unroll
    for (int mi = 0; mi < 4; ++mi)
#pragma unroll
      for (int r = 0; r < 4; ++r) {
        int m = wm * 64 + mi * 16 + lg * 4 + r;
        int di = m >> 6, j = m & 63;
        int oy = 2 * (i0 + di) + dy, ox = 2 * j + dx;
        float v = acc[mi][ni][r];
        ob[(oy * 128 + ox) * 256 + oc] = f2bfu(v);
        s += v; q += v * v;
      }
    atomicAdd(&bins[loc * 2], s);
    atomicAdd(&bins[loc * 2 + 1], q);
  }
  __syncthreads();
  if (tid < 256) atomicAdd(&st4[b * 512 + och0 * 2 + tid], bins[tid]);
}

// ---------------- label map + counts ----------------
__global__ void lab_k(const float* __restrict__ seg, int* __restrict__ lab,
                      float* __restrict__ counts) {
  __shared__ int hist[19];
  int t = threadIdx.x;
  if (t < 19) hist[t] = 0;
  __syncthreads();
  int b = blockIdx.y;
  int p = blockIdx.x * 256 + t;
  int i = p >> 7, j = p & 127;
  const float* sp = seg + (size_t)b * 19 * 65536 + (2 * i) * 256 + 2 * j;
  int l = 0;
  for (int k = 0; k < 19; ++k) { if (sp[(size_t)k * 65536] != 0.f) { l = k; break; } }
  lab[b * 16384 + p] = l;
  atomicAdd(&hist[l], 1);
  __syncthreads();
  if (t < 19) atomicAdd(&counts[b * 19 + t], (float)hist[t]);
}

// ---------------- conv4: fp8 implicit GEMM; A via LDS dbuf, B-frags direct from L2 --------
// A LDS tile [128 rows][128B fp8] double-buffered (33KB total). B-fragments are read
// straight from wb8 (1.2MB, L2-resident): k-permuted layout makes each lane's 32B
// k-block contiguous at (n0+row)*2304 + s*128 + lg*32 — byte-identical to the LDS path.
// Per step: 4 A-staging loads/thread + 8 B register loads/thread; 1 barrier/step.
__global__ __launch_bounds__(256, 4) void conv4_k(
    const unsigned char* __restrict__ xq8, const unsigned char* __restrict__ wb8,
    const float* __restrict__ b4, const float* __restrict__ cb,
    const int* __restrict__ lab, float* __restrict__ sums) {
  __shared__ char smem[33280];  // As dbuf 2x16K | labs 512B
  int* labs = (int*)(smem + 32768);
  int tid = threadIdx.x;
  int id = blockIdx.x;
  int b = id & 7, rr = id >> 3;
  int y = rr >> 2, nblk = rr & 3;
  int n0 = nblk * 128;
  if (tid < 128) labs[tid] = lab[b * 16384 + y * 128 + tid];
  int lane = tid & 63, w = tid >> 6;
  int wm = w >> 1, wn = w & 1;
  int lr = lane & 15, lg = lane >> 4;

  f32x4 acc[4][4];
#pragma unroll
  for (int i = 0; i < 4; ++i)
#pragma unroll
    for (int j = 0; j < 4; ++j) acc[i][j] = (f32x4){0.f, 0.f, 0.f, 0.f};

  const unsigned char* xb = xq8 + (size_t)b * 4194304;

  int rs0 = tid >> 3;
  int csw = ((tid & 7) ^ (rs0 & 7)) << 4;  // byte offset of 16B chunk within 128B row
  int ldoff = tid * 16;                    // + i*4096

  // B-fragment global bases (per ni): 32B contiguous per step at +s*128
  const unsigned char* bb[4];
#pragma unroll
  for (int ni = 0; ni < 4; ++ni)
    bb[ni] = wb8 + (size_t)(n0 + wn * 64 + ni * 16 + lr) * 2304 + lg * 32;

  // A fragment LDS offsets (conflict-free b128 class)
  int aoffL[4][2];
#pragma unroll
  for (int mi = 0; mi < 4; ++mi)
#pragma unroll
    for (int k2 = 0; k2 < 2; ++k2) {
      int row = wm * 64 + mi * 16 + lr;
      aoffL[mi][k2] = row * 128 + ((lg * 32 + k2 * 16) ^ ((row & 7) << 4));
    }

  // step t in [0,18): kk = t>>1, ic0 = (t&1)*128
  auto stageA = [&](int t, char* dst) {
    int kk = t >> 1, ic0 = (t & 1) << 7;
    int ky = (kk * 11) >> 5, kx = kk - ky * 3;
    int sy = y + ky - 1; sy = sy < 0 ? 1 : (sy > 127 ? 126 : sy);
#pragma unroll
    for (int i = 0; i < 4; ++i) {
      int sx = rs0 + 32 * i + kx - 1;
      sx = sx < 0 ? 1 : (sx > 127 ? 126 : sx);
      gload_lds16(xb + ((size_t)(sy * 128 + sx)) * 256 + ic0 + csw, dst + i * 4096 + ldoff);
    }
  };

  char* buf0 = smem;
  char* buf1 = smem + 16384;
  stageA(0, buf0);
  __syncthreads();
  for (int s = 0; s < 18; ++s) {
    char* cur = (s & 1) ? buf1 : buf0;
    char* nxt = (s & 1) ? buf0 : buf1;
    if (s + 1 < 18) stageA(s + 1, nxt);

    longx2 bq[4][2];
#pragma unroll
    for (int ni = 0; ni < 4; ++ni)
#pragma unroll
      for (int k2 = 0; k2 < 2; ++k2)
        bq[ni][k2] = *(const longx2*)(bb[ni] + s * 128 + k2 * 16);

#pragma unroll
    for (int mi = 0; mi < 4; ++mi) {
      longx2 aq[2];
#pragma unroll
      for (int k2 = 0; k2 < 2; ++k2) aq[k2] = *(const longx2*)(cur + aoffL[mi][k2]);
#pragma unroll
      for (int ni = 0; ni < 4; ++ni)
#pragma unroll
        for (int k2 = 0; k2 < 2; ++k2) {
          acc[mi][ni] = __builtin_amdgcn_mfma_f32_16x16x32_fp8_fp8(
              aq[k2][0], bq[ni][k2][0], acc[mi][ni], 0, 0, 0);
          acc[mi][ni] = __builtin_amdgcn_mfma_f32_16x16x32_fp8_fp8(
              aq[k2][1], bq[ni][k2][1], acc[mi][ni], 0, 0, 0);
        }
    }
    __syncthreads();
  }

  // epilogue: (bias - fp8 bias-correction) + tanh + per-label bins
  float* bins = (float*)smem;  // [19][128]
  for (int t2 = tid; t2 < 19 * 128; t2 += 256) bins[t2] = 0.f;
  __syncthreads();
  float bias[4];
#pragma unroll
  for (int ni = 0; ni < 4; ++ni) {
    int gc = n0 + wn * 64 + ni * 16 + lr;
    bias[ni] = b4[gc] - cb[b * 512 + gc];
  }
#pragma unroll
  for (int mi = 0; mi < 4; ++mi)
#pragma unroll
    for (int ni = 0; ni < 4; ++ni) {
      int ct = wn * 64 + ni * 16 + lr;
#pragma unroll
      for (int r = 0; r < 4; ++r) {
        int x = wm * 64 + mi * 16 + lg * 4 + r;
        float v = tanhf(acc[mi][ni][r] + bias[ni]);
        atomicAdd(&bins[labs[x] * 128 + ct], v);
      }
    }
  __syncthreads();
  for (int t2 = tid; t2 < 19 * 128; t2 += 256) {
    float v = bins[t2];
    if (v != 0.f)
      atomicAdd(&sums[((size_t)(b * 19 + (t2 >> 7))) * 512 + n0 + (t2 & 127)], v);
  }
}

// ---------------- finalize ----------------
__global__ void finalize_k(const float* __restrict__ sums, const float* __restrict__ counts,
                           float* __restrict__ out) {
  int idx = blockIdx.x * 256 + threadIdx.x;
  int bl = idx / 512;
  float c = counts[bl];
  out[idx] = c > 0.f ? sums[idx] / fmaxf(c, 1.f) : 0.f;
}

extern "C" void kernel_launch(void* const* d_in, const int* in_sizes, int n_in,
                              void* d_out, int out_size, void* d_ws, size_t ws_size,
                              hipStream_t stream) {
  const float* image = (const float*)d_in[0];
  const float* seg   = (const float*)d_in[1];
  const float* w1    = (const float*)d_in[2];
  const float* w2    = (const float*)d_in[4];
  const float* w3    = (const float*)d_in[6];
  const float* wt    = (const float*)d_in[8];
  const float* w4    = (const float*)d_in[10];
  const float* b4    = (const float*)d_in[11];
  float* out = (float*)d_out;
  char* ws = (char*)d_ws;

  unsigned short* x1  = (unsigned short*)(ws + OFF_X1);
  unsigned char*  xq8 = (unsigned char*)(ws + OFF_XQ8);
  unsigned short* x2  = (unsigned short*)(ws + OFF_X2);
  unsigned short* x3  = (unsigned short*)(ws + OFF_X3);
  unsigned short* y4  = (unsigned short*)(ws + OFF_Y4);
  unsigned char*  wb8 = (unsigned char*)(ws + OFF_WB8);
  unsigned short* wb2 = (unsigned short*)(ws + OFF_WB2);
  unsigned short* wb3 = (unsigned short*)(ws + OFF_WB3);
  unsigned short* wbt = (unsigned short*)(ws + OFF_WBT);
  float* st1 = (float*)(ws + OFF_ST1);
  float* st2 = (float*)(ws + OFF_ST2);
  float* st3 = (float*)(ws + OFF_ST3);
  float* st4 = (float*)(ws + OFF_ST4);
  float* sums = (float*)(ws + OFF_SUMS);
  float* counts = (float*)(ws + OFF_CNT);
  float2* ms1 = (float2*)(ws + OFF_MS1);
  float2* ms2 = (float2*)(ws + OFF_MS2);
  float2* ms3 = (float2*)(ws + OFF_MS3);
  float2* ms4 = (float2*)(ws + OFF_MS4);
  int* lab = (int*)(ws + OFF_LAB);
  float* dws  = (float*)(ws + OFF_DWS);
  float* wsum = (float*)(ws + OFF_WSM);
  float* st5  = (float*)(ws + OFF_ST5);
  float* cbv  = (float*)(ws + OFF_CB);

  // zero only pad borders (interiors fully rewritten each call) + stat buffers
  padz_k<<<324, 256, 0, stream>>>(x1, x2, x3);
  hipMemsetAsync(ws + OFF_ST1, 0, 342624, stream);    // stats+sums+counts
  hipMemsetAsync(ws + OFF_ST5, 0, 16384, stream);     // fp8 channel sums

  wrep2_k<<<80, 256, 0, stream>>>(w2, wb2);
  wrep3_k<<<288, 256, 0, stream>>>(w3, wb3);
  wrepT_k<<<2048, 256, 0, stream>>>(wt, wbt);
  dwrep_k<<<512, 256, 0, stream>>>(w4, wb8, dws, wsum);
  lab_k<<<dim3(64, 8), 256, 0, stream>>>(seg, lab, counts);

  conv1_k<<<dim3(256, 8), 256, 0, stream>>>(image, w1, x1);
  statsn_k<32><<<dim3(16, 8), 256, 0, stream>>>(x1 + 259 * 32, 258 * 32, 10, 16, 2130048L, st1);
  msn_k<<<1, 256, 0, stream>>>(st1, ms1, 1.f / 65536.f, 256);
  nln_k<32><<<dim3(256, 8), 256, 0, stream>>>(x1 + 259 * 32, 258 * 32, 1024, 2130048L, ms1);

  conv2_k<<<dim3(128, 8), 256, 0, stream>>>(x1, wb2, x2, st2);
  msn_k<<<2, 256, 0, stream>>>(st2, ms2, 1.f / 16384.f, 512);
  nln_k<64><<<dim3(128, 8), 256, 0, stream>>>(x2 + 131 * 64, 130 * 64, 1024, 1081600L, ms2);

  conv3_k<<<dim3(32, 8), 256, 0, stream>>>(x2, wb3, x3, st3);
  msn_k<<<4, 256, 0, stream>>>(st3, ms3, 1.f / 4096.f, 1024);
  nln_k<128><<<dim3(64, 8), 256, 0, stream>>>(x3, 65 * 128, 1024, 540800L, ms3);

  convT_k<<<dim3(32, 8, 8), 256, 0, stream>>>(x3, wbt, y4, st4);
  msn_k<<<8, 256, 0, stream>>>(st4, ms4, 1.f / 16384.f, 2048);

  // y4 -> norm+lrelu -> fp8 (xq8, k-permuted) + channel sums; then bias correction
  nln8_k<<<dim3(128, 8), 256, 0, stream>>>(y4, ms4, xq8, st5);
  cbias_k<<<dim3(512, 8), 256, 0, stream>>>(st5, dws, wsum, cbv);

  conv4_k<<<4096, 256, 0, stream>>>(xq8, wb8, b4, cbv, lab, sums);

  finalize_k<<<304, 256, 0, stream>>>(sums, counts, out);
}

// Round 17
// 720.879 us; speedup vs baseline: 1.2299x; 1.2299x over previous
//
#include <hip/hip_runtime.h>
#include <hip/hip_bf16.h>
#include <math.h>

typedef __attribute__((ext_vector_type(8))) short bf16x8;
typedef __attribute__((ext_vector_type(8))) unsigned short u16x8;
typedef __attribute__((ext_vector_type(4))) float f32x4;
typedef __attribute__((ext_vector_type(2))) long longx2;

// ---------------- workspace layout (bytes) ----------------
#define OFF_X1   0ull           // x1 [8,258,258,32] bf16; DEAD after conv2 -> reused as xq8
#define OFF_XQ8  0ull           // xq8 [8,128,128,256] fp8 (33.5 MB), k-permuted per 128-half
#define OFF_X2   34080768ull
#define OFF_X3   51386368ull
#define OFF_Y4   60039168ull
#define OFF_WB8  127148032ull   // wb8 [512,9,256] fp8 (1.18 MB), k-permuted per 128-half
#define OFF_WB2  129507328ull
#define OFF_WB3  129548288ull
#define OFF_WBT  129695744ull
#define OFF_ST1  130744320ull
#define OFF_ST2  130746368ull
#define OFF_ST3  130750464ull
#define OFF_ST4  130758656ull
#define OFF_SUMS 130775040ull
#define OFF_CNT  131086336ull
#define OFF_MS1  131086944ull
#define OFF_MS2  131088992ull
#define OFF_MS3  131093088ull
#define OFF_MS4  131101280ull
#define OFF_LAB  131117664ull
#define OFF_DWS  131641952ull   // dws  [512][256] f32 (512 KB)
#define OFF_WSM  132166240ull   // wsum [512][256] f32 (512 KB)
#define OFF_ST5  132690528ull   // st5  [8][2][256] f32 (16 KB, zeroed)
#define OFF_CB   132706912ull   // cb   [8][512] f32 (16 KB)

__device__ __forceinline__ float bfu2f(unsigned short u) {
  return __builtin_bit_cast(float, ((unsigned)u) << 16);
}
__device__ __forceinline__ unsigned short f2bfu(float f) {
  __hip_bfloat16 h = __float2bfloat16(f);
  return __builtin_bit_cast(unsigned short, h);
}
__device__ __forceinline__ void gload_lds16(const void* g, void* l) {
  __builtin_amdgcn_global_load_lds(
      (const __attribute__((address_space(1))) unsigned int*)g,
      (__attribute__((address_space(3))) unsigned int*)l, 16, 0, 0);
}
template <bool HI>
__device__ __forceinline__ int cvtpk8(float a, float b, int old) {
  return __builtin_amdgcn_cvt_pk_fp8_f32(a, b, old, HI);
}
template <int SEL>
__device__ __forceinline__ float cvtf8(int v) {
  return __builtin_amdgcn_cvt_f32_fp8(v, SEL);
}

#define WAITV(N) asm volatile("s_waitcnt vmcnt(" #N ")" ::: "memory")

// counted-vmcnt pipelined step (2-phase, used by convT)
#define PIPE_STEP(WAITN, BUF, DOSTAGE, SNEXT)                 \
  asm volatile("s_waitcnt vmcnt(" #WAITN ")" ::: "memory");   \
  __builtin_amdgcn_s_barrier();                               \
  __builtin_amdgcn_sched_barrier(0);                          \
  mmaStep(BUF, (BUF) + 16384);                                \
  __builtin_amdgcn_sched_barrier(0);                          \
  __builtin_amdgcn_s_barrier();                               \
  if (DOSTAGE) stage(SNEXT, BUF);

__device__ const int c_taptab[16] = {4, -1, -1, -1, 5, 3, -1, -1, 7, -1, 1, -1, 8, 6, 2, 0};

// ---------------- prep: wrep2 | wrep3 | wrepT | dwrep | padz | lab in ONE launch ----------
// block ranges: [0,80) wrep2, [80,368) wrep3, [368,2416) wrepT, [2416,2928) dwrep,
//               [2928,3252) padz, [3252,3764) lab
__global__ __launch_bounds__(256) void prep_k(
    const float* __restrict__ w2, unsigned short* __restrict__ wb2,
    const float* __restrict__ w3, unsigned short* __restrict__ wb3,
    const float* __restrict__ wt, unsigned short* __restrict__ wbt,
    const float* __restrict__ w4, unsigned char* __restrict__ wb8,
    float* __restrict__ dws, float* __restrict__ wsum,
    unsigned short* __restrict__ x1, unsigned short* __restrict__ x2,
    unsigned short* __restrict__ x3,
    const float* __restrict__ seg, int* __restrict__ lab, float* __restrict__ counts) {
  __shared__ int hist[19];
  int blk = blockIdx.x, t = threadIdx.x;
  if (blk < 80) {
    int idx = blk * 256 + t;
    if (idx < 20480) {
      int oc = idx / 320, r = idx % 320, tap = r >> 5, ic = r & 31;
      wb2[idx] = tap < 9 ? f2bfu(w2[(oc * 32 + ic) * 9 + tap]) : (unsigned short)0;
    }
  } else if (blk < 368) {
    int idx = (blk - 80) * 256 + t;
    int oc = idx / 576, r = idx % 576, tap = r >> 6, ic = r & 63;
    wb3[idx] = f2bfu(w3[(oc * 64 + ic) * 9 + tap]);
  } else if (blk < 2416) {
    int idx = (blk - 368) * 256 + t;
    int n = idx >> 9, k = idx & 511;
    int cl = n >> 8, oc = n & 255, nb = k >> 7, ic = k & 127;
    int tap = c_taptab[cl * 4 + nb];
    wbt[idx] = tap < 0 ? (unsigned short)0 : f2bfu(wt[(ic * 256 + oc) * 9 + tap]);
  } else if (blk < 2928) {
    int oc = blk - 2416, ic = t;
    int local = ic & 127;
    int p = (ic & 128) + ((local >> 3) & 3) * 32 + ((local >> 5) & 3) * 8 + (local & 7);
    float ds = 0.f, ws = 0.f;
    for (int kk = 0; kk < 9; ++kk) {
      float w = w4[(size_t)oc * 2304 + ic * 9 + kk];
      int pk = cvtpk8<false>(w, 0.f, 0);
      wb8[((size_t)oc * 9 + kk) * 256 + p] = (unsigned char)(pk & 0xff);
      float wq = cvtf8<0>(pk);
      ds += wq - w; ws += w;
    }
    dws[oc * 256 + ic] = ds;
    wsum[oc * 256 + ic] = ws;
  } else if (blk < 3252) {
    int u = (blk - 2928) * 256 + t;  // < 82944
    int b = u / 10368, r = u % 10368;
    u16x8 z = {0, 0, 0, 0, 0, 0, 0, 0};
    if (r < 4128) {
      unsigned short* base = x1 + (size_t)b * 2130048;
      if (r < 2064) {
        int row = r < 1032 ? 0 : 257, pos = r < 1032 ? r : r - 1032;
        base += (row * 258 + (pos >> 2)) * 32 + (pos & 3) * 8;
      } else {
        int rc = r - 2064;
        int col = rc < 1032 ? 0 : 257, pos = rc < 1032 ? rc : rc - 1032;
        base += ((pos >> 2) * 258 + col) * 32 + (pos & 3) * 8;
      }
      *(u16x8*)base = z;
    } else if (r < 8288) {
      int s = r - 4128;
      unsigned short* base = x2 + (size_t)b * 1081600;
      if (s < 2080) {
        int row = s < 1040 ? 0 : 129, pos = s < 1040 ? s : s - 1040;
        base += (row * 130 + (pos >> 3)) * 64 + (pos & 7) * 8;
      } else {
        int sc = s - 2080;
        int col = sc < 1040 ? 0 : 129, pos = sc < 1040 ? sc : sc - 1040;
        base += ((pos >> 3) * 130 + col) * 64 + (pos & 7) * 8;
      }
      *(u16x8*)base = z;
    } else {
      int tt = r - 8288;
      unsigned short* base = x3 + (size_t)b * 540800;
      if (tt < 1040) {
        base += (64 * 65 + (tt >> 4)) * 128 + (tt & 15) * 8;
      } else {
        int pos = tt - 1040;
        base += ((pos >> 4) * 65 + 64) * 128 + (pos & 15) * 8;
      }
      *(u16x8*)base = z;
    }
  } else {
    int blk2 = blk - 3252;  // < 512
    int b = blk2 >> 6;
    int p = (blk2 & 63) * 256 + t;
    if (t < 19) hist[t] = 0;
    __syncthreads();
    int i = p >> 7, j = p & 127;
    const float* sp = seg + (size_t)b * 19 * 65536 + (2 * i) * 256 + 2 * j;
    int l = 0;
    for (int k = 0; k < 19; ++k) { if (sp[(size_t)k * 65536] != 0.f) { l = k; break; } }
    lab[b * 16384 + p] = l;
    atomicAdd(&hist[l], 1);
    __syncthreads();
    if (t < 19) atomicAdd(&counts[b * 19 + t], (float)hist[t]);
  }
}

// ---------------- conv1: reflect-pad 3->32 -> x1 NHWC padded bf16 ----------------
__global__ __launch_bounds__(256) void conv1_k(const float* __restrict__ img,
                                               const float* __restrict__ w1,
                                               unsigned short* __restrict__ x1) {
  __shared__ float wl[864];  // [k 27][oc 32]
  int t = threadIdx.x, y = blockIdx.x, b = blockIdx.y;
  for (int i = t; i < 864; i += 256) wl[i] = w1[(i & 31) * 27 + (i >> 5)];
  __syncthreads();
  int x = t;
  float val[27];
  for (int ic = 0; ic < 3; ++ic) {
    const float* ip = img + ((size_t)(b * 3 + ic)) * 65536;
#pragma unroll
    for (int ky = 0; ky < 3; ++ky) {
      int gy = y - 1 + ky; gy = gy < 0 ? -gy : (gy > 255 ? 510 - gy : gy);
#pragma unroll
      for (int kx = 0; kx < 3; ++kx) {
        int gx = x - 1 + kx; gx = gx < 0 ? -gx : (gx > 255 ? 510 - gx : gx);
        val[ic * 9 + ky * 3 + kx] = ip[gy * 256 + gx];
      }
    }
  }
  float a[32];
#pragma unroll
  for (int oc = 0; oc < 32; ++oc) a[oc] = 0.f;
#pragma unroll
  for (int k = 0; k < 27; ++k) {
    float vv = val[k];
#pragma unroll
    for (int oc = 0; oc < 32; ++oc) a[oc] += wl[k * 32 + oc] * vv;
  }
  unsigned short ov[32];
#pragma unroll
  for (int oc = 0; oc < 32; ++oc) ov[oc] = f2bfu(a[oc]);
  unsigned short* op = x1 + ((size_t)(b * 258 + y + 1) * 258 + (x + 1)) * 32;
#pragma unroll
  for (int i = 0; i < 4; ++i) *(u16x8*)(op + i * 8) = *(const u16x8*)(ov + i * 8);
}

// ---------------- generic NHWC channel stats (sum, sumsq) ----------------
template <int C>
__global__ void statsn_k(const unsigned short* __restrict__ base, int rowStride, int unitsLog,
                         int rowsPer, long bStride, float* __restrict__ stats) {
  const int CH8 = C / 8;
  __shared__ float bins[C * 2];
  int tid = threadIdx.x, slice = blockIdx.x, b = blockIdx.y;
  for (int i = tid; i < C * 2; i += 256) bins[i] = 0.f;
  __syncthreads();
  const unsigned short* bp = base + (size_t)b * bStride + (size_t)(slice * rowsPer) * rowStride;
  int total = rowsPer << unitsLog;
  float s8[8] = {0, 0, 0, 0, 0, 0, 0, 0}, q8[8] = {0, 0, 0, 0, 0, 0, 0, 0};
  for (int idx = tid; idx < total; idx += 256) {
    int rl = idx >> unitsLog, ux = idx & ((1 << unitsLog) - 1);
    u16x8 v = *(const u16x8*)(bp + (size_t)rl * rowStride + ux * 8);
#pragma unroll
    for (int e = 0; e < 8; ++e) { float f = bfu2f(v[e]); s8[e] += f; q8[e] += f * f; }
  }
#pragma unroll
  for (int e = 0; e < 8; ++e)
    for (int off = 32; off >= CH8; off >>= 1) {
      s8[e] += __shfl_xor(s8[e], off);
      q8[e] += __shfl_xor(q8[e], off);
    }
  int lane = tid & 63;
  if (lane < CH8) {
#pragma unroll
    for (int e = 0; e < 8; ++e) {
      atomicAdd(&bins[(lane * 8 + e) * 2], s8[e]);
      atomicAdd(&bins[(lane * 8 + e) * 2 + 1], q8[e]);
    }
  }
  __syncthreads();
  for (int i = tid; i < C * 2; i += 256) atomicAdd(&stats[b * C * 2 + i], bins[i]);
}

// ---------------- stats -> (mean, rstd) ----------------
__global__ void msn_k(const float* __restrict__ st, float2* __restrict__ ms, float invN, int total) {
  int i = blockIdx.x * 256 + threadIdx.x;
  if (i < total) {
    float m = st[2 * i] * invN;
    float v = st[2 * i + 1] * invN - m * m;
    ms[i] = make_float2(m, rsqrtf(fmaxf(v, 0.f) + 1e-5f));
  }
}

// ---------------- normalize + leaky-relu in place (NHWC bf16, interior) ----------------
template <int C>
__global__ void nln_k(unsigned short* __restrict__ base, int rowStride, int unitsPerRow,
                      long bStride, const float2* __restrict__ ms) {
  const int CH8 = C / 8;
  int row = blockIdx.x, b = blockIdx.y;
  unsigned short* rp = base + (size_t)b * bStride + (size_t)row * rowStride;
  const float2* msb = ms + b * C;
  for (int idx = threadIdx.x; idx < unitsPerRow; idx += 256) {
    u16x8 v = *(u16x8*)(rp + idx * 8);
    int ch = (idx & (CH8 - 1)) * 8;
    u16x8 o;
#pragma unroll
    for (int e = 0; e < 8; ++e) {
      float2 m = msb[ch + e];
      float f = (bfu2f(v[e]) - m.x) * m.y;
      o[e] = f2bfu(f >= 0.f ? f : 0.2f * f);
    }
    *(u16x8*)(rp + idx * 8) = o;
  }
}

// ---------------- nln8: y4 bf16 -> norm+lrelu -> fp8 xq8 (k-permuted) + channel sums ------
__global__ __launch_bounds__(256) void nln8_k(const unsigned short* __restrict__ y4,
                                              const float2* __restrict__ ms,
                                              unsigned char* __restrict__ xq8,
                                              float* __restrict__ st5) {
  __shared__ float bs[512];
  int t = threadIdx.x, row = blockIdx.x, b = blockIdx.y;
  int cg = t & 31, pg = t >> 5;
  int wof0 = (cg >> 4) * 128 + ((((cg & 15) & 3) << 2) | ((cg & 15) >> 2)) * 8;
  const float2* msb = ms + b * 256;
  float2 m0[8];
#pragma unroll
  for (int e = 0; e < 8; ++e) m0[e] = msb[cg * 8 + e];
  const unsigned short* rp = y4 + ((size_t)b * 16384 + row * 128) * 256;
  unsigned char* op = xq8 + ((size_t)b * 16384 + (size_t)row * 128) * 256;
  float s[8] = {0, 0, 0, 0, 0, 0, 0, 0}, d[8] = {0, 0, 0, 0, 0, 0, 0, 0};
  for (int i = 0; i < 16; ++i) {
    int px = pg * 16 + i;
    u16x8 v = *(const u16x8*)(rp + (size_t)px * 256 + cg * 8);
    float f[8];
#pragma unroll
    for (int e = 0; e < 8; ++e) {
      float x = (bfu2f(v[e]) - m0[e].x) * m0[e].y;
      f[e] = x >= 0.f ? x : 0.2f * x;
    }
    int lo = cvtpk8<false>(f[0], f[1], 0); lo = cvtpk8<true>(f[2], f[3], lo);
    int hi = cvtpk8<false>(f[4], f[5], 0); hi = cvtpk8<true>(f[6], f[7], hi);
    *(long*)(op + (size_t)px * 256 + wof0) =
        ((long)(unsigned)hi << 32) | (unsigned)lo;
    float fq;
    fq = cvtf8<0>(lo); s[0] += fq; d[0] += fq - f[0];
    fq = cvtf8<1>(lo); s[1] += fq; d[1] += fq - f[1];
    fq = cvtf8<2>(lo); s[2] += fq; d[2] += fq - f[2];
    fq = cvtf8<3>(lo); s[3] += fq; d[3] += fq - f[3];
    fq = cvtf8<0>(hi); s[4] += fq; d[4] += fq - f[4];
    fq = cvtf8<1>(hi); s[5] += fq; d[5] += fq - f[5];
    fq = cvtf8<2>(hi); s[6] += fq; d[6] += fq - f[6];
    fq = cvtf8<3>(hi); s[7] += fq; d[7] += fq - f[7];
  }
  for (int i = t; i < 512; i += 256) bs[i] = 0.f;
  __syncthreads();
#pragma unroll
  for (int e = 0; e < 8; ++e) {
    atomicAdd(&bs[cg * 8 + e], s[e]);
    atomicAdd(&bs[256 + cg * 8 + e], d[e]);
  }
  __syncthreads();
  for (int i = t; i < 512; i += 256) atomicAdd(&st5[b * 512 + i], bs[i]);
}

// ---------------- cbias: c[b][oc] = sum_ic( muq*dws + dmu*wsum ) ----------------
__global__ __launch_bounds__(256) void cbias_k(const float* __restrict__ st5,
                                               const float* __restrict__ dws,
                                               const float* __restrict__ wsum,
                                               float* __restrict__ cb) {
  int oc = blockIdx.x, b = blockIdx.y, t = threadIdx.x;
  const float inv = 1.f / 16384.f;
  float muq = st5[b * 512 + t] * inv;
  float dmu = st5[b * 512 + 256 + t] * inv;
  float a = muq * dws[oc * 256 + t] + dmu * wsum[oc * 256 + t];
#pragma unroll
  for (int o = 1; o < 64; o <<= 1) a += __shfl_xor(a, o);
  __shared__ float r[4];
  if ((t & 63) == 0) r[t >> 6] = a;
  __syncthreads();
  if (t == 0) cb[b * 512 + oc] = r[0] + r[1] + r[2] + r[3];
}

// ---------------- conv2 MFMA (double-buffered): x1 -> x2 + stats ----------------
__global__ __launch_bounds__(256) void conv2_k(const unsigned short* __restrict__ x1,
                                               const unsigned short* __restrict__ wb2,
                                               unsigned short* __restrict__ x2,
                                               float* __restrict__ st2) {
  __shared__ char smem[49664];
  float* bins = (float*)(smem + 49152);
  int tid = threadIdx.x, y = blockIdx.x, b = blockIdx.y;
  int lane = tid & 63, w = tid >> 6, wm = w >> 1, wn = w & 1;
  int lr = lane & 15, lg = lane >> 4;
  f32x4 acc[4][2];
#pragma unroll
  for (int i = 0; i < 4; ++i)
#pragma unroll
    for (int j = 0; j < 2; ++j) acc[i][j] = (f32x4){0.f, 0.f, 0.f, 0.f};

  int rowA[4], lcA[4], PbA[4];
#pragma unroll
  for (int i = 0; i < 4; ++i) {
    int pb = i * 256 + tid;
    PbA[i] = pb * 16; rowA[i] = pb >> 3; lcA[i] = (pb & 7) ^ (rowA[i] & 7);
  }
  int rowB[2], lcB[2], PbB[2];
#pragma unroll
  for (int i = 0; i < 2; ++i) {
    int pb = i * 256 + tid;
    PbB[i] = pb * 16; rowB[i] = pb >> 3; lcB[i] = (pb & 7) ^ (rowB[i] & 7);
  }
  const unsigned short* xb = x1 + (size_t)b * 2130048;

  auto stage = [&](int kb, char* base) {
    char* As = base;
    char* Bs = base + 16384;
#pragma unroll
    for (int i = 0; i < 4; ++i) {
      int tp = kb * 2 + (lcA[i] >> 2);
      int ky = (tp * 11) >> 5;
      int kx = tp - ky * 3;
      gload_lds16(xb + ((size_t)((2 * y + ky) * 258 + 2 * rowA[i] + kx)) * 32 + (lcA[i] & 3) * 8,
                  As + PbA[i]);
    }
#pragma unroll
    for (int i = 0; i < 2; ++i)
      gload_lds16(wb2 + rowB[i] * 320 + kb * 64 + lcB[i] * 8, Bs + PbB[i]);
  };

  stage(0, smem);
  __syncthreads();
  for (int kb = 0; kb < 5; ++kb) {
    char* base = smem + (kb & 1) * 24576;
    if (kb + 1 < 5) stage(kb + 1, smem + ((kb + 1) & 1) * 24576);
    char* As = base;
    char* Bs = base + 16384;
    bf16x8 af[4][2], bfr[2][2];
#pragma unroll
    for (int mi = 0; mi < 4; ++mi)
#pragma unroll
      for (int kh = 0; kh < 2; ++kh) {
        int row = wm * 64 + mi * 16 + lr;
        int byte = row * 128 + ((kh * 64 + lg * 16) ^ ((row & 7) << 4));
        af[mi][kh] = *(const bf16x8*)(As + byte);
      }
#pragma unroll
    for (int ni = 0; ni < 2; ++ni)
#pragma unroll
      for (int kh = 0; kh < 2; ++kh) {
        int row = wn * 32 + ni * 16 + lr;
        int byte = row * 128 + ((kh * 64 + lg * 16) ^ ((row & 7) << 4));
        bfr[ni][kh] = *(const bf16x8*)(Bs + byte);
      }
#pragma unroll
    for (int mi = 0; mi < 4; ++mi)
#pragma unroll
      for (int ni = 0; ni < 2; ++ni)
#pragma unroll
        for (int kh = 0; kh < 2; ++kh)
          acc[mi][ni] = __builtin_amdgcn_mfma_f32_16x16x32_bf16(af[mi][kh], bfr[ni][kh],
                                                                acc[mi][ni], 0, 0, 0);
    __syncthreads();
  }

  if (tid < 128) bins[tid] = 0.f;
  __syncthreads();
  unsigned short* ob = x2 + (size_t)b * 1081600;
#pragma unroll
  for (int ni = 0; ni < 2; ++ni) {
    int oc = wn * 32 + ni * 16 + lr;
    float s = 0.f, q = 0.f;
#pragma unroll
    for (int mi = 0; mi < 4; ++mi)
#pragma unroll
      for (int r = 0; r < 4; ++r) {
        int m = wm * 64 + mi * 16 + lg * 4 + r;
        float v = acc[mi][ni][r];
        ob[((y + 1) * 130 + m + 1) * 64 + oc] = f2bfu(v);
        s += v; q += v * v;
      }
    atomicAdd(&bins[oc * 2], s);
    atomicAdd(&bins[oc * 2 + 1], q);
  }
  __syncthreads();
  if (tid < 128) atomicAdd(&st2[b * 128 + tid], bins[tid]);
}

// ---------------- conv3 MFMA (double-buffered): x2 -> x3 + stats ----------------
__global__ __launch_bounds__(256) void conv3_k(const unsigned short* __restrict__ x2,
                                               const unsigned short* __restrict__ wb3,
                                               unsigned short* __restrict__ x3,
                                               float* __restrict__ st3) {
  __shared__ char smem[66560];
  float* bins = (float*)(smem + 65536);
  int tid = threadIdx.x, y0 = blockIdx.x * 2, b = blockIdx.y;
  int lane = tid & 63, w = tid >> 6, wm = w >> 1, wn = w & 1;
  int lr = lane & 15, lg = lane >> 4;
  f32x4 acc[4][4];
#pragma unroll
  for (int i = 0; i < 4; ++i)
#pragma unroll
    for (int j = 0; j < 4; ++j) acc[i][j] = (f32x4){0.f, 0.f, 0.f, 0.f};

  int rowS[4], lc[4], Pb[4];
#pragma unroll
  for (int i = 0; i < 4; ++i) {
    int pb = i * 256 + tid;
    Pb[i] = pb * 16; rowS[i] = pb >> 3; lc[i] = (pb & 7) ^ (rowS[i] & 7);
  }
  const unsigned short* xb = x2 + (size_t)b * 1081600;

  auto stage = [&](int kk, char* base) {
    int ky = kk / 3, kx = kk - ky * 3;
#pragma unroll
    for (int i = 0; i < 4; ++i) {
      int m = rowS[i], di = m >> 6, xx = m & 63;
      gload_lds16(xb + ((size_t)((2 * (y0 + di) + ky) * 130 + 2 * xx + kx)) * 64 + lc[i] * 8,
                  base + Pb[i]);
    }
#pragma unroll
    for (int i = 0; i < 4; ++i)
      gload_lds16(wb3 + (rowS[i] * 9 + kk) * 64 + lc[i] * 8, base + 16384 + Pb[i]);
  };

  stage(0, smem);
  __syncthreads();
  for (int kk = 0; kk < 9; ++kk) {
    char* base = smem + (kk & 1) * 32768;
    if (kk + 1 < 9) stage(kk + 1, smem + ((kk + 1) & 1) * 32768);
    char* As = base;
    char* Bs = base + 16384;
    bf16x8 af[4][2], bfr[4][2];
#pragma unroll
    for (int mi = 0; mi < 4; ++mi)
#pragma unroll
      for (int kh = 0; kh < 2; ++kh) {
        int row = wm * 64 + mi * 16 + lr;
        int byte = row * 128 + ((kh * 64 + lg * 16) ^ ((row & 7) << 4));
        af[mi][kh] = *(const bf16x8*)(As + byte);
      }
#pragma unroll
    for (int ni = 0; ni < 4; ++ni)
#pragma unroll
      for (int kh = 0; kh < 2; ++kh) {
        int row = wn * 64 + ni * 16 + lr;
        int byte = row * 128 + ((kh * 64 + lg * 16) ^ ((row & 7) << 4));
        bfr[ni][kh] = *(const bf16x8*)(Bs + byte);
      }
#pragma unroll
    for (int mi = 0; mi < 4; ++mi)
#pragma unroll
      for (int ni = 0; ni < 4; ++ni)
#pragma unroll
        for (int kh = 0; kh < 2; ++kh)
          acc[mi][ni] = __builtin_amdgcn_mfma_f32_16x16x32_bf16(af[mi][kh], bfr[ni][kh],
                                                                acc[mi][ni], 0, 0, 0);
    __syncthreads();
  }

  if (tid < 256) bins[tid] = 0.f;
  __syncthreads();
  unsigned short* ob = x3 + (size_t)b * 540800;
#pragma unroll
  for (int ni = 0; ni < 4; ++ni) {
    int oc = wn * 64 + ni * 16 + lr;
    float s = 0.f, q = 0.f;
#pragma unroll
    for (int mi = 0; mi < 4; ++mi)
#pragma unroll
      for (int r = 0; r < 4; ++r) {
        int m = wm * 64 + mi * 16 + lg * 4 + r;
        int di = m >> 6, xx = m & 63;
        float v = acc[mi][ni][r];
        ob[((y0 + di) * 65 + xx) * 128 + oc] = f2bfu(v);
        s += v; q += v * v;
      }
    atomicAdd(&bins[oc * 2], s);
    atomicAdd(&bins[oc * 2 + 1], q);
  }
  __syncthreads();
  if (tid < 256) atomicAdd(&st3[b * 256 + tid], bins[tid]);
}

// ---------------- convT MFMA (counted-vmcnt pipeline): x3 -> y4 + stats ----------------
__global__ __launch_bounds__(256) void convT_k(const unsigned short* __restrict__ x3,
                                               const unsigned short* __restrict__ wbt,
                                               unsigned short* __restrict__ y4,
                                               float* __restrict__ st4) {
  __shared__ char smem[67584];
  float* bins = (float*)(smem + 65536);
  int tid = threadIdx.x, i0 = blockIdx.x * 2, nblk = blockIdx.y, b = blockIdx.z;
  int n0 = nblk * 128, cl = nblk >> 1, och0 = (nblk & 1) * 128;
  int lane = tid & 63, w = tid >> 6, wm = w >> 1, wn = w & 1;
  int lr = lane & 15, lg = lane >> 4;
  f32x4 acc[4][4];
#pragma unroll
  for (int i = 0; i < 4; ++i)
#pragma unroll
    for (int j = 0; j < 4; ++j) acc[i][j] = (f32x4){0.f, 0.f, 0.f, 0.f};

  int rowS[4], lc[4], Pb[4];
#pragma unroll
  for (int i = 0; i < 4; ++i) {
    int pb = i * 256 + tid;
    Pb[i] = pb * 16; rowS[i] = pb >> 3; lc[i] = (pb & 7) ^ (rowS[i] & 7);
  }
  int aoff[4][2], boff[4][2];
#pragma unroll
  for (int mi = 0; mi < 4; ++mi)
#pragma unroll
    for (int kh = 0; kh < 2; ++kh) {
      int row = wm * 64 + mi * 16 + lr;
      aoff[mi][kh] = row * 128 + ((kh * 64 + lg * 16) ^ ((row & 7) << 4));
      int rowb = wn * 64 + mi * 16 + lr;
      boff[mi][kh] = rowb * 128 + ((kh * 64 + lg * 16) ^ ((rowb & 7) << 4));
    }
  const unsigned short* xb = x3 + (size_t)b * 540800;

  auto stage = [&](int kb, char* base) {
    int nb = kb >> 1, chalf = (kb & 1) * 64;
#pragma unroll
    for (int i = 0; i < 4; ++i) {
      int m = rowS[i], di = m >> 6, j = m & 63;
      int pi = i0 + di + (nb >> 1), pj = j + (nb & 1);
      gload_lds16(xb + ((size_t)(pi * 65 + pj)) * 128 + chalf + lc[i] * 8, base + Pb[i]);
    }
#pragma unroll
    for (int i = 0; i < 4; ++i)
      gload_lds16(wbt + (size_t)(n0 + rowS[i]) * 512 + kb * 64 + lc[i] * 8,
                  base + 16384 + Pb[i]);
  };

  auto mmaStep = [&](char* As, char* Bs) {
    bf16x8 af[4][2], bfr[4][2];
#pragma unroll
    for (int mi = 0; mi < 4; ++mi)
#pragma unroll
      for (int kh = 0; kh < 2; ++kh) af[mi][kh] = *(const bf16x8*)(As + aoff[mi][kh]);
#pragma unroll
    for (int ni = 0; ni < 4; ++ni)
#pragma unroll
      for (int kh = 0; kh < 2; ++kh) bfr[ni][kh] = *(const bf16x8*)(Bs + boff[ni][kh]);
#pragma unroll
    for (int mi = 0; mi < 4; ++mi)
#pragma unroll
      for (int ni = 0; ni < 4; ++ni)
#pragma unroll
        for (int kh = 0; kh < 2; ++kh)
          acc[mi][ni] = __builtin_amdgcn_mfma_f32_16x16x32_bf16(af[mi][kh], bfr[ni][kh],
                                                                acc[mi][ni], 0, 0, 0);
  };

  char* B0 = smem;
  char* B1 = smem + 32768;
  stage(0, B0);
  stage(1, B1);
  for (int sp = 0; sp < 3; ++sp) {
    PIPE_STEP(8, B0, true, 2 * sp + 2);
    PIPE_STEP(8, B1, true, 2 * sp + 3);
  }
  PIPE_STEP(8, B0, false, 0);
  PIPE_STEP(0, B1, false, 0);

  if (tid < 256) bins[tid] = 0.f;
  __syncthreads();
  unsigned short* ob = y4 + (size_t)b * 4194304;
  int dy = cl >> 1, dx = cl & 1;
#pragma unroll
  for (int ni = 0; ni < 4; ++ni) {
    int loc = wn * 64 + ni * 16 + lr;
    int oc = och0 + loc;
    float s = 0.f, q = 0.f;
#pragma unroll
    for (int mi = 0; mi < 4; ++mi)
#pragma unroll
      for (int r = 0; r < 4; ++r) {
        int m = wm * 64 + mi * 16 + lg * 4 + r;
        int di = m >> 6, j = m & 63;
        int oy = 2 * (i0 + di) + dy, ox = 2 * j + dx;
        float v = acc[mi][ni][r];
        ob[(oy * 128 + ox) * 256 + oc] = f2bfu(v);
        s += v; q += v * v;
      }
    atomicAdd(&bins[loc * 2], s);
    atomicAdd(&bins[loc * 2 + 1], q);
  }
  __syncthreads();
  if (tid < 256) atomicAdd(&st4[b * 512 + och0 * 2 + tid], bins[tid]);
}

// ---------------- conv4: fp8 implicit GEMM, 128x128 tile, BK=128, XCD-swizzled ----------
// A/B LDS tiles [128 rows][128 B fp8], k-permuted layout -> lane lg's four 8B k-fragments
// are contiguous 32B: frag reads are two ds_read_b128 per row (conflict-free class).
__global__ __launch_bounds__(256, 3) void conv4_k(
    const unsigned char* __restrict__ xq8, const unsigned char* __restrict__ wb8,
    const float* __restrict__ b4, const float* __restrict__ cb,
    const int* __restrict__ lab, float* __restrict__ sums) {
  __shared__ char smem[33280];  // As 16K | Bs 16K | labs 512B
  char* As = smem;
  char* Bs = smem + 16384;
  int* labs = (int*)(smem + 32768);
  int tid = threadIdx.x;
  int id = blockIdx.x;
  int b = id & 7, rr = id >> 3;
  int y = rr >> 2, nblk = rr & 3;
  int n0 = nblk * 128;
  if (tid < 128) labs[tid] = lab[b * 16384 + y * 128 + tid];
  int lane = tid & 63, w = tid >> 6;
  int wm = w >> 1, wn = w & 1;
  int lr = lane & 15, lg = lane >> 4;

  f32x4 acc[4][4];
#pragma unroll
  for (int i = 0; i < 4; ++i)
#pragma unroll
    for (int j = 0; j < 4; ++j) acc[i][j] = (f32x4){0.f, 0.f, 0.f, 0.f};

  const unsigned char* xb = xq8 + (size_t)b * 4194304;

  int rs0 = tid >> 3;
  int csw = ((tid & 7) ^ (rs0 & 7)) << 4;  // byte offset of 16B chunk within 128B row
  int ldoff = tid * 16;                    // + i*4096

  const unsigned char* brow[4];
#pragma unroll
  for (int i = 0; i < 4; ++i)
    brow[i] = wb8 + (size_t)(n0 + rs0 + 32 * i) * 2304 + csw;

  int koff = 0;  // kk*256 + ic0 = step*128
  for (int kk = 0; kk < 9; ++kk) {
    int ky = (kk * 11) >> 5, kx = kk - ky * 3;
    int sy = y + ky - 1; sy = sy < 0 ? 1 : (sy > 127 ? 126 : sy);
    const unsigned char* arow[4];
#pragma unroll
    for (int i = 0; i < 4; ++i) {
      int sx = rs0 + 32 * i + kx - 1;
      sx = sx < 0 ? 1 : (sx > 127 ? 126 : sx);
      arow[i] = xb + ((size_t)(sy * 128 + sx)) * 256 + csw;
    }
    for (int ic0 = 0; ic0 < 256; ic0 += 128) {
      __syncthreads();
#pragma unroll
      for (int i = 0; i < 4; ++i) gload_lds16(arow[i] + ic0, As + i * 4096 + ldoff);
#pragma unroll
      for (int i = 0; i < 4; ++i) gload_lds16(brow[i] + koff, Bs + i * 4096 + ldoff);
      koff += 128;
      __syncthreads();

      // b128 frag reads: col = (lg*32 + k2*16) ^ ((row&7)<<4) — conflict-free class
      longx2 bq[4][2];
#pragma unroll
      for (int ni = 0; ni < 4; ++ni) {
        int row = wn * 64 + ni * 16 + lr;
#pragma unroll
        for (int k2 = 0; k2 < 2; ++k2) {
          int byte = row * 128 + ((lg * 32 + k2 * 16) ^ ((row & 7) << 4));
          bq[ni][k2] = *(const longx2*)(Bs + byte);
        }
      }
#pragma unroll
      for (int mi = 0; mi < 4; ++mi) {
        int row = wm * 64 + mi * 16 + lr;
        longx2 aq[2];
#pragma unroll
        for (int k2 = 0; k2 < 2; ++k2) {
          int byte = row * 128 + ((lg * 32 + k2 * 16) ^ ((row & 7) << 4));
          aq[k2] = *(const longx2*)(As + byte);
        }
#pragma unroll
        for (int ni = 0; ni < 4; ++ni)
#pragma unroll
          for (int k2 = 0; k2 < 2; ++k2) {
            acc[mi][ni] = __builtin_amdgcn_mfma_f32_16x16x32_fp8_fp8(
                aq[k2][0], bq[ni][k2][0], acc[mi][ni], 0, 0, 0);
            acc[mi][ni] = __builtin_amdgcn_mfma_f32_16x16x32_fp8_fp8(
                aq[k2][1], bq[ni][k2][1], acc[mi][ni], 0, 0, 0);
          }
      }
    }
  }

  // epilogue: (bias - fp8 bias-correction) + tanh + per-label bins
  __syncthreads();
  float* bins = (float*)smem;  // [19][128]
  for (int t2 = tid; t2 < 19 * 128; t2 += 256) bins[t2] = 0.f;
  __syncthreads();
  float bias[4];
#pragma unroll
  for (int ni = 0; ni < 4; ++ni) {
    int gc = n0 + wn * 64 + ni * 16 + lr;
    bias[ni] = b4[gc] - cb[b * 512 + gc];
  }
#pragma unroll
  for (int mi = 0; mi < 4; ++mi)
#pragma unroll
    for (int ni = 0; ni < 4; ++ni) {
      int ct = wn * 64 + ni * 16 + lr;
#pragma unroll
      for (int r = 0; r < 4; ++r) {
        int x = wm * 64 + mi * 16 + lg * 4 + r;
        float v = tanhf(acc[mi][ni][r] + bias[ni]);
        atomicAdd(&bins[labs[x] * 128 + ct], v);
      }
    }
  __syncthreads();
  for (int t2 = tid; t2 < 19 * 128; t2 += 256) {
    float v = bins[t2];
    if (v != 0.f)
      atomicAdd(&sums[((size_t)(b * 19 + (t2 >> 7))) * 512 + n0 + (t2 & 127)], v);
  }
}

// ---------------- finalize ----------------
__global__ void finalize_k(const float* __restrict__ sums, const float* __restrict__ counts,
                           float* __restrict__ out) {
  int idx = blockIdx.x * 256 + threadIdx.x;
  int bl = idx / 512;
  float c = counts[bl];
  out[idx] = c > 0.f ? sums[idx] / fmaxf(c, 1.f) : 0.f;
}

extern "C" void kernel_launch(void* const* d_in, const int* in_sizes, int n_in,
                              void* d_out, int out_size, void* d_ws, size_t ws_size,
                              hipStream_t stream) {
  const float* image = (const float*)d_in[0];
  const float* seg   = (const float*)d_in[1];
  const float* w1    = (const float*)d_in[2];
  const float* w2    = (const float*)d_in[4];
  const float* w3    = (const float*)d_in[6];
  const float* wt    = (const float*)d_in[8];
  const float* w4    = (const float*)d_in[10];
  const float* b4    = (const float*)d_in[11];
  float* out = (float*)d_out;
  char* ws = (char*)d_ws;

  unsigned short* x1  = (unsigned short*)(ws + OFF_X1);
  unsigned char*  xq8 = (unsigned char*)(ws + OFF_XQ8);
  unsigned short* x2  = (unsigned short*)(ws + OFF_X2);
  unsigned short* x3  = (unsigned short*)(ws + OFF_X3);
  unsigned short* y4  = (unsigned short*)(ws + OFF_Y4);
  unsigned char*  wb8 = (unsigned char*)(ws + OFF_WB8);
  unsigned short* wb2 = (unsigned short*)(ws + OFF_WB2);
  unsigned short* wb3 = (unsigned short*)(ws + OFF_WB3);
  unsigned short* wbt = (unsigned short*)(ws + OFF_WBT);
  float* st1 = (float*)(ws + OFF_ST1);
  float* st2 = (float*)(ws + OFF_ST2);
  float* st3 = (float*)(ws + OFF_ST3);
  float* st4 = (float*)(ws + OFF_ST4);
  float* sums = (float*)(ws + OFF_SUMS);
  float* counts = (float*)(ws + OFF_CNT);
  float2* ms1 = (float2*)(ws + OFF_MS1);
  float2* ms2 = (float2*)(ws + OFF_MS2);
  float2* ms3 = (float2*)(ws + OFF_MS3);
  float2* ms4 = (float2*)(ws + OFF_MS4);
  int* lab = (int*)(ws + OFF_LAB);
  float* dws  = (float*)(ws + OFF_DWS);
  float* wsum = (float*)(ws + OFF_WSM);
  float* st5  = (float*)(ws + OFF_ST5);
  float* cbv  = (float*)(ws + OFF_CB);

  // stat buffers zero + ALL independent prep in one launch
  hipMemsetAsync(ws + OFF_ST1, 0, 342624, stream);    // stats+sums+counts
  hipMemsetAsync(ws + OFF_ST5, 0, 16384, stream);     // fp8 channel sums
  prep_k<<<3764, 256, 0, stream>>>(w2, wb2, w3, wb3, wt, wbt, w4, wb8, dws, wsum,
                                   x1, x2, x3, seg, lab, counts);

  conv1_k<<<dim3(256, 8), 256, 0, stream>>>(image, w1, x1);
  statsn_k<32><<<dim3(16, 8), 256, 0, stream>>>(x1 + 259 * 32, 258 * 32, 10, 16, 2130048L, st1);
  msn_k<<<1, 256, 0, stream>>>(st1, ms1, 1.f / 65536.f, 256);
  nln_k<32><<<dim3(256, 8), 256, 0, stream>>>(x1 + 259 * 32, 258 * 32, 1024, 2130048L, ms1);

  conv2_k<<<dim3(128, 8), 256, 0, stream>>>(x1, wb2, x2, st2);
  msn_k<<<2, 256, 0, stream>>>(st2, ms2, 1.f / 16384.f, 512);
  nln_k<64><<<dim3(128, 8), 256, 0, stream>>>(x2 + 131 * 64, 130 * 64, 1024, 1081600L, ms2);

  conv3_k<<<dim3(32, 8), 256, 0, stream>>>(x2, wb3, x3, st3);
  msn_k<<<4, 256, 0, stream>>>(st3, ms3, 1.f / 4096.f, 1024);
  nln_k<128><<<dim3(64, 8), 256, 0, stream>>>(x3, 65 * 128, 1024, 540800L, ms3);

  convT_k<<<dim3(32, 8, 8), 256, 0, stream>>>(x3, wbt, y4, st4);
  msn_k<<<8, 256, 0, stream>>>(st4, ms4, 1.f / 16384.f, 2048);

  // y4 -> norm+lrelu -> fp8 (xq8, k-permuted) + channel sums; then bias correction
  nln8_k<<<dim3(128, 8), 256, 0, stream>>>(y4, ms4, xq8, st5);
  cbias_k<<<dim3(512, 8), 256, 0, stream>>>(st5, dws, wsum, cbv);

  conv4_k<<<4096, 256, 0, stream>>>(xq8, wb8, b4, cbv, lab, sums);

  finalize_k<<<304, 256, 0, stream>>>(sums, counts, out);
}

// Round 18
// 696.652 us; speedup vs baseline: 1.2727x; 1.0348x over previous
//
#include <hip/hip_runtime.h>
#include <hip/hip_bf16.h>
#include <math.h>

typedef __attribute__((ext_vector_type(8))) short bf16x8;
typedef __attribute__((ext_vector_type(8))) unsigned short u16x8;
typedef __attribute__((ext_vector_type(4))) float f32x4;
typedef __attribute__((ext_vector_type(2))) long longx2;

// ---------------- workspace layout (bytes) ----------------
#define OFF_X1   0ull           // x1 [8,258,258,32] bf16; DEAD after conv2 -> reused as xq8
#define OFF_XQ8  0ull           // xq8 [8,128,128,256] fp8 (33.5 MB), k-permuted per 128-half
#define OFF_X2   34080768ull
#define OFF_X3   51386368ull
#define OFF_Y4   60039168ull
#define OFF_WB8  127148032ull   // wb8 [512,9,256] fp8 (1.18 MB), k-permuted per 128-half
#define OFF_WB2  129507328ull
#define OFF_WB3  129548288ull
#define OFF_WBT  129695744ull
#define OFF_ST1  130744320ull
#define OFF_ST2  130746368ull
#define OFF_ST3  130750464ull
#define OFF_ST4  130758656ull
#define OFF_SUMS 130775040ull
#define OFF_CNT  131086336ull
#define OFF_LAB  131117664ull
#define OFF_DWS  131641952ull   // dws  [512][256] f32 (512 KB)
#define OFF_WSM  132166240ull   // wsum [512][256] f32 (512 KB)
#define OFF_ST5  132690528ull   // st5  [8][2][256] f32 (16 KB, zeroed)
#define OFF_CB   132706912ull   // cb   [8][512] f32 (16 KB)

__device__ __forceinline__ float bfu2f(unsigned short u) {
  return __builtin_bit_cast(float, ((unsigned)u) << 16);
}
__device__ __forceinline__ unsigned short f2bfu(float f) {
  __hip_bfloat16 h = __float2bfloat16(f);
  return __builtin_bit_cast(unsigned short, h);
}
__device__ __forceinline__ void gload_lds16(const void* g, void* l) {
  __builtin_amdgcn_global_load_lds(
      (const __attribute__((address_space(1))) unsigned int*)g,
      (__attribute__((address_space(3))) unsigned int*)l, 16, 0, 0);
}
template <bool HI>
__device__ __forceinline__ int cvtpk8(float a, float b, int old) {
  return __builtin_amdgcn_cvt_pk_fp8_f32(a, b, old, HI);
}
template <int SEL>
__device__ __forceinline__ float cvtf8(int v) {
  return __builtin_amdgcn_cvt_f32_fp8(v, SEL);
}

#define WAITV(N) asm volatile("s_waitcnt vmcnt(" #N ")" ::: "memory")

// counted-vmcnt pipelined step (2-phase, used by convT)
#define PIPE_STEP(WAITN, BUF, DOSTAGE, SNEXT)                 \
  asm volatile("s_waitcnt vmcnt(" #WAITN ")" ::: "memory");   \
  __builtin_amdgcn_s_barrier();                               \
  __builtin_amdgcn_sched_barrier(0);                          \
  mmaStep(BUF, (BUF) + 16384);                                \
  __builtin_amdgcn_sched_barrier(0);                          \
  __builtin_amdgcn_s_barrier();                               \
  if (DOSTAGE) stage(SNEXT, BUF);

__device__ const int c_taptab[16] = {4, -1, -1, -1, 5, 3, -1, -1, 7, -1, 1, -1, 8, 6, 2, 0};

// ---------------- prep: wrep2 | wrep3 | wrepT | dwrep | padz | lab in ONE launch ----------
// block ranges: [0,80) wrep2, [80,368) wrep3, [368,2416) wrepT, [2416,2928) dwrep,
//               [2928,3252) padz, [3252,3764) lab
__global__ __launch_bounds__(256) void prep_k(
    const float* __restrict__ w2, unsigned short* __restrict__ wb2,
    const float* __restrict__ w3, unsigned short* __restrict__ wb3,
    const float* __restrict__ wt, unsigned short* __restrict__ wbt,
    const float* __restrict__ w4, unsigned char* __restrict__ wb8,
    float* __restrict__ dws, float* __restrict__ wsum,
    unsigned short* __restrict__ x1, unsigned short* __restrict__ x2,
    unsigned short* __restrict__ x3,
    const float* __restrict__ seg, int* __restrict__ lab, float* __restrict__ counts) {
  __shared__ int hist[19];
  int blk = blockIdx.x, t = threadIdx.x;
  if (blk < 80) {
    int idx = blk * 256 + t;
    if (idx < 20480) {
      int oc = idx / 320, r = idx % 320, tap = r >> 5, ic = r & 31;
      wb2[idx] = tap < 9 ? f2bfu(w2[(oc * 32 + ic) * 9 + tap]) : (unsigned short)0;
    }
  } else if (blk < 368) {
    int idx = (blk - 80) * 256 + t;
    int oc = idx / 576, r = idx % 576, tap = r >> 6, ic = r & 63;
    wb3[idx] = f2bfu(w3[(oc * 64 + ic) * 9 + tap]);
  } else if (blk < 2416) {
    int idx = (blk - 368) * 256 + t;
    int n = idx >> 9, k = idx & 511;
    int cl = n >> 8, oc = n & 255, nb = k >> 7, ic = k & 127;
    int tap = c_taptab[cl * 4 + nb];
    wbt[idx] = tap < 0 ? (unsigned short)0 : f2bfu(wt[(ic * 256 + oc) * 9 + tap]);
  } else if (blk < 2928) {
    int oc = blk - 2416, ic = t;
    int local = ic & 127;
    int p = (ic & 128) + ((local >> 3) & 3) * 32 + ((local >> 5) & 3) * 8 + (local & 7);
    float ds = 0.f, ws = 0.f;
    for (int kk = 0; kk < 9; ++kk) {
      float w = w4[(size_t)oc * 2304 + ic * 9 + kk];
      int pk = cvtpk8<false>(w, 0.f, 0);
      wb8[((size_t)oc * 9 + kk) * 256 + p] = (unsigned char)(pk & 0xff);
      float wq = cvtf8<0>(pk);
      ds += wq - w; ws += w;
    }
    dws[oc * 256 + ic] = ds;
    wsum[oc * 256 + ic] = ws;
  } else if (blk < 3252) {
    int u = (blk - 2928) * 256 + t;  // < 82944
    int b = u / 10368, r = u % 10368;
    u16x8 z = {0, 0, 0, 0, 0, 0, 0, 0};
    if (r < 4128) {
      unsigned short* base = x1 + (size_t)b * 2130048;
      if (r < 2064) {
        int row = r < 1032 ? 0 : 257, pos = r < 1032 ? r : r - 1032;
        base += (row * 258 + (pos >> 2)) * 32 + (pos & 3) * 8;
      } else {
        int rc = r - 2064;
        int col = rc < 1032 ? 0 : 257, pos = rc < 1032 ? rc : rc - 1032;
        base += ((pos >> 2) * 258 + col) * 32 + (pos & 3) * 8;
      }
      *(u16x8*)base = z;
    } else if (r < 8288) {
      int s = r - 4128;
      unsigned short* base = x2 + (size_t)b * 1081600;
      if (s < 2080) {
        int row = s < 1040 ? 0 : 129, pos = s < 1040 ? s : s - 1040;
        base += (row * 130 + (pos >> 3)) * 64 + (pos & 7) * 8;
      } else {
        int sc = s - 2080;
        int col = sc < 1040 ? 0 : 129, pos = sc < 1040 ? sc : sc - 1040;
        base += ((pos >> 3) * 130 + col) * 64 + (pos & 7) * 8;
      }
      *(u16x8*)base = z;
    } else {
      int tt = r - 8288;
      unsigned short* base = x3 + (size_t)b * 540800;
      if (tt < 1040) {
        base += (64 * 65 + (tt >> 4)) * 128 + (tt & 15) * 8;
      } else {
        int pos = tt - 1040;
        base += ((pos >> 4) * 65 + 64) * 128 + (pos & 15) * 8;
      }
      *(u16x8*)base = z;
    }
  } else {
    int blk2 = blk - 3252;  // < 512
    int b = blk2 >> 6;
    int p = (blk2 & 63) * 256 + t;
    if (t < 19) hist[t] = 0;
    __syncthreads();
    int i = p >> 7, j = p & 127;
    const float* sp = seg + (size_t)b * 19 * 65536 + (2 * i) * 256 + 2 * j;
    int l = 0;
    for (int k = 0; k < 19; ++k) { if (sp[(size_t)k * 65536] != 0.f) { l = k; break; } }
    lab[b * 16384 + p] = l;
    atomicAdd(&hist[l], 1);
    __syncthreads();
    if (t < 19) atomicAdd(&counts[b * 19 + t], (float)hist[t]);
  }
}

// ---------------- conv1: reflect-pad 3->32 -> x1 NHWC padded bf16 + fused channel stats ----
__global__ __launch_bounds__(256) void conv1_k(const float* __restrict__ img,
                                               const float* __restrict__ w1,
                                               unsigned short* __restrict__ x1,
                                               float* __restrict__ st1) {
  __shared__ float wl[864];        // [k 27][oc 32]
  __shared__ float tile[256][33];  // padded: avoids 1056 % 32 == 0 bank alias
  __shared__ float cbins[64];
  int t = threadIdx.x, y = blockIdx.x, b = blockIdx.y;
  for (int i = t; i < 864; i += 256) wl[i] = w1[(i & 31) * 27 + (i >> 5)];
  if (t < 64) cbins[t] = 0.f;
  __syncthreads();
  int x = t;
  float val[27];
  for (int ic = 0; ic < 3; ++ic) {
    const float* ip = img + ((size_t)(b * 3 + ic)) * 65536;
#pragma unroll
    for (int ky = 0; ky < 3; ++ky) {
      int gy = y - 1 + ky; gy = gy < 0 ? -gy : (gy > 255 ? 510 - gy : gy);
#pragma unroll
      for (int kx = 0; kx < 3; ++kx) {
        int gx = x - 1 + kx; gx = gx < 0 ? -gx : (gx > 255 ? 510 - gx : gx);
        val[ic * 9 + ky * 3 + kx] = ip[gy * 256 + gx];
      }
    }
  }
  float a[32];
#pragma unroll
  for (int oc = 0; oc < 32; ++oc) a[oc] = 0.f;
#pragma unroll
  for (int k = 0; k < 27; ++k) {
    float vv = val[k];
#pragma unroll
    for (int oc = 0; oc < 32; ++oc) a[oc] += wl[k * 32 + oc] * vv;
  }
  unsigned short ov[32];
#pragma unroll
  for (int oc = 0; oc < 32; ++oc) ov[oc] = f2bfu(a[oc]);
  unsigned short* op = x1 + ((size_t)(b * 258 + y + 1) * 258 + (x + 1)) * 32;
#pragma unroll
  for (int i = 0; i < 4; ++i) *(u16x8*)(op + i * 8) = *(const u16x8*)(ov + i * 8);

  // fused stats: block-local column sums of the [256 px][32 ch] tile
#pragma unroll
  for (int oc = 0; oc < 32; ++oc) tile[t][oc] = a[oc];
  __syncthreads();
  int ch = t & 31, seg = t >> 5;
  float s = 0.f, q = 0.f;
  for (int r = 0; r < 32; ++r) {
    float v = tile[seg * 32 + ((r + seg) & 31)][ch];
    s += v; q += v * v;
  }
  atomicAdd(&cbins[ch * 2], s);
  atomicAdd(&cbins[ch * 2 + 1], q);
  __syncthreads();
  if (t < 64) atomicAdd(&st1[b * 64 + t], cbins[t]);
}

// ---------------- normalize + leaky-relu in place; (mean,rstd) computed inline from st ----
// each thread touches exactly one 8-channel group (256 % CH8 == 0 for all C used)
template <int C>
__global__ void nln_k(unsigned short* __restrict__ base, int rowStride, int unitsPerRow,
                      long bStride, const float* __restrict__ st, float invN) {
  const int CH8 = C / 8;
  int row = blockIdx.x, b = blockIdx.y;
  unsigned short* rp = base + (size_t)b * bStride + (size_t)row * rowStride;
  int ch = (threadIdx.x & (CH8 - 1)) * 8;
  const float* stb = st + b * C * 2;
  float2 m0[8];
#pragma unroll
  for (int e = 0; e < 8; ++e) {
    float m = stb[(ch + e) * 2] * invN;
    float v = stb[(ch + e) * 2 + 1] * invN - m * m;
    m0[e] = make_float2(m, rsqrtf(fmaxf(v, 0.f) + 1e-5f));
  }
  for (int idx = threadIdx.x; idx < unitsPerRow; idx += 256) {
    u16x8 v = *(u16x8*)(rp + idx * 8);
    u16x8 o;
#pragma unroll
    for (int e = 0; e < 8; ++e) {
      float f = (bfu2f(v[e]) - m0[e].x) * m0[e].y;
      o[e] = f2bfu(f >= 0.f ? f : 0.2f * f);
    }
    *(u16x8*)(rp + idx * 8) = o;
  }
}

// ---------------- nln8: y4 bf16 -> norm+lrelu -> fp8 xq8 (k-permuted) + channel sums ------
// (mean,rstd) computed inline from st4
__global__ __launch_bounds__(256) void nln8_k(const unsigned short* __restrict__ y4,
                                              const float* __restrict__ st4,
                                              unsigned char* __restrict__ xq8,
                                              float* __restrict__ st5) {
  __shared__ float bs[512];
  int t = threadIdx.x, row = blockIdx.x, b = blockIdx.y;
  int cg = t & 31, pg = t >> 5;
  int wof0 = (cg >> 4) * 128 + ((((cg & 15) & 3) << 2) | ((cg & 15) >> 2)) * 8;
  const float* stb = st4 + b * 512;
  const float invN = 1.f / 16384.f;
  float2 m0[8];
#pragma unroll
  for (int e = 0; e < 8; ++e) {
    float m = stb[(cg * 8 + e) * 2] * invN;
    float v = stb[(cg * 8 + e) * 2 + 1] * invN - m * m;
    m0[e] = make_float2(m, rsqrtf(fmaxf(v, 0.f) + 1e-5f));
  }
  const unsigned short* rp = y4 + ((size_t)b * 16384 + row * 128) * 256;
  unsigned char* op = xq8 + ((size_t)b * 16384 + (size_t)row * 128) * 256;
  float s[8] = {0, 0, 0, 0, 0, 0, 0, 0}, d[8] = {0, 0, 0, 0, 0, 0, 0, 0};
  for (int i = 0; i < 16; ++i) {
    int px = pg * 16 + i;
    u16x8 v = *(const u16x8*)(rp + (size_t)px * 256 + cg * 8);
    float f[8];
#pragma unroll
    for (int e = 0; e < 8; ++e) {
      float x = (bfu2f(v[e]) - m0[e].x) * m0[e].y;
      f[e] = x >= 0.f ? x : 0.2f * x;
    }
    int lo = cvtpk8<false>(f[0], f[1], 0); lo = cvtpk8<true>(f[2], f[3], lo);
    int hi = cvtpk8<false>(f[4], f[5], 0); hi = cvtpk8<true>(f[6], f[7], hi);
    *(long*)(op + (size_t)px * 256 + wof0) =
        ((long)(unsigned)hi << 32) | (unsigned)lo;
    float fq;
    fq = cvtf8<0>(lo); s[0] += fq; d[0] += fq - f[0];
    fq = cvtf8<1>(lo); s[1] += fq; d[1] += fq - f[1];
    fq = cvtf8<2>(lo); s[2] += fq; d[2] += fq - f[2];
    fq = cvtf8<3>(lo); s[3] += fq; d[3] += fq - f[3];
    fq = cvtf8<0>(hi); s[4] += fq; d[4] += fq - f[4];
    fq = cvtf8<1>(hi); s[5] += fq; d[5] += fq - f[5];
    fq = cvtf8<2>(hi); s[6] += fq; d[6] += fq - f[6];
    fq = cvtf8<3>(hi); s[7] += fq; d[7] += fq - f[7];
  }
  for (int i = t; i < 512; i += 256) bs[i] = 0.f;
  __syncthreads();
#pragma unroll
  for (int e = 0; e < 8; ++e) {
    atomicAdd(&bs[cg * 8 + e], s[e]);
    atomicAdd(&bs[256 + cg * 8 + e], d[e]);
  }
  __syncthreads();
  for (int i = t; i < 512; i += 256) atomicAdd(&st5[b * 512 + i], bs[i]);
}

// ---------------- cbias: c[b][oc] = sum_ic( muq*dws + dmu*wsum ) ----------------
__global__ __launch_bounds__(256) void cbias_k(const float* __restrict__ st5,
                                               const float* __restrict__ dws,
                                               const float* __restrict__ wsum,
                                               float* __restrict__ cb) {
  int oc = blockIdx.x, b = blockIdx.y, t = threadIdx.x;
  const float inv = 1.f / 16384.f;
  float muq = st5[b * 512 + t] * inv;
  float dmu = st5[b * 512 + 256 + t] * inv;
  float a = muq * dws[oc * 256 + t] + dmu * wsum[oc * 256 + t];
#pragma unroll
  for (int o = 1; o < 64; o <<= 1) a += __shfl_xor(a, o);
  __shared__ float r[4];
  if ((t & 63) == 0) r[t >> 6] = a;
  __syncthreads();
  if (t == 0) cb[b * 512 + oc] = r[0] + r[1] + r[2] + r[3];
}

// ---------------- conv2 MFMA (double-buffered): x1 -> x2 + stats ----------------
__global__ __launch_bounds__(256) void conv2_k(const unsigned short* __restrict__ x1,
                                               const unsigned short* __restrict__ wb2,
                                               unsigned short* __restrict__ x2,
                                               float* __restrict__ st2) {
  __shared__ char smem[49664];
  float* bins = (float*)(smem + 49152);
  int tid = threadIdx.x, y = blockIdx.x, b = blockIdx.y;
  int lane = tid & 63, w = tid >> 6, wm = w >> 1, wn = w & 1;
  int lr = lane & 15, lg = lane >> 4;
  f32x4 acc[4][2];
#pragma unroll
  for (int i = 0; i < 4; ++i)
#pragma unroll
    for (int j = 0; j < 2; ++j) acc[i][j] = (f32x4){0.f, 0.f, 0.f, 0.f};

  int rowA[4], lcA[4], PbA[4];
#pragma unroll
  for (int i = 0; i < 4; ++i) {
    int pb = i * 256 + tid;
    PbA[i] = pb * 16; rowA[i] = pb >> 3; lcA[i] = (pb & 7) ^ (rowA[i] & 7);
  }
  int rowB[2], lcB[2], PbB[2];
#pragma unroll
  for (int i = 0; i < 2; ++i) {
    int pb = i * 256 + tid;
    PbB[i] = pb * 16; rowB[i] = pb >> 3; lcB[i] = (pb & 7) ^ (rowB[i] & 7);
  }
  const unsigned short* xb = x1 + (size_t)b * 2130048;

  auto stage = [&](int kb, char* base) {
    char* As = base;
    char* Bs = base + 16384;
#pragma unroll
    for (int i = 0; i < 4; ++i) {
      int tp = kb * 2 + (lcA[i] >> 2);
      int ky = (tp * 11) >> 5;
      int kx = tp - ky * 3;
      gload_lds16(xb + ((size_t)((2 * y + ky) * 258 + 2 * rowA[i] + kx)) * 32 + (lcA[i] & 3) * 8,
                  As + PbA[i]);
    }
#pragma unroll
    for (int i = 0; i < 2; ++i)
      gload_lds16(wb2 + rowB[i] * 320 + kb * 64 + lcB[i] * 8, Bs + PbB[i]);
  };

  stage(0, smem);
  __syncthreads();
  for (int kb = 0; kb < 5; ++kb) {
    char* base = smem + (kb & 1) * 24576;
    if (kb + 1 < 5) stage(kb + 1, smem + ((kb + 1) & 1) * 24576);
    char* As = base;
    char* Bs = base + 16384;
    bf16x8 af[4][2], bfr[2][2];
#pragma unroll
    for (int mi = 0; mi < 4; ++mi)
#pragma unroll
      for (int kh = 0; kh < 2; ++kh) {
        int row = wm * 64 + mi * 16 + lr;
        int byte = row * 128 + ((kh * 64 + lg * 16) ^ ((row & 7) << 4));
        af[mi][kh] = *(const bf16x8*)(As + byte);
      }
#pragma unroll
    for (int ni = 0; ni < 2; ++ni)
#pragma unroll
      for (int kh = 0; kh < 2; ++kh) {
        int row = wn * 32 + ni * 16 + lr;
        int byte = row * 128 + ((kh * 64 + lg * 16) ^ ((row & 7) << 4));
        bfr[ni][kh] = *(const bf16x8*)(Bs + byte);
      }
#pragma unroll
    for (int mi = 0; mi < 4; ++mi)
#pragma unroll
      for (int ni = 0; ni < 2; ++ni)
#pragma unroll
        for (int kh = 0; kh < 2; ++kh)
          acc[mi][ni] = __builtin_amdgcn_mfma_f32_16x16x32_bf16(af[mi][kh], bfr[ni][kh],
                                                                acc[mi][ni], 0, 0, 0);
    __syncthreads();
  }

  if (tid < 128) bins[tid] = 0.f;
  __syncthreads();
  unsigned short* ob = x2 + (size_t)b * 1081600;
#pragma unroll
  for (int ni = 0; ni < 2; ++ni) {
    int oc = wn * 32 + ni * 16 + lr;
    float s = 0.f, q = 0.f;
#pragma unroll
    for (int mi = 0; mi < 4; ++mi)
#pragma unroll
      for (int r = 0; r < 4; ++r) {
        int m = wm * 64 + mi * 16 + lg * 4 + r;
        float v = acc[mi][ni][r];
        ob[((y + 1) * 130 + m + 1) * 64 + oc] = f2bfu(v);
        s += v; q += v * v;
      }
    atomicAdd(&bins[oc * 2], s);
    atomicAdd(&bins[oc * 2 + 1], q);
  }
  __syncthreads();
  if (tid < 128) atomicAdd(&st2[b * 128 + tid], bins[tid]);
}

// ---------------- conv3 MFMA (double-buffered): x2 -> x3 + stats ----------------
__global__ __launch_bounds__(256) void conv3_k(const unsigned short* __restrict__ x2,
                                               const unsigned short* __restrict__ wb3,
                                               unsigned short* __restrict__ x3,
                                               float* __restrict__ st3) {
  __shared__ char smem[66560];
  float* bins = (float*)(smem + 65536);
  int tid = threadIdx.x, y0 = blockIdx.x * 2, b = blockIdx.y;
  int lane = tid & 63, w = tid >> 6, wm = w >> 1, wn = w & 1;
  int lr = lane & 15, lg = lane >> 4;
  f32x4 acc[4][4];
#pragma unroll
  for (int i = 0; i < 4; ++i)
#pragma unroll
    for (int j = 0; j < 4; ++j) acc[i][j] = (f32x4){0.f, 0.f, 0.f, 0.f};

  int rowS[4], lc[4], Pb[4];
#pragma unroll
  for (int i = 0; i < 4; ++i) {
    int pb = i * 256 + tid;
    Pb[i] = pb * 16; rowS[i] = pb >> 3; lc[i] = (pb & 7) ^ (rowS[i] & 7);
  }
  const unsigned short* xb = x2 + (size_t)b * 1081600;

  auto stage = [&](int kk, char* base) {
    int ky = kk / 3, kx = kk - ky * 3;
#pragma unroll
    for (int i = 0; i < 4; ++i) {
      int m = rowS[i], di = m >> 6, xx = m & 63;
      gload_lds16(xb + ((size_t)((2 * (y0 + di) + ky) * 130 + 2 * xx + kx)) * 64 + lc[i] * 8,
                  base + Pb[i]);
    }
#pragma unroll
    for (int i = 0; i < 4; ++i)
      gload_lds16(wb3 + (rowS[i] * 9 + kk) * 64 + lc[i] * 8, base + 16384 + Pb[i]);
  };

  stage(0, smem);
  __syncthreads();
  for (int kk = 0; kk < 9; ++kk) {
    char* base = smem + (kk & 1) * 32768;
    if (kk + 1 < 9) stage(kk + 1, smem + ((kk + 1) & 1) * 32768);
    char* As = base;
    char* Bs = base + 16384;
    bf16x8 af[4][2], bfr[4][2];
#pragma unroll
    for (int mi = 0; mi < 4; ++mi)
#pragma unroll
      for (int kh = 0; kh < 2; ++kh) {
        int row = wm * 64 + mi * 16 + lr;
        int byte = row * 128 + ((kh * 64 + lg * 16) ^ ((row & 7) << 4));
        af[mi][kh] = *(const bf16x8*)(As + byte);
      }
#pragma unroll
    for (int ni = 0; ni < 4; ++ni)
#pragma unroll
      for (int kh = 0; kh < 2; ++kh) {
        int row = wn * 64 + ni * 16 + lr;
        int byte = row * 128 + ((kh * 64 + lg * 16) ^ ((row & 7) << 4));
        bfr[ni][kh] = *(const bf16x8*)(Bs + byte);
      }
#pragma unroll
    for (int mi = 0; mi < 4; ++mi)
#pragma unroll
      for (int ni = 0; ni < 4; ++ni)
#pragma unroll
        for (int kh = 0; kh < 2; ++kh)
          acc[mi][ni] = __builtin_amdgcn_mfma_f32_16x16x32_bf16(af[mi][kh], bfr[ni][kh],
                                                                acc[mi][ni], 0, 0, 0);
    __syncthreads();
  }

  if (tid < 256) bins[tid] = 0.f;
  __syncthreads();
  unsigned short* ob = x3 + (size_t)b * 540800;
#pragma unroll
  for (int ni = 0; ni < 4; ++ni) {
    int oc = wn * 64 + ni * 16 + lr;
    float s = 0.f, q = 0.f;
#pragma unroll
    for (int mi = 0; mi < 4; ++mi)
#pragma unroll
      for (int r = 0; r < 4; ++r) {
        int m = wm * 64 + mi * 16 + lg * 4 + r;
        int di = m >> 6, xx = m & 63;
        float v = acc[mi][ni][r];
        ob[((y0 + di) * 65 + xx) * 128 + oc] = f2bfu(v);
        s += v; q += v * v;
      }
    atomicAdd(&bins[oc * 2], s);
    atomicAdd(&bins[oc * 2 + 1], q);
  }
  __syncthreads();
  if (tid < 256) atomicAdd(&st3[b * 256 + tid], bins[tid]);
}

// ---------------- convT MFMA (counted-vmcnt pipeline): x3 -> y4 + stats ----------------
__global__ __launch_bounds__(256) void convT_k(const unsigned short* __restrict__ x3,
                                               const unsigned short* __restrict__ wbt,
                                               unsigned short* __restrict__ y4,
                                               float* __restrict__ st4) {
  __shared__ char smem[67584];
  float* bins = (float*)(smem + 65536);
  int tid = threadIdx.x, i0 = blockIdx.x * 2, nblk = blockIdx.y, b = blockIdx.z;
  int n0 = nblk * 128, cl = nblk >> 1, och0 = (nblk & 1) * 128;
  int lane = tid & 63, w = tid >> 6, wm = w >> 1, wn = w & 1;
  int lr = lane & 15, lg = lane >> 4;
  f32x4 acc[4][4];
#pragma unroll
  for (int i = 0; i < 4; ++i)
#pragma unroll
    for (int j = 0; j < 4; ++j) acc[i][j] = (f32x4){0.f, 0.f, 0.f, 0.f};

  int rowS[4], lc[4], Pb[4];
#pragma unroll
  for (int i = 0; i < 4; ++i) {
    int pb = i * 256 + tid;
    Pb[i] = pb * 16; rowS[i] = pb >> 3; lc[i] = (pb & 7) ^ (rowS[i] & 7);
  }
  int aoff[4][2], boff[4][2];
#pragma unroll
  for (int mi = 0; mi < 4; ++mi)
#pragma unroll
    for (int kh = 0; kh < 2; ++kh) {
      int row = wm * 64 + mi * 16 + lr;
      aoff[mi][kh] = row * 128 + ((kh * 64 + lg * 16) ^ ((row & 7) << 4));
      int rowb = wn * 64 + mi * 16 + lr;
      boff[mi][kh] = rowb * 128 + ((kh * 64 + lg * 16) ^ ((rowb & 7) << 4));
    }
  const unsigned short* xb = x3 + (size_t)b * 540800;

  auto stage = [&](int kb, char* base) {
    int nb = kb >> 1, chalf = (kb & 1) * 64;
#pragma unroll
    for (int i = 0; i < 4; ++i) {
      int m = rowS[i], di = m >> 6, j = m & 63;
      int pi = i0 + di + (nb >> 1), pj = j + (nb & 1);
      gload_lds16(xb + ((size_t)(pi * 65 + pj)) * 128 + chalf + lc[i] * 8, base + Pb[i]);
    }
#pragma unroll
    for (int i = 0; i < 4; ++i)
      gload_lds16(wbt + (size_t)(n0 + rowS[i]) * 512 + kb * 64 + lc[i] * 8,
                  base + 16384 + Pb[i]);
  };

  auto mmaStep = [&](char* As, char* Bs) {
    bf16x8 af[4][2], bfr[4][2];
#pragma unroll
    for (int mi = 0; mi < 4; ++mi)
#pragma unroll
      for (int kh = 0; kh < 2; ++kh) af[mi][kh] = *(const bf16x8*)(As + aoff[mi][kh]);
#pragma unroll
    for (int ni = 0; ni < 4; ++ni)
#pragma unroll
      for (int kh = 0; kh < 2; ++kh) bfr[ni][kh] = *(const bf16x8*)(Bs + boff[ni][kh]);
#pragma unroll
    for (int mi = 0; mi < 4; ++mi)
#pragma unroll
      for (int ni = 0; ni < 4; ++ni)
#pragma unroll
        for (int kh = 0; kh < 2; ++kh)
          acc[mi][ni] = __builtin_amdgcn_mfma_f32_16x16x32_bf16(af[mi][kh], bfr[ni][kh],
                                                                acc[mi][ni], 0, 0, 0);
  };

  char* B0 = smem;
  char* B1 = smem + 32768;
  stage(0, B0);
  stage(1, B1);
  for (int sp = 0; sp < 3; ++sp) {
    PIPE_STEP(8, B0, true, 2 * sp + 2);
    PIPE_STEP(8, B1, true, 2 * sp + 3);
  }
  PIPE_STEP(8, B0, false, 0);
  PIPE_STEP(0, B1, false, 0);

  if (tid < 256) bins[tid] = 0.f;
  __syncthreads();
  unsigned short* ob = y4 + (size_t)b * 4194304;
  int dy = cl >> 1, dx = cl & 1;
#pragma unroll
  for (int ni = 0; ni < 4; ++ni) {
    int loc = wn * 64 + ni * 16 + lr;
    int oc = och0 + loc;
    float s = 0.f, q = 0.f;
#pragma unroll
    for (int mi = 0; mi < 4; ++mi)
#pragma unroll
      for (int r = 0; r < 4; ++r) {
        int m = wm * 64 + mi * 16 + lg * 4 + r;
        int di = m >> 6, j = m & 63;
        int oy = 2 * (i0 + di) + dy, ox = 2 * j + dx;
        float v = acc[mi][ni][r];
        ob[(oy * 128 + ox) * 256 + oc] = f2bfu(v);
        s += v; q += v * v;
      }
    atomicAdd(&bins[loc * 2], s);
    atomicAdd(&bins[loc * 2 + 1], q);
  }
  __syncthreads();
  if (tid < 256) atomicAdd(&st4[b * 512 + och0 * 2 + tid], bins[tid]);
}

// ---------------- conv4: fp8 implicit GEMM, 128x128 tile, BK=128, XCD-swizzled ----------
// A/B LDS tiles [128 rows][128 B fp8], k-permuted layout -> lane lg's four 8B k-fragments
// are contiguous 32B: frag reads are two ds_read_b128 per row (conflict-free class).
__global__ __launch_bounds__(256, 3) void conv4_k(
    const unsigned char* __restrict__ xq8, const unsigned char* __restrict__ wb8,
    const float* __restrict__ b4, const float* __restrict__ cb,
    const int* __restrict__ lab, float* __restrict__ sums) {
  __shared__ char smem[33280];  // As 16K | Bs 16K | labs 512B
  char* As = smem;
  char* Bs = smem + 16384;
  int* labs = (int*)(smem + 32768);
  int tid = threadIdx.x;
  int id = blockIdx.x;
  int b = id & 7, rr = id >> 3;
  int y = rr >> 2, nblk = rr & 3;
  int n0 = nblk * 128;
  if (tid < 128) labs[tid] = lab[b * 16384 + y * 128 + tid];
  int lane = tid & 63, w = tid >> 6;
  int wm = w >> 1, wn = w & 1;
  int lr = lane & 15, lg = lane >> 4;

  f32x4 acc[4][4];
#pragma unroll
  for (int i = 0; i < 4; ++i)
#pragma unroll
    for (int j = 0; j < 4; ++j) acc[i][j] = (f32x4){0.f, 0.f, 0.f, 0.f};

  const unsigned char* xb = xq8 + (size_t)b * 4194304;

  int rs0 = tid >> 3;
  int csw = ((tid & 7) ^ (rs0 & 7)) << 4;  // byte offset of 16B chunk within 128B row
  int ldoff = tid * 16;                    // + i*4096

  const unsigned char* brow[4];
#pragma unroll
  for (int i = 0; i < 4; ++i)
    brow[i] = wb8 + (size_t)(n0 + rs0 + 32 * i) * 2304 + csw;

  int koff = 0;  // kk*256 + ic0 = step*128
  for (int kk = 0; kk < 9; ++kk) {
    int ky = (kk * 11) >> 5, kx = kk - ky * 3;
    int sy = y + ky - 1; sy = sy < 0 ? 1 : (sy > 127 ? 126 : sy);
    const unsigned char* arow[4];
#pragma unroll
    for (int i = 0; i < 4; ++i) {
      int sx = rs0 + 32 * i + kx - 1;
      sx = sx < 0 ? 1 : (sx > 127 ? 126 : sx);
      arow[i] = xb + ((size_t)(sy * 128 + sx)) * 256 + csw;
    }
    for (int ic0 = 0; ic0 < 256; ic0 += 128) {
      __syncthreads();
#pragma unroll
      for (int i = 0; i < 4; ++i) gload_lds16(arow[i] + ic0, As + i * 4096 + ldoff);
#pragma unroll
      for (int i = 0; i < 4; ++i) gload_lds16(brow[i] + koff, Bs + i * 4096 + ldoff);
      koff += 128;
      __syncthreads();

      // b128 frag reads: col = (lg*32 + k2*16) ^ ((row&7)<<4) — conflict-free class
      longx2 bq[4][2];
#pragma unroll
      for (int ni = 0; ni < 4; ++ni) {
        int row = wn * 64 + ni * 16 + lr;
#pragma unroll
        for (int k2 = 0; k2 < 2; ++k2) {
          int byte = row * 128 + ((lg * 32 + k2 * 16) ^ ((row & 7) << 4));
          bq[ni][k2] = *(const longx2*)(Bs + byte);
        }
      }
#pragma unroll
      for (int mi = 0; mi < 4; ++mi) {
        int row = wm * 64 + mi * 16 + lr;
        longx2 aq[2];
#pragma unroll
        for (int k2 = 0; k2 < 2; ++k2) {
          int byte = row * 128 + ((lg * 32 + k2 * 16) ^ ((row & 7) << 4));
          aq[k2] = *(const longx2*)(As + byte);
        }
#pragma unroll
        for (int ni = 0; ni < 4; ++ni)
#pragma unroll
          for (int k2 = 0; k2 < 2; ++k2) {
            acc[mi][ni] = __builtin_amdgcn_mfma_f32_16x16x32_fp8_fp8(
                aq[k2][0], bq[ni][k2][0], acc[mi][ni], 0, 0, 0);
            acc[mi][ni] = __builtin_amdgcn_mfma_f32_16x16x32_fp8_fp8(
                aq[k2][1], bq[ni][k2][1], acc[mi][ni], 0, 0, 0);
          }
      }
    }
  }

  // epilogue: (bias - fp8 bias-correction) + tanh + per-label bins
  __syncthreads();
  float* bins = (float*)smem;  // [19][128]
  for (int t2 = tid; t2 < 19 * 128; t2 += 256) bins[t2] = 0.f;
  __syncthreads();
  float bias[4];
#pragma unroll
  for (int ni = 0; ni < 4; ++ni) {
    int gc = n0 + wn * 64 + ni * 16 + lr;
    bias[ni] = b4[gc] - cb[b * 512 + gc];
  }
#pragma unroll
  for (int mi = 0; mi < 4; ++mi)
#pragma unroll
    for (int ni = 0; ni < 4; ++ni) {
      int ct = wn * 64 + ni * 16 + lr;
#pragma unroll
      for (int r = 0; r < 4; ++r) {
        int x = wm * 64 + mi * 16 + lg * 4 + r;
        float v = tanhf(acc[mi][ni][r] + bias[ni]);
        atomicAdd(&bins[labs[x] * 128 + ct], v);
      }
    }
  __syncthreads();
  for (int t2 = tid; t2 < 19 * 128; t2 += 256) {
    float v = bins[t2];
    if (v != 0.f)
      atomicAdd(&sums[((size_t)(b * 19 + (t2 >> 7))) * 512 + n0 + (t2 & 127)], v);
  }
}

// ---------------- finalize ----------------
__global__ void finalize_k(const float* __restrict__ sums, const float* __restrict__ counts,
                           float* __restrict__ out) {
  int idx = blockIdx.x * 256 + threadIdx.x;
  int bl = idx / 512;
  float c = counts[bl];
  out[idx] = c > 0.f ? sums[idx] / fmaxf(c, 1.f) : 0.f;
}

extern "C" void kernel_launch(void* const* d_in, const int* in_sizes, int n_in,
                              void* d_out, int out_size, void* d_ws, size_t ws_size,
                              hipStream_t stream) {
  const float* image = (const float*)d_in[0];
  const float* seg   = (const float*)d_in[1];
  const float* w1    = (const float*)d_in[2];
  const float* w2    = (const float*)d_in[4];
  const float* w3    = (const float*)d_in[6];
  const float* wt    = (const float*)d_in[8];
  const float* w4    = (const float*)d_in[10];
  const float* b4    = (const float*)d_in[11];
  float* out = (float*)d_out;
  char* ws = (char*)d_ws;

  unsigned short* x1  = (unsigned short*)(ws + OFF_X1);
  unsigned char*  xq8 = (unsigned char*)(ws + OFF_XQ8);
  unsigned short* x2  = (unsigned short*)(ws + OFF_X2);
  unsigned short* x3  = (unsigned short*)(ws + OFF_X3);
  unsigned short* y4  = (unsigned short*)(ws + OFF_Y4);
  unsigned char*  wb8 = (unsigned char*)(ws + OFF_WB8);
  unsigned short* wb2 = (unsigned short*)(ws + OFF_WB2);
  unsigned short* wb3 = (unsigned short*)(ws + OFF_WB3);
  unsigned short* wbt = (unsigned short*)(ws + OFF_WBT);
  float* st1 = (float*)(ws + OFF_ST1);
  float* st2 = (float*)(ws + OFF_ST2);
  float* st3 = (float*)(ws + OFF_ST3);
  float* st4 = (float*)(ws + OFF_ST4);
  float* sums = (float*)(ws + OFF_SUMS);
  float* counts = (float*)(ws + OFF_CNT);
  int* lab = (int*)(ws + OFF_LAB);
  float* dws  = (float*)(ws + OFF_DWS);
  float* wsum = (float*)(ws + OFF_WSM);
  float* st5  = (float*)(ws + OFF_ST5);
  float* cbv  = (float*)(ws + OFF_CB);

  // stat buffers zero + ALL independent prep in one launch
  hipMemsetAsync(ws + OFF_ST1, 0, 342624, stream);    // stats+sums+counts
  hipMemsetAsync(ws + OFF_ST5, 0, 16384, stream);     // fp8 channel sums
  prep_k<<<3764, 256, 0, stream>>>(w2, wb2, w3, wb3, wt, wbt, w4, wb8, dws, wsum,
                                   x1, x2, x3, seg, lab, counts);

  conv1_k<<<dim3(256, 8), 256, 0, stream>>>(image, w1, x1, st1);
  nln_k<32><<<dim3(256, 8), 256, 0, stream>>>(x1 + 259 * 32, 258 * 32, 1024, 2130048L,
                                              st1, 1.f / 65536.f);

  conv2_k<<<dim3(128, 8), 256, 0, stream>>>(x1, wb2, x2, st2);
  nln_k<64><<<dim3(128, 8), 256, 0, stream>>>(x2 + 131 * 64, 130 * 64, 1024, 1081600L,
                                              st2, 1.f / 16384.f);

  conv3_k<<<dim3(32, 8), 256, 0, stream>>>(x2, wb3, x3, st3);
  nln_k<128><<<dim3(64, 8), 256, 0, stream>>>(x3, 65 * 128, 1024, 540800L,
                                              st3, 1.f / 4096.f);

  convT_k<<<dim3(32, 8, 8), 256, 0, stream>>>(x3, wbt, y4, st4);

  // y4 -> norm+lrelu -> fp8 (xq8, k-permuted) + channel sums; then bias correction
  nln8_k<<<dim3(128, 8), 256, 0, stream>>>(y4, st4, xq8, st5);
  cbias_k<<<dim3(512, 8), 256, 0, stream>>>(st5, dws, wsum, cbv);

  conv4_k<<<4096, 256, 0, stream>>>(xq8, wb8, b4, cbv, lab, sums);

  finalize_k<<<304, 256, 0, stream>>>(sums, counts, out);
}

// Round 19
// 691.488 us; speedup vs baseline: 1.2822x; 1.0075x over previous
//
#include <hip/hip_runtime.h>
#include <hip/hip_bf16.h>
#include <math.h>

typedef __attribute__((ext_vector_type(8))) short bf16x8;
typedef __attribute__((ext_vector_type(8))) unsigned short u16x8;
typedef __attribute__((ext_vector_type(4))) float f32x4;
typedef __attribute__((ext_vector_type(2))) long longx2;

// ---------------- workspace layout (bytes) ----------------
#define OFF_X1   0ull           // x1 [8,258,258,32] bf16; DEAD after conv2 -> reused as xq8
#define OFF_XQ8  0ull           // xq8 [8,128,128,256] fp8 (33.5 MB), k-permuted per 128-half
#define OFF_X2   34080768ull
#define OFF_X3   51386368ull
#define OFF_Y4   60039168ull
#define OFF_WB8  127148032ull   // wb8 [512,9,256] fp8 (1.18 MB), k-permuted per 128-half
#define OFF_WB2  129507328ull
#define OFF_WB3  129548288ull
#define OFF_WBT  129695744ull
#define OFF_ST1  130744320ull
#define OFF_ST2  130746368ull
#define OFF_ST3  130750464ull
#define OFF_ST4  130758656ull
#define OFF_SUMS 130775040ull
#define OFF_CNT  131086336ull
#define OFF_LAB  131117664ull
#define OFF_DWS  131641952ull   // dws  [512][256] f32 (512 KB)
#define OFF_WSM  132166240ull   // wsum [512][256] f32 (512 KB)
#define OFF_ST5  132690528ull   // st5  [8][2][256] f32 (16 KB, zeroed)
#define OFF_CB   132706912ull   // cb   [8][512] f32 (16 KB)

__device__ __forceinline__ float bfu2f(unsigned short u) {
  return __builtin_bit_cast(float, ((unsigned)u) << 16);
}
__device__ __forceinline__ unsigned short f2bfu(float f) {
  __hip_bfloat16 h = __float2bfloat16(f);
  return __builtin_bit_cast(unsigned short, h);
}
__device__ __forceinline__ void gload_lds16(const void* g, void* l) {
  __builtin_amdgcn_global_load_lds(
      (const __attribute__((address_space(1))) unsigned int*)g,
      (__attribute__((address_space(3))) unsigned int*)l, 16, 0, 0);
}
template <bool HI>
__device__ __forceinline__ int cvtpk8(float a, float b, int old) {
  return __builtin_amdgcn_cvt_pk_fp8_f32(a, b, old, HI);
}
template <int SEL>
__device__ __forceinline__ float cvtf8(int v) {
  return __builtin_amdgcn_cvt_f32_fp8(v, SEL);
}

#define WAITV(N) asm volatile("s_waitcnt vmcnt(" #N ")" ::: "memory")

// counted-vmcnt pipelined step (2-phase, used by convT)
#define PIPE_STEP(WAITN, BUF, DOSTAGE, SNEXT)                 \
  asm volatile("s_waitcnt vmcnt(" #WAITN ")" ::: "memory");   \
  __builtin_amdgcn_s_barrier();                               \
  __builtin_amdgcn_sched_barrier(0);                          \
  mmaStep(BUF, (BUF) + 16384);                                \
  __builtin_amdgcn_sched_barrier(0);                          \
  __builtin_amdgcn_s_barrier();                               \
  if (DOSTAGE) stage(SNEXT, BUF);

__device__ const int c_taptab[16] = {4, -1, -1, -1, 5, 3, -1, -1, 7, -1, 1, -1, 8, 6, 2, 0};

// ---------------- prep: wrep2 | wrep3 | wrepT | dwrep | padz | lab in ONE launch ----------
// block ranges: [0,80) wrep2, [80,368) wrep3, [368,2416) wrepT, [2416,2928) dwrep,
//               [2928,3252) padz, [3252,3764) lab
__global__ __launch_bounds__(256) void prep_k(
    const float* __restrict__ w2, unsigned short* __restrict__ wb2,
    const float* __restrict__ w3, unsigned short* __restrict__ wb3,
    const float* __restrict__ wt, unsigned short* __restrict__ wbt,
    const float* __restrict__ w4, unsigned char* __restrict__ wb8,
    float* __restrict__ dws, float* __restrict__ wsum,
    unsigned short* __restrict__ x1, unsigned short* __restrict__ x2,
    unsigned short* __restrict__ x3,
    const float* __restrict__ seg, int* __restrict__ lab, float* __restrict__ counts) {
  __shared__ int hist[19];
  int blk = blockIdx.x, t = threadIdx.x;
  if (blk < 80) {
    int idx = blk * 256 + t;
    if (idx < 20480) {
      int oc = idx / 320, r = idx % 320, tap = r >> 5, ic = r & 31;
      wb2[idx] = tap < 9 ? f2bfu(w2[(oc * 32 + ic) * 9 + tap]) : (unsigned short)0;
    }
  } else if (blk < 368) {
    int idx = (blk - 80) * 256 + t;
    int oc = idx / 576, r = idx % 576, tap = r >> 6, ic = r & 63;
    wb3[idx] = f2bfu(w3[(oc * 64 + ic) * 9 + tap]);
  } else if (blk < 2416) {
    int idx = (blk - 368) * 256 + t;
    int n = idx >> 9, k = idx & 511;
    int cl = n >> 8, oc = n & 255, nb = k >> 7, ic = k & 127;
    int tap = c_taptab[cl * 4 + nb];
    wbt[idx] = tap < 0 ? (unsigned short)0 : f2bfu(wt[(ic * 256 + oc) * 9 + tap]);
  } else if (blk < 2928) {
    int oc = blk - 2416, ic = t;
    int local = ic & 127;
    int p = (ic & 128) + ((local >> 3) & 3) * 32 + ((local >> 5) & 3) * 8 + (local & 7);
    float ds = 0.f, ws = 0.f;
    for (int kk = 0; kk < 9; ++kk) {
      float w = w4[(size_t)oc * 2304 + ic * 9 + kk];
      int pk = cvtpk8<false>(w, 0.f, 0);
      wb8[((size_t)oc * 9 + kk) * 256 + p] = (unsigned char)(pk & 0xff);
      float wq = cvtf8<0>(pk);
      ds += wq - w; ws += w;
    }
    dws[oc * 256 + ic] = ds;
    wsum[oc * 256 + ic] = ws;
  } else if (blk < 3252) {
    int u = (blk - 2928) * 256 + t;  // < 82944
    int b = u / 10368, r = u % 10368;
    u16x8 z = {0, 0, 0, 0, 0, 0, 0, 0};
    if (r < 4128) {
      unsigned short* base = x1 + (size_t)b * 2130048;
      if (r < 2064) {
        int row = r < 1032 ? 0 : 257, pos = r < 1032 ? r : r - 1032;
        base += (row * 258 + (pos >> 2)) * 32 + (pos & 3) * 8;
      } else {
        int rc = r - 2064;
        int col = rc < 1032 ? 0 : 257, pos = rc < 1032 ? rc : rc - 1032;
        base += ((pos >> 2) * 258 + col) * 32 + (pos & 3) * 8;
      }
      *(u16x8*)base = z;
    } else if (r < 8288) {
      int s = r - 4128;
      unsigned short* base = x2 + (size_t)b * 1081600;
      if (s < 2080) {
        int row = s < 1040 ? 0 : 129, pos = s < 1040 ? s : s - 1040;
        base += (row * 130 + (pos >> 3)) * 64 + (pos & 7) * 8;
      } else {
        int sc = s - 2080;
        int col = sc < 1040 ? 0 : 129, pos = sc < 1040 ? sc : sc - 1040;
        base += ((pos >> 3) * 130 + col) * 64 + (pos & 7) * 8;
      }
      *(u16x8*)base = z;
    } else {
      int tt = r - 8288;
      unsigned short* base = x3 + (size_t)b * 540800;
      if (tt < 1040) {
        base += (64 * 65 + (tt >> 4)) * 128 + (tt & 15) * 8;
      } else {
        int pos = tt - 1040;
        base += ((pos >> 4) * 65 + 64) * 128 + (pos & 15) * 8;
      }
      *(u16x8*)base = z;
    }
  } else {
    int blk2 = blk - 3252;  // < 512
    int b = blk2 >> 6;
    int p = (blk2 & 63) * 256 + t;
    if (t < 19) hist[t] = 0;
    __syncthreads();
    int i = p >> 7, j = p & 127;
    const float* sp = seg + (size_t)b * 19 * 65536 + (2 * i) * 256 + 2 * j;
    int l = 0;
    for (int k = 0; k < 19; ++k) { if (sp[(size_t)k * 65536] != 0.f) { l = k; break; } }
    lab[b * 16384 + p] = l;
    atomicAdd(&hist[l], 1);
    __syncthreads();
    if (t < 19) atomicAdd(&counts[b * 19 + t], (float)hist[t]);
  }
}

// ---------------- conv1: reflect-pad 3->32 -> x1 NHWC padded bf16 + fused channel stats ----
__global__ __launch_bounds__(256) void conv1_k(const float* __restrict__ img,
                                               const float* __restrict__ w1,
                                               unsigned short* __restrict__ x1,
                                               float* __restrict__ st1) {
  __shared__ float wl[864];        // [k 27][oc 32]
  __shared__ float tile[256][33];  // padded: avoids 1056 % 32 == 0 bank alias
  __shared__ float cbins[64];
  int t = threadIdx.x, y = blockIdx.x, b = blockIdx.y;
  for (int i = t; i < 864; i += 256) wl[i] = w1[(i & 31) * 27 + (i >> 5)];
  if (t < 64) cbins[t] = 0.f;
  __syncthreads();
  int x = t;
  float val[27];
  for (int ic = 0; ic < 3; ++ic) {
    const float* ip = img + ((size_t)(b * 3 + ic)) * 65536;
#pragma unroll
    for (int ky = 0; ky < 3; ++ky) {
      int gy = y - 1 + ky; gy = gy < 0 ? -gy : (gy > 255 ? 510 - gy : gy);
#pragma unroll
      for (int kx = 0; kx < 3; ++kx) {
        int gx = x - 1 + kx; gx = gx < 0 ? -gx : (gx > 255 ? 510 - gx : gx);
        val[ic * 9 + ky * 3 + kx] = ip[gy * 256 + gx];
      }
    }
  }
  float a[32];
#pragma unroll
  for (int oc = 0; oc < 32; ++oc) a[oc] = 0.f;
#pragma unroll
  for (int k = 0; k < 27; ++k) {
    float vv = val[k];
#pragma unroll
    for (int oc = 0; oc < 32; ++oc) a[oc] += wl[k * 32 + oc] * vv;
  }
  unsigned short ov[32];
#pragma unroll
  for (int oc = 0; oc < 32; ++oc) ov[oc] = f2bfu(a[oc]);
  unsigned short* op = x1 + ((size_t)(b * 258 + y + 1) * 258 + (x + 1)) * 32;
#pragma unroll
  for (int i = 0; i < 4; ++i) *(u16x8*)(op + i * 8) = *(const u16x8*)(ov + i * 8);

  // fused stats: block-local column sums of the [256 px][32 ch] tile
#pragma unroll
  for (int oc = 0; oc < 32; ++oc) tile[t][oc] = a[oc];
  __syncthreads();
  int ch = t & 31, seg = t >> 5;
  float s = 0.f, q = 0.f;
  for (int r = 0; r < 32; ++r) {
    float v = tile[seg * 32 + ((r + seg) & 31)][ch];
    s += v; q += v * v;
  }
  atomicAdd(&cbins[ch * 2], s);
  atomicAdd(&cbins[ch * 2 + 1], q);
  __syncthreads();
  if (t < 64) atomicAdd(&st1[b * 64 + t], cbins[t]);
}

// ---------------- normalize + leaky-relu in place; (mean,rstd) computed inline from st ----
// each thread touches exactly one 8-channel group (256 % CH8 == 0 for all C used)
template <int C>
__global__ void nln_k(unsigned short* __restrict__ base, int rowStride, int unitsPerRow,
                      long bStride, const float* __restrict__ st, float invN) {
  const int CH8 = C / 8;
  int row = blockIdx.x, b = blockIdx.y;
  unsigned short* rp = base + (size_t)b * bStride + (size_t)row * rowStride;
  int ch = (threadIdx.x & (CH8 - 1)) * 8;
  const float* stb = st + b * C * 2;
  float2 m0[8];
#pragma unroll
  for (int e = 0; e < 8; ++e) {
    float m = stb[(ch + e) * 2] * invN;
    float v = stb[(ch + e) * 2 + 1] * invN - m * m;
    m0[e] = make_float2(m, rsqrtf(fmaxf(v, 0.f) + 1e-5f));
  }
  for (int idx = threadIdx.x; idx < unitsPerRow; idx += 256) {
    u16x8 v = *(u16x8*)(rp + idx * 8);
    u16x8 o;
#pragma unroll
    for (int e = 0; e < 8; ++e) {
      float f = (bfu2f(v[e]) - m0[e].x) * m0[e].y;
      o[e] = f2bfu(f >= 0.f ? f : 0.2f * f);
    }
    *(u16x8*)(rp + idx * 8) = o;
  }
}

// ---------------- nln8: y4 bf16 -> norm+lrelu -> fp8 xq8 (k-permuted) + channel sums ------
// (mean,rstd) computed inline from st4
__global__ __launch_bounds__(256) void nln8_k(const unsigned short* __restrict__ y4,
                                              const float* __restrict__ st4,
                                              unsigned char* __restrict__ xq8,
                                              float* __restrict__ st5) {
  __shared__ float bs[512];
  int t = threadIdx.x, row = blockIdx.x, b = blockIdx.y;
  int cg = t & 31, pg = t >> 5;
  int wof0 = (cg >> 4) * 128 + ((((cg & 15) & 3) << 2) | ((cg & 15) >> 2)) * 8;
  const float* stb = st4 + b * 512;
  const float invN = 1.f / 16384.f;
  float2 m0[8];
#pragma unroll
  for (int e = 0; e < 8; ++e) {
    float m = stb[(cg * 8 + e) * 2] * invN;
    float v = stb[(cg * 8 + e) * 2 + 1] * invN - m * m;
    m0[e] = make_float2(m, rsqrtf(fmaxf(v, 0.f) + 1e-5f));
  }
  const unsigned short* rp = y4 + ((size_t)b * 16384 + row * 128) * 256;
  unsigned char* op = xq8 + ((size_t)b * 16384 + (size_t)row * 128) * 256;
  float s[8] = {0, 0, 0, 0, 0, 0, 0, 0}, d[8] = {0, 0, 0, 0, 0, 0, 0, 0};
  for (int i = 0; i < 16; ++i) {
    int px = pg * 16 + i;
    u16x8 v = *(const u16x8*)(rp + (size_t)px * 256 + cg * 8);
    float f[8];
#pragma unroll
    for (int e = 0; e < 8; ++e) {
      float x = (bfu2f(v[e]) - m0[e].x) * m0[e].y;
      f[e] = x >= 0.f ? x : 0.2f * x;
    }
    int lo = cvtpk8<false>(f[0], f[1], 0); lo = cvtpk8<true>(f[2], f[3], lo);
    int hi = cvtpk8<false>(f[4], f[5], 0); hi = cvtpk8<true>(f[6], f[7], hi);
    *(long*)(op + (size_t)px * 256 + wof0) =
        ((long)(unsigned)hi << 32) | (unsigned)lo;
    float fq;
    fq = cvtf8<0>(lo); s[0] += fq; d[0] += fq - f[0];
    fq = cvtf8<1>(lo); s[1] += fq; d[1] += fq - f[1];
    fq = cvtf8<2>(lo); s[2] += fq; d[2] += fq - f[2];
    fq = cvtf8<3>(lo); s[3] += fq; d[3] += fq - f[3];
    fq = cvtf8<0>(hi); s[4] += fq; d[4] += fq - f[4];
    fq = cvtf8<1>(hi); s[5] += fq; d[5] += fq - f[5];
    fq = cvtf8<2>(hi); s[6] += fq; d[6] += fq - f[6];
    fq = cvtf8<3>(hi); s[7] += fq; d[7] += fq - f[7];
  }
  for (int i = t; i < 512; i += 256) bs[i] = 0.f;
  __syncthreads();
#pragma unroll
  for (int e = 0; e < 8; ++e) {
    atomicAdd(&bs[cg * 8 + e], s[e]);
    atomicAdd(&bs[256 + cg * 8 + e], d[e]);
  }
  __syncthreads();
  for (int i = t; i < 512; i += 256) atomicAdd(&st5[b * 512 + i], bs[i]);
}

// ---------------- cbias: c[b][oc] = sum_ic( muq*dws + dmu*wsum ) ----------------
__global__ __launch_bounds__(256) void cbias_k(const float* __restrict__ st5,
                                               const float* __restrict__ dws,
                                               const float* __restrict__ wsum,
                                               float* __restrict__ cb) {
  int oc = blockIdx.x, b = blockIdx.y, t = threadIdx.x;
  const float inv = 1.f / 16384.f;
  float muq = st5[b * 512 + t] * inv;
  float dmu = st5[b * 512 + 256 + t] * inv;
  float a = muq * dws[oc * 256 + t] + dmu * wsum[oc * 256 + t];
#pragma unroll
  for (int o = 1; o < 64; o <<= 1) a += __shfl_xor(a, o);
  __shared__ float r[4];
  if ((t & 63) == 0) r[t >> 6] = a;
  __syncthreads();
  if (t == 0) cb[b * 512 + oc] = r[0] + r[1] + r[2] + r[3];
}

// ---------------- conv2 MFMA (double-buffered): x1 -> x2 + stats ----------------
__global__ __launch_bounds__(256) void conv2_k(const unsigned short* __restrict__ x1,
                                               const unsigned short* __restrict__ wb2,
                                               unsigned short* __restrict__ x2,
                                               float* __restrict__ st2) {
  __shared__ char smem[49664];
  float* bins = (float*)(smem + 49152);
  int tid = threadIdx.x, y = blockIdx.x, b = blockIdx.y;
  int lane = tid & 63, w = tid >> 6, wm = w >> 1, wn = w & 1;
  int lr = lane & 15, lg = lane >> 4;
  f32x4 acc[4][2];
#pragma unroll
  for (int i = 0; i < 4; ++i)
#pragma unroll
    for (int j = 0; j < 2; ++j) acc[i][j] = (f32x4){0.f, 0.f, 0.f, 0.f};

  int rowA[4], lcA[4], PbA[4];
#pragma unroll
  for (int i = 0; i < 4; ++i) {
    int pb = i * 256 + tid;
    PbA[i] = pb * 16; rowA[i] = pb >> 3; lcA[i] = (pb & 7) ^ (rowA[i] & 7);
  }
  int rowB[2], lcB[2], PbB[2];
#pragma unroll
  for (int i = 0; i < 2; ++i) {
    int pb = i * 256 + tid;
    PbB[i] = pb * 16; rowB[i] = pb >> 3; lcB[i] = (pb & 7) ^ (rowB[i] & 7);
  }
  const unsigned short* xb = x1 + (size_t)b * 2130048;

  auto stage = [&](int kb, char* base) {
    char* As = base;
    char* Bs = base + 16384;
#pragma unroll
    for (int i = 0; i < 4; ++i) {
      int tp = kb * 2 + (lcA[i] >> 2);
      int ky = (tp * 11) >> 5;
      int kx = tp - ky * 3;
      gload_lds16(xb + ((size_t)((2 * y + ky) * 258 + 2 * rowA[i] + kx)) * 32 + (lcA[i] & 3) * 8,
                  As + PbA[i]);
    }
#pragma unroll
    for (int i = 0; i < 2; ++i)
      gload_lds16(wb2 + rowB[i] * 320 + kb * 64 + lcB[i] * 8, Bs + PbB[i]);
  };

  stage(0, smem);
  __syncthreads();
  for (int kb = 0; kb < 5; ++kb) {
    char* base = smem + (kb & 1) * 24576;
    if (kb + 1 < 5) stage(kb + 1, smem + ((kb + 1) & 1) * 24576);
    char* As = base;
    char* Bs = base + 16384;
    bf16x8 af[4][2], bfr[2][2];
#pragma unroll
    for (int mi = 0; mi < 4; ++mi)
#pragma unroll
      for (int kh = 0; kh < 2; ++kh) {
        int row = wm * 64 + mi * 16 + lr;
        int byte = row * 128 + ((kh * 64 + lg * 16) ^ ((row & 7) << 4));
        af[mi][kh] = *(const bf16x8*)(As + byte);
      }
#pragma unroll
    for (int ni = 0; ni < 2; ++ni)
#pragma unroll
      for (int kh = 0; kh < 2; ++kh) {
        int row = wn * 32 + ni * 16 + lr;
        int byte = row * 128 + ((kh * 64 + lg * 16) ^ ((row & 7) << 4));
        bfr[ni][kh] = *(const bf16x8*)(Bs + byte);
      }
#pragma unroll
    for (int mi = 0; mi < 4; ++mi)
#pragma unroll
      for (int ni = 0; ni < 2; ++ni)
#pragma unroll
        for (int kh = 0; kh < 2; ++kh)
          acc[mi][ni] = __builtin_amdgcn_mfma_f32_16x16x32_bf16(af[mi][kh], bfr[ni][kh],
                                                                acc[mi][ni], 0, 0, 0);
    __syncthreads();
  }

  if (tid < 128) bins[tid] = 0.f;
  __syncthreads();
  unsigned short* ob = x2 + (size_t)b * 1081600;
#pragma unroll
  for (int ni = 0; ni < 2; ++ni) {
    int oc = wn * 32 + ni * 16 + lr;
    float s = 0.f, q = 0.f;
#pragma unroll
    for (int mi = 0; mi < 4; ++mi)
#pragma unroll
      for (int r = 0; r < 4; ++r) {
        int m = wm * 64 + mi * 16 + lg * 4 + r;
        float v = acc[mi][ni][r];
        ob[((y + 1) * 130 + m + 1) * 64 + oc] = f2bfu(v);
        s += v; q += v * v;
      }
    atomicAdd(&bins[oc * 2], s);
    atomicAdd(&bins[oc * 2 + 1], q);
  }
  __syncthreads();
  if (tid < 128) atomicAdd(&st2[b * 128 + tid], bins[tid]);
}

// ---------------- conv3 MFMA (double-buffered): x2 -> x3 + stats ----------------
__global__ __launch_bounds__(256) void conv3_k(const unsigned short* __restrict__ x2,
                                               const unsigned short* __restrict__ wb3,
                                               unsigned short* __restrict__ x3,
                                               float* __restrict__ st3) {
  __shared__ char smem[66560];
  float* bins = (float*)(smem + 65536);
  int tid = threadIdx.x, y0 = blockIdx.x * 2, b = blockIdx.y;
  int lane = tid & 63, w = tid >> 6, wm = w >> 1, wn = w & 1;
  int lr = lane & 15, lg = lane >> 4;
  f32x4 acc[4][4];
#pragma unroll
  for (int i = 0; i < 4; ++i)
#pragma unroll
    for (int j = 0; j < 4; ++j) acc[i][j] = (f32x4){0.f, 0.f, 0.f, 0.f};

  int rowS[4], lc[4], Pb[4];
#pragma unroll
  for (int i = 0; i < 4; ++i) {
    int pb = i * 256 + tid;
    Pb[i] = pb * 16; rowS[i] = pb >> 3; lc[i] = (pb & 7) ^ (rowS[i] & 7);
  }
  const unsigned short* xb = x2 + (size_t)b * 1081600;

  auto stage = [&](int kk, char* base) {
    int ky = kk / 3, kx = kk - ky * 3;
#pragma unroll
    for (int i = 0; i < 4; ++i) {
      int m = rowS[i], di = m >> 6, xx = m & 63;
      gload_lds16(xb + ((size_t)((2 * (y0 + di) + ky) * 130 + 2 * xx + kx)) * 64 + lc[i] * 8,
                  base + Pb[i]);
    }
#pragma unroll
    for (int i = 0; i < 4; ++i)
      gload_lds16(wb3 + (rowS[i] * 9 + kk) * 64 + lc[i] * 8, base + 16384 + Pb[i]);
  };

  stage(0, smem);
  __syncthreads();
  for (int kk = 0; kk < 9; ++kk) {
    char* base = smem + (kk & 1) * 32768;
    if (kk + 1 < 9) stage(kk + 1, smem + ((kk + 1) & 1) * 32768);
    char* As = base;
    char* Bs = base + 16384;
    bf16x8 af[4][2], bfr[4][2];
#pragma unroll
    for (int mi = 0; mi < 4; ++mi)
#pragma unroll
      for (int kh = 0; kh < 2; ++kh) {
        int row = wm * 64 + mi * 16 + lr;
        int byte = row * 128 + ((kh * 64 + lg * 16) ^ ((row & 7) << 4));
        af[mi][kh] = *(const bf16x8*)(As + byte);
      }
#pragma unroll
    for (int ni = 0; ni < 4; ++ni)
#pragma unroll
      for (int kh = 0; kh < 2; ++kh) {
        int row = wn * 64 + ni * 16 + lr;
        int byte = row * 128 + ((kh * 64 + lg * 16) ^ ((row & 7) << 4));
        bfr[ni][kh] = *(const bf16x8*)(Bs + byte);
      }
#pragma unroll
    for (int mi = 0; mi < 4; ++mi)
#pragma unroll
      for (int ni = 0; ni < 4; ++ni)
#pragma unroll
        for (int kh = 0; kh < 2; ++kh)
          acc[mi][ni] = __builtin_amdgcn_mfma_f32_16x16x32_bf16(af[mi][kh], bfr[ni][kh],
                                                                acc[mi][ni], 0, 0, 0);
    __syncthreads();
  }

  if (tid < 256) bins[tid] = 0.f;
  __syncthreads();
  unsigned short* ob = x3 + (size_t)b * 540800;
#pragma unroll
  for (int ni = 0; ni < 4; ++ni) {
    int oc = wn * 64 + ni * 16 + lr;
    float s = 0.f, q = 0.f;
#pragma unroll
    for (int mi = 0; mi < 4; ++mi)
#pragma unroll
      for (int r = 0; r < 4; ++r) {
        int m = wm * 64 + mi * 16 + lg * 4 + r;
        int di = m >> 6, xx = m & 63;
        float v = acc[mi][ni][r];
        ob[((y0 + di) * 65 + xx) * 128 + oc] = f2bfu(v);
        s += v; q += v * v;
      }
    atomicAdd(&bins[oc * 2], s);
    atomicAdd(&bins[oc * 2 + 1], q);
  }
  __syncthreads();
  if (tid < 256) atomicAdd(&st3[b * 256 + tid], bins[tid]);
}

// ---------------- convT MFMA (counted-vmcnt pipeline): x3 -> y4 + stats ----------------
__global__ __launch_bounds__(256) void convT_k(const unsigned short* __restrict__ x3,
                                               const unsigned short* __restrict__ wbt,
                                               unsigned short* __restrict__ y4,
                                               float* __restrict__ st4) {
  __shared__ char smem[67584];
  float* bins = (float*)(smem + 65536);
  int tid = threadIdx.x, i0 = blockIdx.x * 2, nblk = blockIdx.y, b = blockIdx.z;
  int n0 = nblk * 128, cl = nblk >> 1, och0 = (nblk & 1) * 128;
  int lane = tid & 63, w = tid >> 6, wm = w >> 1, wn = w & 1;
  int lr = lane & 15, lg = lane >> 4;
  f32x4 acc[4][4];
#pragma unroll
  for (int i = 0; i < 4; ++i)
#pragma unroll
    for (int j = 0; j < 4; ++j) acc[i][j] = (f32x4){0.f, 0.f, 0.f, 0.f};

  int rowS[4], lc[4], Pb[4];
#pragma unroll
  for (int i = 0; i < 4; ++i) {
    int pb = i * 256 + tid;
    Pb[i] = pb * 16; rowS[i] = pb >> 3; lc[i] = (pb & 7) ^ (rowS[i] & 7);
  }
  int aoff[4][2], boff[4][2];
#pragma unroll
  for (int mi = 0; mi < 4; ++mi)
#pragma unroll
    for (int kh = 0; kh < 2; ++kh) {
      int row = wm * 64 + mi * 16 + lr;
      aoff[mi][kh] = row * 128 + ((kh * 64 + lg * 16) ^ ((row & 7) << 4));
      int rowb = wn * 64 + mi * 16 + lr;
      boff[mi][kh] = rowb * 128 + ((kh * 64 + lg * 16) ^ ((rowb & 7) << 4));
    }
  const unsigned short* xb = x3 + (size_t)b * 540800;

  auto stage = [&](int kb, char* base) {
    int nb = kb >> 1, chalf = (kb & 1) * 64;
#pragma unroll
    for (int i = 0; i < 4; ++i) {
      int m = rowS[i], di = m >> 6, j = m & 63;
      int pi = i0 + di + (nb >> 1), pj = j + (nb & 1);
      gload_lds16(xb + ((size_t)(pi * 65 + pj)) * 128 + chalf + lc[i] * 8, base + Pb[i]);
    }
#pragma unroll
    for (int i = 0; i < 4; ++i)
      gload_lds16(wbt + (size_t)(n0 + rowS[i]) * 512 + kb * 64 + lc[i] * 8,
                  base + 16384 + Pb[i]);
  };

  auto mmaStep = [&](char* As, char* Bs) {
    bf16x8 af[4][2], bfr[4][2];
#pragma unroll
    for (int mi = 0; mi < 4; ++mi)
#pragma unroll
      for (int kh = 0; kh < 2; ++kh) af[mi][kh] = *(const bf16x8*)(As + aoff[mi][kh]);
#pragma unroll
    for (int ni = 0; ni < 4; ++ni)
#pragma unroll
      for (int kh = 0; kh < 2; ++kh) bfr[ni][kh] = *(const bf16x8*)(Bs + boff[ni][kh]);
#pragma unroll
    for (int mi = 0; mi < 4; ++mi)
#pragma unroll
      for (int ni = 0; ni < 4; ++ni)
#pragma unroll
        for (int kh = 0; kh < 2; ++kh)
          acc[mi][ni] = __builtin_amdgcn_mfma_f32_16x16x32_bf16(af[mi][kh], bfr[ni][kh],
                                                                acc[mi][ni], 0, 0, 0);
  };

  char* B0 = smem;
  char* B1 = smem + 32768;
  stage(0, B0);
  stage(1, B1);
  for (int sp = 0; sp < 3; ++sp) {
    PIPE_STEP(8, B0, true, 2 * sp + 2);
    PIPE_STEP(8, B1, true, 2 * sp + 3);
  }
  PIPE_STEP(8, B0, false, 0);
  PIPE_STEP(0, B1, false, 0);

  if (tid < 256) bins[tid] = 0.f;
  __syncthreads();
  unsigned short* ob = y4 + (size_t)b * 4194304;
  int dy = cl >> 1, dx = cl & 1;
#pragma unroll
  for (int ni = 0; ni < 4; ++ni) {
    int loc = wn * 64 + ni * 16 + lr;
    int oc = och0 + loc;
    float s = 0.f, q = 0.f;
#pragma unroll
    for (int mi = 0; mi < 4; ++mi)
#pragma unroll
      for (int r = 0; r < 4; ++r) {
        int m = wm * 64 + mi * 16 + lg * 4 + r;
        int di = m >> 6, j = m & 63;
        int oy = 2 * (i0 + di) + dy, ox = 2 * j + dx;
        float v = acc[mi][ni][r];
        ob[(oy * 128 + ox) * 256 + oc] = f2bfu(v);
        s += v; q += v * v;
      }
    atomicAdd(&bins[loc * 2], s);
    atomicAdd(&bins[loc * 2 + 1], q);
  }
  __syncthreads();
  if (tid < 256) atomicAdd(&st4[b * 512 + och0 * 2 + tid], bins[tid]);
}

// ---------------- conv4: fp8 implicit GEMM, 128x128 tile, BK=128, XCD-swizzled ----------
// A/B LDS tiles [128 rows][128 B fp8], k-permuted layout -> lane lg's four 8B k-fragments
// are contiguous 32B: frag reads are two ds_read_b128 per row (conflict-free class).
// __launch_bounds__(256,4): 4 blocks/CU (LDS 4x33.3KB fits; VGPR cap 128 >= 72).
__global__ __launch_bounds__(256, 4) void conv4_k(
    const unsigned char* __restrict__ xq8, const unsigned char* __restrict__ wb8,
    const float* __restrict__ b4, const float* __restrict__ cb,
    const int* __restrict__ lab, float* __restrict__ sums) {
  __shared__ char smem[33280];  // As 16K | Bs 16K | labs 512B
  char* As = smem;
  char* Bs = smem + 16384;
  int* labs = (int*)(smem + 32768);
  int tid = threadIdx.x;
  int id = blockIdx.x;
  int b = id & 7, rr = id >> 3;
  int y = rr >> 2, nblk = rr & 3;
  int n0 = nblk * 128;
  if (tid < 128) labs[tid] = lab[b * 16384 + y * 128 + tid];
  int lane = tid & 63, w = tid >> 6;
  int wm = w >> 1, wn = w & 1;
  int lr = lane & 15, lg = lane >> 4;

  f32x4 acc[4][4];
#pragma unroll
  for (int i = 0; i < 4; ++i)
#pragma unroll
    for (int j = 0; j < 4; ++j) acc[i][j] = (f32x4){0.f, 0.f, 0.f, 0.f};

  const unsigned char* xb = xq8 + (size_t)b * 4194304;

  int rs0 = tid >> 3;
  int csw = ((tid & 7) ^ (rs0 & 7)) << 4;  // byte offset of 16B chunk within 128B row
  int ldoff = tid * 16;                    // + i*4096

  const unsigned char* brow[4];
#pragma unroll
  for (int i = 0; i < 4; ++i)
    brow[i] = wb8 + (size_t)(n0 + rs0 + 32 * i) * 2304 + csw;

  int koff = 0;  // kk*256 + ic0 = step*128
  for (int kk = 0; kk < 9; ++kk) {
    int ky = (kk * 11) >> 5, kx = kk - ky * 3;
    int sy = y + ky - 1; sy = sy < 0 ? 1 : (sy > 127 ? 126 : sy);
    const unsigned char* arow[4];
#pragma unroll
    for (int i = 0; i < 4; ++i) {
      int sx = rs0 + 32 * i + kx - 1;
      sx = sx < 0 ? 1 : (sx > 127 ? 126 : sx);
      arow[i] = xb + ((size_t)(sy * 128 + sx)) * 256 + csw;
    }
    for (int ic0 = 0; ic0 < 256; ic0 += 128) {
      __syncthreads();
#pragma unroll
      for (int i = 0; i < 4; ++i) gload_lds16(arow[i] + ic0, As + i * 4096 + ldoff);
#pragma unroll
      for (int i = 0; i < 4; ++i) gload_lds16(brow[i] + koff, Bs + i * 4096 + ldoff);
      koff += 128;
      __syncthreads();

      // b128 frag reads: col = (lg*32 + k2*16) ^ ((row&7)<<4) — conflict-free class
      longx2 bq[4][2];
#pragma unroll
      for (int ni = 0; ni < 4; ++ni) {
        int row = wn * 64 + ni * 16 + lr;
#pragma unroll
        for (int k2 = 0; k2 < 2; ++k2) {
          int byte = row * 128 + ((lg * 32 + k2 * 16) ^ ((row & 7) << 4));
          bq[ni][k2] = *(const longx2*)(Bs + byte);
        }
      }
#pragma unroll
      for (int mi = 0; mi < 4; ++mi) {
        int row = wm * 64 + mi * 16 + lr;
        longx2 aq[2];
#pragma unroll
        for (int k2 = 0; k2 < 2; ++k2) {
          int byte = row * 128 + ((lg * 32 + k2 * 16) ^ ((row & 7) << 4));
          aq[k2] = *(const longx2*)(As + byte);
        }
#pragma unroll
        for (int ni = 0; ni < 4; ++ni)
#pragma unroll
          for (int k2 = 0; k2 < 2; ++k2) {
            acc[mi][ni] = __builtin_amdgcn_mfma_f32_16x16x32_fp8_fp8(
                aq[k2][0], bq[ni][k2][0], acc[mi][ni], 0, 0, 0);
            acc[mi][ni] = __builtin_amdgcn_mfma_f32_16x16x32_fp8_fp8(
                aq[k2][1], bq[ni][k2][1], acc[mi][ni], 0, 0, 0);
          }
      }
    }
  }

  // epilogue: (bias - fp8 bias-correction) + tanh + per-label bins
  __syncthreads();
  float* bins = (float*)smem;  // [19][128]
  for (int t2 = tid; t2 < 19 * 128; t2 += 256) bins[t2] = 0.f;
  __syncthreads();
  float bias[4];
#pragma unroll
  for (int ni = 0; ni < 4; ++ni) {
    int gc = n0 + wn * 64 + ni * 16 + lr;
    bias[ni] = b4[gc] - cb[b * 512 + gc];
  }
#pragma unroll
  for (int mi = 0; mi < 4; ++mi)
#pragma unroll
    for (int ni = 0; ni < 4; ++ni) {
      int ct = wn * 64 + ni * 16 + lr;
#pragma unroll
      for (int r = 0; r < 4; ++r) {
        int x = wm * 64 + mi * 16 + lg * 4 + r;
        float v = tanhf(acc[mi][ni][r] + bias[ni]);
        atomicAdd(&bins[labs[x] * 128 + ct], v);
      }
    }
  __syncthreads();
  for (int t2 = tid; t2 < 19 * 128; t2 += 256) {
    float v = bins[t2];
    if (v != 0.f)
      atomicAdd(&sums[((size_t)(b * 19 + (t2 >> 7))) * 512 + n0 + (t2 & 127)], v);
  }
}

// ---------------- finalize ----------------
__global__ void finalize_k(const float* __restrict__ sums, const float* __restrict__ counts,
                           float* __restrict__ out) {
  int idx = blockIdx.x * 256 + threadIdx.x;
  int bl = idx / 512;
  float c = counts[bl];
  out[idx] = c > 0.f ? sums[idx] / fmaxf(c, 1.f) : 0.f;
}

extern "C" void kernel_launch(void* const* d_in, const int* in_sizes, int n_in,
                              void* d_out, int out_size, void* d_ws, size_t ws_size,
                              hipStream_t stream) {
  const float* image = (const float*)d_in[0];
  const float* seg   = (const float*)d_in[1];
  const float* w1    = (const float*)d_in[2];
  const float* w2    = (const float*)d_in[4];
  const float* w3    = (const float*)d_in[6];
  const float* wt    = (const float*)d_in[8];
  const float* w4    = (const float*)d_in[10];
  const float* b4    = (const float*)d_in[11];
  float* out = (float*)d_out;
  char* ws = (char*)d_ws;

  unsigned short* x1  = (unsigned short*)(ws + OFF_X1);
  unsigned char*  xq8 = (unsigned char*)(ws + OFF_XQ8);
  unsigned short* x2  = (unsigned short*)(ws + OFF_X2);
  unsigned short* x3  = (unsigned short*)(ws + OFF_X3);
  unsigned short* y4  = (unsigned short*)(ws + OFF_Y4);
  unsigned char*  wb8 = (unsigned char*)(ws + OFF_WB8);
  unsigned short* wb2 = (unsigned short*)(ws + OFF_WB2);
  unsigned short* wb3 = (unsigned short*)(ws + OFF_WB3);
  unsigned short* wbt = (unsigned short*)(ws + OFF_WBT);
  float* st1 = (float*)(ws + OFF_ST1);
  float* st2 = (float*)(ws + OFF_ST2);
  float* st3 = (float*)(ws + OFF_ST3);
  float* st4 = (float*)(ws + OFF_ST4);
  float* sums = (float*)(ws + OFF_SUMS);
  float* counts = (float*)(ws + OFF_CNT);
  int* lab = (int*)(ws + OFF_LAB);
  float* dws  = (float*)(ws + OFF_DWS);
  float* wsum = (float*)(ws + OFF_WSM);
  float* st5  = (float*)(ws + OFF_ST5);
  float* cbv  = (float*)(ws + OFF_CB);

  // stat buffers zero + ALL independent prep in one launch
  hipMemsetAsync(ws + OFF_ST1, 0, 342624, stream);    // stats+sums+counts
  hipMemsetAsync(ws + OFF_ST5, 0, 16384, stream);     // fp8 channel sums
  prep_k<<<3764, 256, 0, stream>>>(w2, wb2, w3, wb3, wt, wbt, w4, wb8, dws, wsum,
                                   x1, x2, x3, seg, lab, counts);

  conv1_k<<<dim3(256, 8), 256, 0, stream>>>(image, w1, x1, st1);
  nln_k<32><<<dim3(256, 8), 256, 0, stream>>>(x1 + 259 * 32, 258 * 32, 1024, 2130048L,
                                              st1, 1.f / 65536.f);

  conv2_k<<<dim3(128, 8), 256, 0, stream>>>(x1, wb2, x2, st2);
  nln_k<64><<<dim3(128, 8), 256, 0, stream>>>(x2 + 131 * 64, 130 * 64, 1024, 1081600L,
                                              st2, 1.f / 16384.f);

  conv3_k<<<dim3(32, 8), 256, 0, stream>>>(x2, wb3, x3, st3);
  nln_k<128><<<dim3(64, 8), 256, 0, stream>>>(x3, 65 * 128, 1024, 540800L,
                                              st3, 1.f / 4096.f);

  convT_k<<<dim3(32, 8, 8), 256, 0, stream>>>(x3, wbt, y4, st4);

  // y4 -> norm+lrelu -> fp8 (xq8, k-permuted) + channel sums; then bias correction
  nln8_k<<<dim3(128, 8), 256, 0, stream>>>(y4, st4, xq8, st5);
  cbias_k<<<dim3(512, 8), 256, 0, stream>>>(st5, dws, wsum, cbv);

  conv4_k<<<4096, 256, 0, stream>>>(xq8, wb8, b4, cbv, lab, sums);

  finalize_k<<<304, 256, 0, stream>>>(sums, counts, out);
}

// Round 20
// 679.605 us; speedup vs baseline: 1.3046x; 1.0175x over previous
//
#include <hip/hip_runtime.h>
#include <hip/hip_bf16.h>
#include <math.h>

typedef __attribute__((ext_vector_type(8))) short bf16x8;
typedef __attribute__((ext_vector_type(8))) unsigned short u16x8;
typedef __attribute__((ext_vector_type(4))) float f32x4;
typedef __attribute__((ext_vector_type(2))) long longx2;

// ---------------- workspace layout (bytes) ----------------
#define OFF_X1   0ull           // x1 [8,258,258,32] bf16; DEAD after conv2 -> reused as xq8
#define OFF_XQ8  0ull           // xq8 [8,128,128,256] fp8 (33.5 MB), k-permuted per 128-half
#define OFF_X2   34080768ull
#define OFF_X3   51386368ull
#define OFF_Y4   60039168ull
#define OFF_WB8  127148032ull   // wb8 [512,9,256] fp8 (1.18 MB), k-permuted per 128-half
#define OFF_WB2  129507328ull
#define OFF_WB3  129548288ull
#define OFF_WBT  129695744ull   // wbt8 [1024,512] fp8 (512 KB), k-permuted per 128-block
#define OFF_ST1  130744320ull
#define OFF_ST2  130746368ull
#define OFF_ST3  130750464ull
#define OFF_ST4  130758656ull
#define OFF_SUMS 130775040ull
#define OFF_CNT  131086336ull
#define OFF_LAB  131117664ull
#define OFF_DWS  131641952ull   // dws  [512][256] f32 (512 KB)
#define OFF_WSM  132166240ull   // wsum [512][256] f32 (512 KB)
#define OFF_ST5  132690528ull   // st5  [8][2][256] f32 (16 KB, zeroed)
#define OFF_CB   132706912ull   // cb   [8][512] f32 (16 KB)
#define OFF_X3Q  132723296ull   // x3q8 [8,65,65,128] fp8 (4.33 MB), k-permuted

__device__ __forceinline__ float bfu2f(unsigned short u) {
  return __builtin_bit_cast(float, ((unsigned)u) << 16);
}
__device__ __forceinline__ unsigned short f2bfu(float f) {
  __hip_bfloat16 h = __float2bfloat16(f);
  return __builtin_bit_cast(unsigned short, h);
}
__device__ __forceinline__ void gload_lds16(const void* g, void* l) {
  __builtin_amdgcn_global_load_lds(
      (const __attribute__((address_space(1))) unsigned int*)g,
      (__attribute__((address_space(3))) unsigned int*)l, 16, 0, 0);
}
template <bool HI>
__device__ __forceinline__ int cvtpk8(float a, float b, int old) {
  return __builtin_amdgcn_cvt_pk_fp8_f32(a, b, old, HI);
}
template <int SEL>
__device__ __forceinline__ float cvtf8(int v) {
  return __builtin_amdgcn_cvt_f32_fp8(v, SEL);
}

__device__ const int c_taptab[16] = {4, -1, -1, -1, 5, 3, -1, -1, 7, -1, 1, -1, 8, 6, 2, 0};

// ---------------- prep: wrep2 | wrep3 | wrepT8 | dwrep | padz | lab in ONE launch ---------
// block ranges: [0,80) wrep2, [80,368) wrep3, [368,2416) wrepT8, [2416,2928) dwrep,
//               [2928,3220) padz, [3220,3732) lab
__global__ __launch_bounds__(256) void prep_k(
    const float* __restrict__ w2, unsigned short* __restrict__ wb2,
    const float* __restrict__ w3, unsigned short* __restrict__ wb3,
    const float* __restrict__ wt, unsigned char* __restrict__ wbt8,
    const float* __restrict__ w4, unsigned char* __restrict__ wb8,
    float* __restrict__ dws, float* __restrict__ wsum,
    unsigned short* __restrict__ x1, unsigned short* __restrict__ x2,
    unsigned char* __restrict__ x3q8,
    const float* __restrict__ seg, int* __restrict__ lab, float* __restrict__ counts) {
  __shared__ int hist[19];
  int blk = blockIdx.x, t = threadIdx.x;
  if (blk < 80) {
    int idx = blk * 256 + t;
    if (idx < 20480) {
      int oc = idx / 320, r = idx % 320, tap = r >> 5, ic = r & 31;
      wb2[idx] = tap < 9 ? f2bfu(w2[(oc * 32 + ic) * 9 + tap]) : (unsigned short)0;
    }
  } else if (blk < 368) {
    int idx = (blk - 80) * 256 + t;
    int oc = idx / 576, r = idx % 576, tap = r >> 6, ic = r & 63;
    wb3[idx] = f2bfu(w3[(oc * 64 + ic) * 9 + tap]);
  } else if (blk < 2416) {
    int idx = (blk - 368) * 256 + t;
    int n = idx >> 9, k = idx & 511;
    int cl = n >> 8, oc = n & 255, nb = k >> 7, ic = k & 127;
    int tap = c_taptab[cl * 4 + nb];
    int p = ((ic >> 3) & 3) * 32 + ((ic >> 5) & 3) * 8 + (ic & 7);
    unsigned char v = 0;
    if (tap >= 0) {
      int pk = cvtpk8<false>(wt[(ic * 256 + oc) * 9 + tap], 0.f, 0);
      v = (unsigned char)(pk & 0xff);
    }
    wbt8[(size_t)n * 512 + nb * 128 + p] = v;
  } else if (blk < 2928) {
    int oc = blk - 2416, ic = t;
    int local = ic & 127;
    int p = (ic & 128) + ((local >> 3) & 3) * 32 + ((local >> 5) & 3) * 8 + (local & 7);
    float ds = 0.f, ws = 0.f;
    for (int kk = 0; kk < 9; ++kk) {
      float w = w4[(size_t)oc * 2304 + ic * 9 + kk];
      int pk = cvtpk8<false>(w, 0.f, 0);
      wb8[((size_t)oc * 9 + kk) * 256 + p] = (unsigned char)(pk & 0xff);
      float wq = cvtf8<0>(pk);
      ds += wq - w; ws += w;
    }
    dws[oc * 256 + ic] = ds;
    wsum[oc * 256 + ic] = ws;
  } else if (blk < 3220) {
    int u = (blk - 2928) * 256 + t;  // < 74560
    if (u < 74560) {
      int b = u / 9320, r = u % 9320;
      u16x8 z = {0, 0, 0, 0, 0, 0, 0, 0};
      if (r < 4128) {
        unsigned short* base = x1 + (size_t)b * 2130048;
        if (r < 2064) {
          int row = r < 1032 ? 0 : 257, pos = r < 1032 ? r : r - 1032;
          base += (row * 258 + (pos >> 2)) * 32 + (pos & 3) * 8;
        } else {
          int rc = r - 2064;
          int col = rc < 1032 ? 0 : 257, pos = rc < 1032 ? rc : rc - 1032;
          base += ((pos >> 2) * 258 + col) * 32 + (pos & 3) * 8;
        }
        *(u16x8*)base = z;
      } else if (r < 8288) {
        int s = r - 4128;
        unsigned short* base = x2 + (size_t)b * 1081600;
        if (s < 2080) {
          int row = s < 1040 ? 0 : 129, pos = s < 1040 ? s : s - 1040;
          base += (row * 130 + (pos >> 3)) * 64 + (pos & 7) * 8;
        } else {
          int sc = s - 2080;
          int col = sc < 1040 ? 0 : 129, pos = sc < 1040 ? sc : sc - 1040;
          base += ((pos >> 3) * 130 + col) * 64 + (pos & 7) * 8;
        }
        *(u16x8*)base = z;
      } else {
        int r3 = r - 8288;  // < 1032: x3q8 pads (row 64 all cols; col 64 rows 0..63)
        int idx = r3 >> 3, un = r3 & 7;
        int lin = idx < 65 ? (64 * 65 + idx) : ((idx - 65) * 65 + 64);
        longx2 zz = {0, 0};
        *(longx2*)(x3q8 + (size_t)b * 540800 + (size_t)lin * 128 + un * 16) = zz;
      }
    }
  } else {
    int blk2 = blk - 3220;  // < 512
    int b = blk2 >> 6;
    int p = (blk2 & 63) * 256 + t;
    if (t < 19) hist[t] = 0;
    __syncthreads();
    int i = p >> 7, j = p & 127;
    const float* sp = seg + (size_t)b * 19 * 65536 + (2 * i) * 256 + 2 * j;
    int l = 0;
    for (int k = 0; k < 19; ++k) { if (sp[(size_t)k * 65536] != 0.f) { l = k; break; } }
    lab[b * 16384 + p] = l;
    atomicAdd(&hist[l], 1);
    __syncthreads();
    if (t < 19) atomicAdd(&counts[b * 19 + t], (float)hist[t]);
  }
}

// ---------------- conv1: reflect-pad 3->32 -> x1 NHWC padded bf16 + fused channel stats ----
__global__ __launch_bounds__(256) void conv1_k(const float* __restrict__ img,
                                               const float* __restrict__ w1,
                                               unsigned short* __restrict__ x1,
                                               float* __restrict__ st1) {
  __shared__ float wl[864];        // [k 27][oc 32]
  __shared__ float tile[256][33];  // padded: avoids 1056 % 32 == 0 bank alias
  __shared__ float cbins[64];
  int t = threadIdx.x, y = blockIdx.x, b = blockIdx.y;
  for (int i = t; i < 864; i += 256) wl[i] = w1[(i & 31) * 27 + (i >> 5)];
  if (t < 64) cbins[t] = 0.f;
  __syncthreads();
  int x = t;
  float val[27];
  for (int ic = 0; ic < 3; ++ic) {
    const float* ip = img + ((size_t)(b * 3 + ic)) * 65536;
#pragma unroll
    for (int ky = 0; ky < 3; ++ky) {
      int gy = y - 1 + ky; gy = gy < 0 ? -gy : (gy > 255 ? 510 - gy : gy);
#pragma unroll
      for (int kx = 0; kx < 3; ++kx) {
        int gx = x - 1 + kx; gx = gx < 0 ? -gx : (gx > 255 ? 510 - gx : gx);
        val[ic * 9 + ky * 3 + kx] = ip[gy * 256 + gx];
      }
    }
  }
  float a[32];
#pragma unroll
  for (int oc = 0; oc < 32; ++oc) a[oc] = 0.f;
#pragma unroll
  for (int k = 0; k < 27; ++k) {
    float vv = val[k];
#pragma unroll
    for (int oc = 0; oc < 32; ++oc) a[oc] += wl[k * 32 + oc] * vv;
  }
  unsigned short ov[32];
#pragma unroll
  for (int oc = 0; oc < 32; ++oc) ov[oc] = f2bfu(a[oc]);
  unsigned short* op = x1 + ((size_t)(b * 258 + y + 1) * 258 + (x + 1)) * 32;
#pragma unroll
  for (int i = 0; i < 4; ++i) *(u16x8*)(op + i * 8) = *(const u16x8*)(ov + i * 8);

  // fused stats: block-local column sums of the [256 px][32 ch] tile
#pragma unroll
  for (int oc = 0; oc < 32; ++oc) tile[t][oc] = a[oc];
  __syncthreads();
  int ch = t & 31, seg = t >> 5;
  float s = 0.f, q = 0.f;
  for (int r = 0; r < 32; ++r) {
    float v = tile[seg * 32 + ((r + seg) & 31)][ch];
    s += v; q += v * v;
  }
  atomicAdd(&cbins[ch * 2], s);
  atomicAdd(&cbins[ch * 2 + 1], q);
  __syncthreads();
  if (t < 64) atomicAdd(&st1[b * 64 + t], cbins[t]);
}

// ---------------- normalize + leaky-relu in place; (mean,rstd) computed inline from st ----
template <int C>
__global__ void nln_k(unsigned short* __restrict__ base, int rowStride, int unitsPerRow,
                      long bStride, const float* __restrict__ st, float invN) {
  const int CH8 = C / 8;
  int row = blockIdx.x, b = blockIdx.y;
  unsigned short* rp = base + (size_t)b * bStride + (size_t)row * rowStride;
  int ch = (threadIdx.x & (CH8 - 1)) * 8;
  const float* stb = st + b * C * 2;
  float2 m0[8];
#pragma unroll
  for (int e = 0; e < 8; ++e) {
    float m = stb[(ch + e) * 2] * invN;
    float v = stb[(ch + e) * 2 + 1] * invN - m * m;
    m0[e] = make_float2(m, rsqrtf(fmaxf(v, 0.f) + 1e-5f));
  }
  for (int idx = threadIdx.x; idx < unitsPerRow; idx += 256) {
    u16x8 v = *(u16x8*)(rp + idx * 8);
    u16x8 o;
#pragma unroll
    for (int e = 0; e < 8; ++e) {
      float f = (bfu2f(v[e]) - m0[e].x) * m0[e].y;
      o[e] = f2bfu(f >= 0.f ? f : 0.2f * f);
    }
    *(u16x8*)(rp + idx * 8) = o;
  }
}

// ---------------- x3cvt: x3 bf16 -> norm+lrelu -> fp8 x3q8 (k-permuted), interior ---------
__global__ __launch_bounds__(256) void x3cvt_k(const unsigned short* __restrict__ x3,
                                               const float* __restrict__ st3,
                                               unsigned char* __restrict__ x3q8) {
  int t = threadIdx.x, i = blockIdx.x, b = blockIdx.y;  // i: 0..63
  int cg = t & 15, pg = t >> 4;                          // 16 ch-groups x 16 px-groups
  int wof = ((((cg & 3) << 2) | (cg >> 2))) * 8;
  const float* stb = st3 + b * 256;
  const float invN = 1.f / 4096.f;
  float2 m0[8];
#pragma unroll
  for (int e = 0; e < 8; ++e) {
    float m = stb[(cg * 8 + e) * 2] * invN;
    float v = stb[(cg * 8 + e) * 2 + 1] * invN - m * m;
    m0[e] = make_float2(m, rsqrtf(fmaxf(v, 0.f) + 1e-5f));
  }
  const unsigned short* rp = x3 + (size_t)b * 540800;
  unsigned char* op = x3q8 + (size_t)b * 540800;
#pragma unroll
  for (int jj = 0; jj < 4; ++jj) {
    int j = pg * 4 + jj;
    u16x8 v = *(const u16x8*)(rp + ((size_t)(i * 65 + j)) * 128 + cg * 8);
    float f[8];
#pragma unroll
    for (int e = 0; e < 8; ++e) {
      float x = (bfu2f(v[e]) - m0[e].x) * m0[e].y;
      f[e] = x >= 0.f ? x : 0.2f * x;
    }
    int lo = cvtpk8<false>(f[0], f[1], 0); lo = cvtpk8<true>(f[2], f[3], lo);
    int hi = cvtpk8<false>(f[4], f[5], 0); hi = cvtpk8<true>(f[6], f[7], hi);
    *(long*)(op + ((size_t)(i * 65 + j)) * 128 + wof) =
        ((long)(unsigned)hi << 32) | (unsigned)lo;
  }
}

// ---------------- nln8: y4 bf16 -> norm+lrelu -> fp8 xq8 (k-permuted) + channel sums ------
__global__ __launch_bounds__(256) void nln8_k(const unsigned short* __restrict__ y4,
                                              const float* __restrict__ st4,
                                              unsigned char* __restrict__ xq8,
                                              float* __restrict__ st5) {
  __shared__ float bs[512];
  int t = threadIdx.x, row = blockIdx.x, b = blockIdx.y;
  int cg = t & 31, pg = t >> 5;
  int wof0 = (cg >> 4) * 128 + ((((cg & 15) & 3) << 2) | ((cg & 15) >> 2)) * 8;
  const float* stb = st4 + b * 512;
  const float invN = 1.f / 16384.f;
  float2 m0[8];
#pragma unroll
  for (int e = 0; e < 8; ++e) {
    float m = stb[(cg * 8 + e) * 2] * invN;
    float v = stb[(cg * 8 + e) * 2 + 1] * invN - m * m;
    m0[e] = make_float2(m, rsqrtf(fmaxf(v, 0.f) + 1e-5f));
  }
  const unsigned short* rp = y4 + ((size_t)b * 16384 + row * 128) * 256;
  unsigned char* op = xq8 + ((size_t)b * 16384 + (size_t)row * 128) * 256;
  float s[8] = {0, 0, 0, 0, 0, 0, 0, 0}, d[8] = {0, 0, 0, 0, 0, 0, 0, 0};
  for (int i = 0; i < 16; ++i) {
    int px = pg * 16 + i;
    u16x8 v = *(const u16x8*)(rp + (size_t)px * 256 + cg * 8);
    float f[8];
#pragma unroll
    for (int e = 0; e < 8; ++e) {
      float x = (bfu2f(v[e]) - m0[e].x) * m0[e].y;
      f[e] = x >= 0.f ? x : 0.2f * x;
    }
    int lo = cvtpk8<false>(f[0], f[1], 0); lo = cvtpk8<true>(f[2], f[3], lo);
    int hi = cvtpk8<false>(f[4], f[5], 0); hi = cvtpk8<true>(f[6], f[7], hi);
    *(long*)(op + (size_t)px * 256 + wof0) =
        ((long)(unsigned)hi << 32) | (unsigned)lo;
    float fq;
    fq = cvtf8<0>(lo); s[0] += fq; d[0] += fq - f[0];
    fq = cvtf8<1>(lo); s[1] += fq; d[1] += fq - f[1];
    fq = cvtf8<2>(lo); s[2] += fq; d[2] += fq - f[2];
    fq = cvtf8<3>(lo); s[3] += fq; d[3] += fq - f[3];
    fq = cvtf8<0>(hi); s[4] += fq; d[4] += fq - f[4];
    fq = cvtf8<1>(hi); s[5] += fq; d[5] += fq - f[5];
    fq = cvtf8<2>(hi); s[6] += fq; d[6] += fq - f[6];
    fq = cvtf8<3>(hi); s[7] += fq; d[7] += fq - f[7];
  }
  for (int i = t; i < 512; i += 256) bs[i] = 0.f;
  __syncthreads();
#pragma unroll
  for (int e = 0; e < 8; ++e) {
    atomicAdd(&bs[cg * 8 + e], s[e]);
    atomicAdd(&bs[256 + cg * 8 + e], d[e]);
  }
  __syncthreads();
  for (int i = t; i < 512; i += 256) atomicAdd(&st5[b * 512 + i], bs[i]);
}

// ---------------- cbias: c[b][oc] = sum_ic( muq*dws + dmu*wsum ) ----------------
__global__ __launch_bounds__(256) void cbias_k(const float* __restrict__ st5,
                                               const float* __restrict__ dws,
                                               const float* __restrict__ wsum,
                                               float* __restrict__ cb) {
  int oc = blockIdx.x, b = blockIdx.y, t = threadIdx.x;
  const float inv = 1.f / 16384.f;
  float muq = st5[b * 512 + t] * inv;
  float dmu = st5[b * 512 + 256 + t] * inv;
  float a = muq * dws[oc * 256 + t] + dmu * wsum[oc * 256 + t];
#pragma unroll
  for (int o = 1; o < 64; o <<= 1) a += __shfl_xor(a, o);
  __shared__ float r[4];
  if ((t & 63) == 0) r[t >> 6] = a;
  __syncthreads();
  if (t == 0) cb[b * 512 + oc] = r[0] + r[1] + r[2] + r[3];
}

// ---------------- conv2 MFMA (double-buffered): x1 -> x2 + stats ----------------
__global__ __launch_bounds__(256) void conv2_k(const unsigned short* __restrict__ x1,
                                               const unsigned short* __restrict__ wb2,
                                               unsigned short* __restrict__ x2,
                                               float* __restrict__ st2) {
  __shared__ char smem[49664];
  float* bins = (float*)(smem + 49152);
  int tid = threadIdx.x, y = blockIdx.x, b = blockIdx.y;
  int lane = tid & 63, w = tid >> 6, wm = w >> 1, wn = w & 1;
  int lr = lane & 15, lg = lane >> 4;
  f32x4 acc[4][2];
#pragma unroll
  for (int i = 0; i < 4; ++i)
#pragma unroll
    for (int j = 0; j < 2; ++j) acc[i][j] = (f32x4){0.f, 0.f, 0.f, 0.f};

  int rowA[4], lcA[4], PbA[4];
#pragma unroll
  for (int i = 0; i < 4; ++i) {
    int pb = i * 256 + tid;
    PbA[i] = pb * 16; rowA[i] = pb >> 3; lcA[i] = (pb & 7) ^ (rowA[i] & 7);
  }
  int rowB[2], lcB[2], PbB[2];
#pragma unroll
  for (int i = 0; i < 2; ++i) {
    int pb = i * 256 + tid;
    PbB[i] = pb * 16; rowB[i] = pb >> 3; lcB[i] = (pb & 7) ^ (rowB[i] & 7);
  }
  const unsigned short* xb = x1 + (size_t)b * 2130048;

  auto stage = [&](int kb, char* base) {
    char* As = base;
    char* Bs = base + 16384;
#pragma unroll
    for (int i = 0; i < 4; ++i) {
      int tp = kb * 2 + (lcA[i] >> 2);
      int ky = (tp * 11) >> 5;
      int kx = tp - ky * 3;
      gload_lds16(xb + ((size_t)((2 * y + ky) * 258 + 2 * rowA[i] + kx)) * 32 + (lcA[i] & 3) * 8,
                  As + PbA[i]);
    }
#pragma unroll
    for (int i = 0; i < 2; ++i)
      gload_lds16(wb2 + rowB[i] * 320 + kb * 64 + lcB[i] * 8, Bs + PbB[i]);
  };

  stage(0, smem);
  __syncthreads();
  for (int kb = 0; kb < 5; ++kb) {
    char* base = smem + (kb & 1) * 24576;
    if (kb + 1 < 5) stage(kb + 1, smem + ((kb + 1) & 1) * 24576);
    char* As = base;
    char* Bs = base + 16384;
    bf16x8 af[4][2], bfr[2][2];
#pragma unroll
    for (int mi = 0; mi < 4; ++mi)
#pragma unroll
      for (int kh = 0; kh < 2; ++kh) {
        int row = wm * 64 + mi * 16 + lr;
        int byte = row * 128 + ((kh * 64 + lg * 16) ^ ((row & 7) << 4));
        af[mi][kh] = *(const bf16x8*)(As + byte);
      }
#pragma unroll
    for (int ni = 0; ni < 2; ++ni)
#pragma unroll
      for (int kh = 0; kh < 2; ++kh) {
        int row = wn * 32 + ni * 16 + lr;
        int byte = row * 128 + ((kh * 64 + lg * 16) ^ ((row & 7) << 4));
        bfr[ni][kh] = *(const bf16x8*)(Bs + byte);
      }
#pragma unroll
    for (int mi = 0; mi < 4; ++mi)
#pragma unroll
      for (int ni = 0; ni < 2; ++ni)
#pragma unroll
        for (int kh = 0; kh < 2; ++kh)
          acc[mi][ni] = __builtin_amdgcn_mfma_f32_16x16x32_bf16(af[mi][kh], bfr[ni][kh],
                                                                acc[mi][ni], 0, 0, 0);
    __syncthreads();
  }

  if (tid < 128) bins[tid] = 0.f;
  __syncthreads();
  unsigned short* ob = x2 + (size_t)b * 1081600;
#pragma unroll
  for (int ni = 0; ni < 2; ++ni) {
    int oc = wn * 32 + ni * 16 + lr;
    float s = 0.f, q = 0.f;
#pragma unroll
    for (int mi = 0; mi < 4; ++mi)
#pragma unroll
      for (int r = 0; r < 4; ++r) {
        int m = wm * 64 + mi * 16 + lg * 4 + r;
        float v = acc[mi][ni][r];
        ob[((y + 1) * 130 + m + 1) * 64 + oc] = f2bfu(v);
        s += v; q += v * v;
      }
    atomicAdd(&bins[oc * 2], s);
    atomicAdd(&bins[oc * 2 + 1], q);
  }
  __syncthreads();
  if (tid < 128) atomicAdd(&st2[b * 128 + tid], bins[tid]);
}

// ---------------- conv3 MFMA (double-buffered): x2 -> x3 + stats ----------------
__global__ __launch_bounds__(256) void conv3_k(const unsigned short* __restrict__ x2,
                                               const unsigned short* __restrict__ wb3,
                                               unsigned short* __restrict__ x3,
                                               float* __restrict__ st3) {
  __shared__ char smem[66560];
  float* bins = (float*)(smem + 65536);
  int tid = threadIdx.x, y0 = blockIdx.x * 2, b = blockIdx.y;
  int lane = tid & 63, w = tid >> 6, wm = w >> 1, wn = w & 1;
  int lr = lane & 15, lg = lane >> 4;
  f32x4 acc[4][4];
#pragma unroll
  for (int i = 0; i < 4; ++i)
#pragma unroll
    for (int j = 0; j < 4; ++j) acc[i][j] = (f32x4){0.f, 0.f, 0.f, 0.f};

  int rowS[4], lc[4], Pb[4];
#pragma unroll
  for (int i = 0; i < 4; ++i) {
    int pb = i * 256 + tid;
    Pb[i] = pb * 16; rowS[i] = pb >> 3; lc[i] = (pb & 7) ^ (rowS[i] & 7);
  }
  const unsigned short* xb = x2 + (size_t)b * 1081600;

  auto stage = [&](int kk, char* base) {
    int ky = kk / 3, kx = kk - ky * 3;
#pragma unroll
    for (int i = 0; i < 4; ++i) {
      int m = rowS[i], di = m >> 6, xx = m & 63;
      gload_lds16(xb + ((size_t)((2 * (y0 + di) + ky) * 130 + 2 * xx + kx)) * 64 + lc[i] * 8,
                  base + Pb[i]);
    }
#pragma unroll
    for (int i = 0; i < 4; ++i)
      gload_lds16(wb3 + (rowS[i] * 9 + kk) * 64 + lc[i] * 8, base + 16384 + Pb[i]);
  };

  stage(0, smem);
  __syncthreads();
  for (int kk = 0; kk < 9; ++kk) {
    char* base = smem + (kk & 1) * 32768;
    if (kk + 1 < 9) stage(kk + 1, smem + ((kk + 1) & 1) * 32768);
    char* As = base;
    char* Bs = base + 16384;
    bf16x8 af[4][2], bfr[4][2];
#pragma unroll
    for (int mi = 0; mi < 4; ++mi)
#pragma unroll
      for (int kh = 0; kh < 2; ++kh) {
        int row = wm * 64 + mi * 16 + lr;
        int byte = row * 128 + ((kh * 64 + lg * 16) ^ ((row & 7) << 4));
        af[mi][kh] = *(const bf16x8*)(As + byte);
      }
#pragma unroll
    for (int ni = 0; ni < 4; ++ni)
#pragma unroll
      for (int kh = 0; kh < 2; ++kh) {
        int row = wn * 64 + ni * 16 + lr;
        int byte = row * 128 + ((kh * 64 + lg * 16) ^ ((row & 7) << 4));
        bfr[ni][kh] = *(const bf16x8*)(Bs + byte);
      }
#pragma unroll
    for (int mi = 0; mi < 4; ++mi)
#pragma unroll
      for (int ni = 0; ni < 4; ++ni)
#pragma unroll
        for (int kh = 0; kh < 2; ++kh)
          acc[mi][ni] = __builtin_amdgcn_mfma_f32_16x16x32_bf16(af[mi][kh], bfr[ni][kh],
                                                                acc[mi][ni], 0, 0, 0);
    __syncthreads();
  }

  if (tid < 256) bins[tid] = 0.f;
  __syncthreads();
  unsigned short* ob = x3 + (size_t)b * 540800;
#pragma unroll
  for (int ni = 0; ni < 4; ++ni) {
    int oc = wn * 64 + ni * 16 + lr;
    float s = 0.f, q = 0.f;
#pragma unroll
    for (int mi = 0; mi < 4; ++mi)
#pragma unroll
      for (int r = 0; r < 4; ++r) {
        int m = wm * 64 + mi * 16 + lg * 4 + r;
        int di = m >> 6, xx = m & 63;
        float v = acc[mi][ni][r];
        ob[((y0 + di) * 65 + xx) * 128 + oc] = f2bfu(v);
        s += v; q += v * v;
      }
    atomicAdd(&bins[oc * 2], s);
    atomicAdd(&bins[oc * 2 + 1], q);
  }
  __syncthreads();
  if (tid < 256) atomicAdd(&st3[b * 256 + tid], bins[tid]);
}

// ---------------- convT8: fp8 unified GEMM, conv4-style loop: x3q8 -> y4 + stats ----------
// BM=128 (2 i-rows x 64 j), BN=128 (class/oc-half), BK=128 (one neighbor), 4 K-steps.
// A/B LDS [128 rows][128B fp8] k-permuted; conflict-free b128 frag reads. No bias
// correction needed: instance norm after convT absorbs fp8 weight mean-shift.
__global__ __launch_bounds__(256, 4) void convT8_k(const unsigned char* __restrict__ x3q8,
                                                   const unsigned char* __restrict__ wbt8,
                                                   unsigned short* __restrict__ y4,
                                                   float* __restrict__ st4) {
  __shared__ char smem[33792];  // As 16K | Bs 16K | bins 1K
  char* As = smem;
  char* Bs = smem + 16384;
  float* bins = (float*)(smem + 32768);
  int tid = threadIdx.x, i0 = blockIdx.x * 2, nblk = blockIdx.y, b = blockIdx.z;
  int n0 = nblk * 128, cl = nblk >> 1, och0 = (nblk & 1) * 128;
  int lane = tid & 63, w = tid >> 6, wm = w >> 1, wn = w & 1;
  int lr = lane & 15, lg = lane >> 4;
  f32x4 acc[4][4];
#pragma unroll
  for (int i = 0; i < 4; ++i)
#pragma unroll
    for (int j = 0; j < 4; ++j) acc[i][j] = (f32x4){0.f, 0.f, 0.f, 0.f};

  int rs0 = tid >> 3;
  int csw = ((tid & 7) ^ (rs0 & 7)) << 4;
  int ldoff = tid * 16;
  const unsigned char* xb = x3q8 + (size_t)b * 540800;

  for (int nb = 0; nb < 4; ++nb) {
    __syncthreads();
#pragma unroll
    for (int i = 0; i < 4; ++i) {
      int m = rs0 + 32 * i, di = m >> 6, j = m & 63;
      int pi = i0 + di + (nb >> 1), pj = j + (nb & 1);
      gload_lds16(xb + ((size_t)(pi * 65 + pj)) * 128 + csw, As + i * 4096 + ldoff);
    }
#pragma unroll
    for (int i = 0; i < 4; ++i) {
      int n = rs0 + 32 * i;
      gload_lds16(wbt8 + (size_t)(n0 + n) * 512 + nb * 128 + csw, Bs + i * 4096 + ldoff);
    }
    __syncthreads();

    longx2 bq[4][2];
#pragma unroll
    for (int ni = 0; ni < 4; ++ni) {
      int row = wn * 64 + ni * 16 + lr;
#pragma unroll
      for (int k2 = 0; k2 < 2; ++k2) {
        int byte = row * 128 + ((lg * 32 + k2 * 16) ^ ((row & 7) << 4));
        bq[ni][k2] = *(const longx2*)(Bs + byte);
      }
    }
#pragma unroll
    for (int mi = 0; mi < 4; ++mi) {
      int row = wm * 64 + mi * 16 + lr;
      longx2 aq[2];
#pragma unroll
      for (int k2 = 0; k2 < 2; ++k2) {
        int byte = row * 128 + ((lg * 32 + k2 * 16) ^ ((row & 7) << 4));
        aq[k2] = *(const longx2*)(As + byte);
      }
#pragma unroll
      for (int ni = 0; ni < 4; ++ni)
#pragma unroll
        for (int k2 = 0; k2 < 2; ++k2) {
          acc[mi][ni] = __builtin_amdgcn_mfma_f32_16x16x32_fp8_fp8(
              aq[k2][0], bq[ni][k2][0], acc[mi][ni], 0, 0, 0);
          acc[mi][ni] = __builtin_amdgcn_mfma_f32_16x16x32_fp8_fp8(
              aq[k2][1], bq[ni][k2][1], acc[mi][ni], 0, 0, 0);
        }
    }
  }

  __syncthreads();
  if (tid < 256) bins[tid] = 0.f;
  __syncthreads();
  unsigned short* ob = y4 + (size_t)b * 4194304;
  int dy = cl >> 1, dx = cl & 1;
#pragma unroll
  for (int ni = 0; ni < 4; ++ni) {
    int loc = wn * 64 + ni * 16 + lr;
    int oc = och0 + loc;
    float s = 0.f, q = 0.f;
#pragma unroll
    for (int mi = 0; mi < 4; ++mi)
#pragma unroll
      for (int r = 0; r < 4; ++r) {
        int m = wm * 64 + mi * 16 + lg * 4 + r;
        int di = m >> 6, j = m & 63;
        int oy = 2 * (i0 + di) + dy, ox = 2 * j + dx;
        float v = acc[mi][ni][r];
        ob[(oy * 128 + ox) * 256 + oc] = f2bfu(v);
        s += v; q += v * v;
      }
    atomicAdd(&bins[loc * 2], s);
    atomicAdd(&bins[loc * 2 + 1], q);
  }
  __syncthreads();
  if (tid < 256) atomicAdd(&st4[b * 512 + och0 * 2 + tid], bins[tid]);
}

// ---------------- conv4: fp8 implicit GEMM, 128x128 tile, BK=128, XCD-swizzled ----------
__global__ __launch_bounds__(256, 4) void conv4_k(
    const unsigned char* __restrict__ xq8, const unsigned char* __restrict__ wb8,
    const float* __restrict__ b4, const float* __restrict__ cb,
    const int* __restrict__ lab, float* __restrict__ sums) {
  __shared__ char smem[33280];  // As 16K | Bs 16K | labs 512B
  char* As = smem;
  char* Bs = smem + 16384;
  int* labs = (int*)(smem + 32768);
  int tid = threadIdx.x;
  int id = blockIdx.x;
  int b = id & 7, rr = id >> 3;
  int y = rr >> 2, nblk = rr & 3;
  int n0 = nblk * 128;
  if (tid < 128) labs[tid] = lab[b * 16384 + y * 128 + tid];
  int lane = tid & 63, w = tid >> 6;
  int wm = w >> 1, wn = w & 1;
  int lr = lane & 15, lg = lane >> 4;

  f32x4 acc[4][4];
#pragma unroll
  for (int i = 0; i < 4; ++i)
#pragma unroll
    for (int j = 0; j < 4; ++j) acc[i][j] = (f32x4){0.f, 0.f, 0.f, 0.f};

  const unsigned char* xb = xq8 + (size_t)b * 4194304;

  int rs0 = tid >> 3;
  int csw = ((tid & 7) ^ (rs0 & 7)) << 4;  // byte offset of 16B chunk within 128B row
  int ldoff = tid * 16;                    // + i*4096

  const unsigned char* brow[4];
#pragma unroll
  for (int i = 0; i < 4; ++i)
    brow[i] = wb8 + (size_t)(n0 + rs0 + 32 * i) * 2304 + csw;

  int koff = 0;  // kk*256 + ic0 = step*128
  for (int kk = 0; kk < 9; ++kk) {
    int ky = (kk * 11) >> 5, kx = kk - ky * 3;
    int sy = y + ky - 1; sy = sy < 0 ? 1 : (sy > 127 ? 126 : sy);
    const unsigned char* arow[4];
#pragma unroll
    for (int i = 0; i < 4; ++i) {
      int sx = rs0 + 32 * i + kx - 1;
      sx = sx < 0 ? 1 : (sx > 127 ? 126 : sx);
      arow[i] = xb + ((size_t)(sy * 128 + sx)) * 256 + csw;
    }
    for (int ic0 = 0; ic0 < 256; ic0 += 128) {
      __syncthreads();
#pragma unroll
      for (int i = 0; i < 4; ++i) gload_lds16(arow[i] + ic0, As + i * 4096 + ldoff);
#pragma unroll
      for (int i = 0; i < 4; ++i) gload_lds16(brow[i] + koff, Bs + i * 4096 + ldoff);
      koff += 128;
      __syncthreads();

      longx2 bq[4][2];
#pragma unroll
      for (int ni = 0; ni < 4; ++ni) {
        int row = wn * 64 + ni * 16 + lr;
#pragma unroll
        for (int k2 = 0; k2 < 2; ++k2) {
          int byte = row * 128 + ((lg * 32 + k2 * 16) ^ ((row & 7) << 4));
          bq[ni][k2] = *(const longx2*)(Bs + byte);
        }
      }
#pragma unroll
      for (int mi = 0; mi < 4; ++mi) {
        int row = wm * 64 + mi * 16 + lr;
        longx2 aq[2];
#pragma unroll
        for (int k2 = 0; k2 < 2; ++k2) {
          int byte = row * 128 + ((lg * 32 + k2 * 16) ^ ((row & 7) << 4));
          aq[k2] = *(const longx2*)(As + byte);
        }
#pragma unroll
        for (int ni = 0; ni < 4; ++ni)
#pragma unroll
          for (int k2 = 0; k2 < 2; ++k2) {
            acc[mi][ni] = __builtin_amdgcn_mfma_f32_16x16x32_fp8_fp8(
                aq[k2][0], bq[ni][k2][0], acc[mi][ni], 0, 0, 0);
            acc[mi][ni] = __builtin_amdgcn_mfma_f32_16x16x32_fp8_fp8(
                aq[k2][1], bq[ni][k2][1], acc[mi][ni], 0, 0, 0);
          }
      }
    }
  }

  // epilogue: (bias - fp8 bias-correction) + tanh + per-label bins
  __syncthreads();
  float* bins = (float*)smem;  // [19][128]
  for (int t2 = tid; t2 < 19 * 128; t2 += 256) bins[t2] = 0.f;
  __syncthreads();
  float bias[4];
#pragma unroll
  for (int ni = 0; ni < 4; ++ni) {
    int gc = n0 + wn * 64 + ni * 16 + lr;
    bias[ni] = b4[gc] - cb[b * 512 + gc];
  }
#pragma unroll
  for (int mi = 0; mi < 4; ++mi)
#pragma unroll
    for (int ni = 0; ni < 4; ++ni) {
      int ct = wn * 64 + ni * 16 + lr;
#pragma unroll
      for (int r = 0; r < 4; ++r) {
        int x = wm * 64 + mi * 16 + lg * 4 + r;
        float v = tanhf(acc[mi][ni][r] + bias[ni]);
        atomicAdd(&bins[labs[x] * 128 + ct], v);
      }
    }
  __syncthreads();
  for (int t2 = tid; t2 < 19 * 128; t2 += 256) {
    float v = bins[t2];
    if (v != 0.f)
      atomicAdd(&sums[((size_t)(b * 19 + (t2 >> 7))) * 512 + n0 + (t2 & 127)], v);
  }
}

// ---------------- finalize ----------------
__global__ void finalize_k(const float* __restrict__ sums, const float* __restrict__ counts,
                           float* __restrict__ out) {
  int idx = blockIdx.x * 256 + threadIdx.x;
  int bl = idx / 512;
  float c = counts[bl];
  out[idx] = c > 0.f ? sums[idx] / fmaxf(c, 1.f) : 0.f;
}

extern "C" void kernel_launch(void* const* d_in, const int* in_sizes, int n_in,
                              void* d_out, int out_size, void* d_ws, size_t ws_size,
                              hipStream_t stream) {
  const float* image = (const float*)d_in[0];
  const float* seg   = (const float*)d_in[1];
  const float* w1    = (const float*)d_in[2];
  const float* w2    = (const float*)d_in[4];
  const float* w3    = (const float*)d_in[6];
  const float* wt    = (const float*)d_in[8];
  const float* w4    = (const float*)d_in[10];
  const float* b4    = (const float*)d_in[11];
  float* out = (float*)d_out;
  char* ws = (char*)d_ws;

  unsigned short* x1   = (unsigned short*)(ws + OFF_X1);
  unsigned char*  xq8  = (unsigned char*)(ws + OFF_XQ8);
  unsigned short* x2   = (unsigned short*)(ws + OFF_X2);
  unsigned short* x3   = (unsigned short*)(ws + OFF_X3);
  unsigned char*  x3q8 = (unsigned char*)(ws + OFF_X3Q);
  unsigned short* y4   = (unsigned short*)(ws + OFF_Y4);
  unsigned char*  wb8  = (unsigned char*)(ws + OFF_WB8);
  unsigned short* wb2  = (unsigned short*)(ws + OFF_WB2);
  unsigned short* wb3  = (unsigned short*)(ws + OFF_WB3);
  unsigned char*  wbt8 = (unsigned char*)(ws + OFF_WBT);
  float* st1 = (float*)(ws + OFF_ST1);
  float* st2 = (float*)(ws + OFF_ST2);
  float* st3 = (float*)(ws + OFF_ST3);
  float* st4 = (float*)(ws + OFF_ST4);
  float* sums = (float*)(ws + OFF_SUMS);
  float* counts = (float*)(ws + OFF_CNT);
  int* lab = (int*)(ws + OFF_LAB);
  float* dws  = (float*)(ws + OFF_DWS);
  float* wsum = (float*)(ws + OFF_WSM);
  float* st5  = (float*)(ws + OFF_ST5);
  float* cbv  = (float*)(ws + OFF_CB);

  // stat buffers zero + ALL independent prep in one launch
  hipMemsetAsync(ws + OFF_ST1, 0, 342624, stream);    // stats+sums+counts
  hipMemsetAsync(ws + OFF_ST5, 0, 16384, stream);     // fp8 channel sums
  prep_k<<<3732, 256, 0, stream>>>(w2, wb2, w3, wb3, wt, wbt8, w4, wb8, dws, wsum,
                                   x1, x2, x3q8, seg, lab, counts);

  conv1_k<<<dim3(256, 8), 256, 0, stream>>>(image, w1, x1, st1);
  nln_k<32><<<dim3(256, 8), 256, 0, stream>>>(x1 + 259 * 32, 258 * 32, 1024, 2130048L,
                                              st1, 1.f / 65536.f);

  conv2_k<<<dim3(128, 8), 256, 0, stream>>>(x1, wb2, x2, st2);
  nln_k<64><<<dim3(128, 8), 256, 0, stream>>>(x2 + 131 * 64, 130 * 64, 1024, 1081600L,
                                              st2, 1.f / 16384.f);

  conv3_k<<<dim3(32, 8), 256, 0, stream>>>(x2, wb3, x3, st3);
  x3cvt_k<<<dim3(64, 8), 256, 0, stream>>>(x3, st3, x3q8);

  convT8_k<<<dim3(32, 8, 8), 256, 0, stream>>>(x3q8, wbt8, y4, st4);

  // y4 -> norm+lrelu -> fp8 (xq8, k-permuted) + channel sums; then bias correction
  nln8_k<<<dim3(128, 8), 256, 0, stream>>>(y4, st4, xq8, st5);
  cbias_k<<<dim3(512, 8), 256, 0, stream>>>(st5, dws, wsum, cbv);

  conv4_k<<<4096, 256, 0, stream>>>(xq8, wb8, b4, cbv, lab, sums);

  finalize_k<<<304, 256, 0, stream>>>(sums, counts, out);
}